// Round 3
// baseline (385.836 us; speedup 1.0000x reference)
//
#include <hip/hip_runtime.h>
#include <math.h>

#define CC 64
#define KK 48
#define HH 4
#define DD 16
#define FF 256
#define QPB 4   // queries per block, one per wave

#define WS_FLAG 49408

// per-wave LDS ordering fence: waits LDS ops, compiler memory fence.
// Global loads (vmcnt) stay in flight across it.
#define LDSFENCE() asm volatile("s_waitcnt lgkmcnt(0)" ::: "memory")

struct __align__(16) QState {
  unsigned short kin[KK][72];  // bf16 k_in, row stride 144 B (16B-aligned, odd granule stride)
  float rel[KK][4];            // xyz rel + idx bits; later overlaid by softmax weights (float4/key)
  float vec[CC];               // q_in, later o
  float q[CC];
  float qw[HH][68];            // folded q·wk; later overlaid by t[4][68]
  float qb[HH];
};  // 9296 B; x4 = 37184 B/block -> 4 blocks/CU

__device__ __forceinline__ unsigned short f2bf(float f) {
  unsigned u = __float_as_uint(f);
  unsigned r = (u + 0x7fffu + ((u >> 16) & 1u)) >> 16;  // RNE
  return (unsigned short)r;
}

// ---------------- mask dtype detection ----------------
__global__ __launch_bounds__(256) void detect_mask_kernel(
    const unsigned char* __restrict__ km, int* __restrict__ flag)
{
  int any = 0;
  for (int i = threadIdx.x; i < 4096; i += 256)
    if ((i & 3) && km[i]) any = 1;
  __shared__ int s;
  if (threadIdx.x == 0) s = 0;
  __syncthreads();
  if (any) atomicOr(&s, 1);
  __syncthreads();
  if (threadIdx.x == 0) *flag = s;
}

// ---------------- prep: transposes + BN folds into d_ws (mlp consumables) ----------------
__global__ __launch_bounds__(256) void prep_kernel(
    const float* __restrict__ ipw, const float* __restrict__ opw,
    const float* __restrict__ l1w, const float* __restrict__ l2w,
    const float* __restrict__ ow,
    const float* __restrict__ ng, const float* __restrict__ nb,
    const float* __restrict__ nm, const float* __restrict__ nv,
    const float* __restrict__ b2g, const float* __restrict__ b2b,
    const float* __restrict__ b2m, const float* __restrict__ b2v,
    float* __restrict__ ws)
{
  int t = blockIdx.x * 256 + threadIdx.x;
  float* l1T = ws + 12288;
  float* l2T = ws + 28672;
  float* oT  = ws + 45056;
  float* nrm = ws + 49152;
  float* bn2 = ws + 49280;
  if (t >= 12288 && t < 28672) { int i = t - 12288; int c = i >> 8, f = i & 255; l1T[i] = l1w[f * CC + c]; }
  else if (t >= 28672 && t < 45056) { int i = t - 28672; int f = i >> 6, c = i & 63; l2T[i] = l2w[c * FF + f]; }
  else if (t >= 45056 && t < 49152) { int i = t - 45056; int c = i >> 6, co = i & 63; oT[i] = ow[co * CC + c]; }
  else if (t >= 49152 && t < 49216) { int c = t - 49152; float s = ng[c] / sqrtf(nv[c] + 1e-5f); nrm[c] = s; nrm[64 + c] = nb[c] - nm[c] * s; }
  else if (t >= 49216 && t < 49280) { int c = t - 49216; float s = b2g[c] / sqrtf(b2v[c] + 1e-5f); bn2[c] = s; bn2[64 + c] = b2b[c] - b2m[c] * s; }
}

// ---------------- attention: 4 independent waves per block, no barriers ----------------
__global__ __launch_bounds__(256, 4) void attn_kernel(
    const float* __restrict__ vfeat, const float* __restrict__ vcoord,
    const float* __restrict__ qcoord, const int* __restrict__ kidx,
    const unsigned char* __restrict__ km8, const int* __restrict__ km32,
    const int* __restrict__ maskfmt,
    const float* __restrict__ qpw, const float* __restrict__ qpb,
    const float* __restrict__ kpw, const float* __restrict__ kpb,
    const float* __restrict__ ipw, const float* __restrict__ ipb,
    const float* __restrict__ opw, const float* __restrict__ opb,
    float* __restrict__ attend, int M)
{
  __shared__ QState qs[QPB];
  const int w = threadIdx.x >> 6;
  const int l = threadIdx.x & 63;
  const int m = blockIdx.x * QPB + w;
  if (m >= M) return;                 // no barriers anywhere: safe
  QState& s = qs[w];
  const int is_u8 = *maskfmt;

  const float qx = qcoord[m * 3 + 0], qy = qcoord[m * 3 + 1], qz = qcoord[m * 3 + 2];
  // per-lane k_pos weights (kept in regs, used in P5)
  const float kw0 = kpw[l * 3 + 0], kw1 = kpw[l * 3 + 1], kw2 = kpw[l * 3 + 2], kb = kpb[l];

  // ---- P1: q_in, key indices / rel coords / mask ----
  {
    float v = qpw[l * 3 + 0] * qx + qpw[l * 3 + 1] * qy + qpw[l * 3 + 2] * qz + qpb[l];
    s.vec[l] = fmaxf(v, 0.f);
  }
  unsigned char msk = 0;
  if (l < KK) {
    int idx = kidx[m * KK + l];
    msk = is_u8 ? km8[m * KK + l] : (unsigned char)(km32[m * KK + l] != 0);
    float rx = vcoord[idx * 3 + 0] - qx;
    float ry = vcoord[idx * 3 + 1] - qy;
    float rz = vcoord[idx * 3 + 2] - qz;
    s.rel[l][0] = rx; s.rel[l][1] = ry; s.rel[l][2] = rz;
    s.rel[l][3] = __int_as_float(idx);
  }
  LDSFENCE();

  // ---- P4: issue the 48-deep feature gather (stays in flight) ----
  float fv[KK];
  #pragma unroll
  for (int k = 0; k < KK; ++k) {
    int idx = __float_as_int(s.rel[k][3]);     // LDS broadcast
    fv[k] = vfeat[(size_t)idx * CC + l];       // coalesced 256B per k
  }

  // ---- P2: q = (q_in @ wq.T + bq) * d^-0.5  (lane reads own wq row, vectorized) ----
  {
    float acc = ipb[l];
    const float4* wrow = reinterpret_cast<const float4*>(ipw + (size_t)l * CC);
    #pragma unroll
    for (int j4 = 0; j4 < 16; ++j4) {
      float4 wv4 = wrow[j4];
      acc += wv4.x * s.vec[j4 * 4 + 0] + wv4.y * s.vec[j4 * 4 + 1]
           + wv4.z * s.vec[j4 * 4 + 2] + wv4.w * s.vec[j4 * 4 + 3];
    }
    s.q[l] = acc * 0.25f;
  }
  LDSFENCE();

  // ---- P3: fold q into wk: qw[h][c] = sum_d q[h*16+d]*wk[h*16+d][c] ----
  #pragma unroll
  for (int h = 0; h < HH; ++h) {
    float acc = 0.f;
    #pragma unroll
    for (int d = 0; d < DD; ++d)
      acc += s.q[h * DD + d] * ipw[(size_t)(CC + h * DD + d) * CC + l];  // coalesced
    s.qw[h][l] = acc;
  }
  if (l < HH) {
    float acc = 0.f;
    #pragma unroll
    for (int d = 0; d < DD; ++d) acc += s.q[l * DD + d] * ipb[CC + l * DD + d];
    s.qb[l] = acc;
  }

  // ---- P5: k_in = gather + relu(kpos), store bf16 ----
  #pragma unroll
  for (int k = 0; k < KK; ++k) {
    float4 r = *reinterpret_cast<const float4*>(&s.rel[k][0]);  // broadcast
    float pos = fmaxf(kw0 * r.x + kw1 * r.y + kw2 * r.z + kb, 0.f);
    s.kin[k][l] = f2bf(fv[k] + pos);
  }
  LDSFENCE();

  // ---- P6: scores + softmax ----
  float scv[HH] = {-1e9f, -1e9f, -1e9f, -1e9f};
  if (l < KK && !msk) {
    float a0 = s.qb[0], a1 = s.qb[1], a2 = s.qb[2], a3 = s.qb[3];
    const uint4* row = reinterpret_cast<const uint4*>(&s.kin[l][0]);
    #pragma unroll
    for (int c8 = 0; c8 < 8; ++c8) {
      uint4 ch = row[c8];
      float f0 = __uint_as_float(ch.x << 16), f1 = __uint_as_float(ch.x & 0xffff0000u);
      float f2 = __uint_as_float(ch.y << 16), f3 = __uint_as_float(ch.y & 0xffff0000u);
      float f4 = __uint_as_float(ch.z << 16), f5 = __uint_as_float(ch.z & 0xffff0000u);
      float f6 = __uint_as_float(ch.w << 16), f7 = __uint_as_float(ch.w & 0xffff0000u);
      #pragma unroll
      for (int h = 0; h < HH; ++h) {
        const float4 qa = *reinterpret_cast<const float4*>(&s.qw[h][c8 * 8]);
        const float4 qb4 = *reinterpret_cast<const float4*>(&s.qw[h][c8 * 8 + 4]);
        float part = qa.x * f0 + qa.y * f1 + qa.z * f2 + qa.w * f3
                   + qb4.x * f4 + qb4.y * f5 + qb4.z * f6 + qb4.w * f7;
        if (h == 0) a0 += part; else if (h == 1) a1 += part;
        else if (h == 2) a2 += part; else a3 += part;
      }
    }
    scv[0] = a0; scv[1] = a1; scv[2] = a2; scv[3] = a3;
  }
  // wave-parallel softmax over k (lanes >=48 and masked lanes hold -1e9 -> weight 0)
  float wgt[HH];
  #pragma unroll
  for (int h = 0; h < HH; ++h) {
    float v = scv[h];
    float mx = v;
    #pragma unroll
    for (int off = 32; off > 0; off >>= 1) mx = fmaxf(mx, __shfl_xor(mx, off, 64));
    float e = __expf(v - mx);
    float sm = e;
    #pragma unroll
    for (int off = 32; off > 0; off >>= 1) sm += __shfl_xor(sm, off, 64);
    wgt[h] = e * __builtin_amdgcn_rcpf(sm);
  }
  if (l < KK)
    *reinterpret_cast<float4*>(&s.rel[l][0]) = make_float4(wgt[0], wgt[1], wgt[2], wgt[3]);
  LDSFENCE();

  // ---- P7: t[h][c] = sum_k a[h][k] * k_in[k][c]  (lane = c) ----
  {
    float tv0 = 0.f, tv1 = 0.f, tv2 = 0.f, tv3 = 0.f;
    const float4* sc4 = reinterpret_cast<const float4*>(&s.rel[0][0]);
    #pragma unroll
    for (int k = 0; k < KK; ++k) {
      float4 a = sc4[k];                                   // broadcast
      float v = __uint_as_float(((unsigned)s.kin[k][l]) << 16);
      tv0 += a.x * v; tv1 += a.y * v; tv2 += a.z * v; tv3 += a.w * v;
    }
    float* tt = &s.qw[0][0];                               // overlay t over qw
    tt[0 * 68 + l] = tv0; tt[1 * 68 + l] = tv1;
    tt[2 * 68 + l] = tv2; tt[3 * 68 + l] = tv3;
  }
  LDSFENCE();

  // ---- P8: o[c] = wv[c]·t[h(c)] + bv[c] (lane reads own wv row) ----
  {
    const float* trow = &s.qw[0][0] + (l >> 4) * 68;
    float acc = ipb[2 * CC + l];
    const float4* wrow = reinterpret_cast<const float4*>(ipw + (size_t)(2 * CC + l) * CC);
    #pragma unroll
    for (int j4 = 0; j4 < 16; ++j4) {
      float4 wv4 = wrow[j4];
      acc += wv4.x * trow[j4 * 4 + 0] + wv4.y * trow[j4 * 4 + 1]
           + wv4.z * trow[j4 * 4 + 2] + wv4.w * trow[j4 * 4 + 3];
    }
    s.vec[l] = acc;
  }
  LDSFENCE();

  // ---- P9: attend[c] = op[c]·o + opb[c] ----
  {
    float acc = opb[l];
    const float4* wrow = reinterpret_cast<const float4*>(opw + (size_t)l * CC);
    #pragma unroll
    for (int j4 = 0; j4 < 16; ++j4) {
      float4 wv4 = wrow[j4];
      acc += wv4.x * s.vec[j4 * 4 + 0] + wv4.y * s.vec[j4 * 4 + 1]
           + wv4.z * s.vec[j4 * 4 + 2] + wv4.w * s.vec[j4 * 4 + 3];
    }
    attend[(size_t)m * CC + l] = acc;
  }
}

// ---------------- MLP chain: 32 queries per block, in-place on d_out ----------------
__global__ __launch_bounds__(256) void mlp_kernel(
    float* __restrict__ inout,
    const float* __restrict__ l1T, const float* __restrict__ l1b,
    const float* __restrict__ l2T, const float* __restrict__ l2b,
    const float* __restrict__ oT,  const float* __restrict__ ob,
    const float* __restrict__ nrm, const float* __restrict__ bn2,
    int M)
{
  const int q0 = blockIdx.x * 32;
  const int tid = threadIdx.x;
  __shared__ float s_x[32][68];
  __shared__ float s_h1[32][257];
  const int nq = min(32, M - q0);

  for (int i = tid; i < 32 * 64; i += 256) {
    int q = i >> 6, c = i & 63;
    s_x[q][c] = (q < nq) ? inout[(size_t)(q0 + q) * 64 + c] : 0.f;
  }
  __syncthreads();

  {
    float w[64];
    #pragma unroll
    for (int c = 0; c < 64; ++c) w[c] = l1T[c * 256 + tid];
    const float bf = l1b[tid];
    for (int q = 0; q < 32; ++q) {
      float acc = bf;
      const float4* a4 = reinterpret_cast<const float4*>(&s_x[q][0]);
      #pragma unroll
      for (int c4 = 0; c4 < 16; ++c4) {
        float4 v = a4[c4];
        acc += w[c4 * 4 + 0] * v.x + w[c4 * 4 + 1] * v.y + w[c4 * 4 + 2] * v.z + w[c4 * 4 + 3] * v.w;
      }
      s_h1[q][tid] = fmaxf(acc, 0.f);
    }
  }
  __syncthreads();

  {
    const int cq = tid & 15, qg = tid >> 4;
    const int c0 = cq * 4;
    const int qA = qg * 2, qB = qg * 2 + 1;
    float acc[4][2];
    #pragma unroll
    for (int i = 0; i < 4; ++i) { acc[i][0] = 0.f; acc[i][1] = 0.f; }
    #pragma unroll 4
    for (int f = 0; f < 256; ++f) {
      const float4 w4 = *reinterpret_cast<const float4*>(&l2T[f * 64 + c0]);
      const float hA = s_h1[qA][f];
      const float hB = s_h1[qB][f];
      acc[0][0] += w4.x * hA; acc[0][1] += w4.x * hB;
      acc[1][0] += w4.y * hA; acc[1][1] += w4.y * hB;
      acc[2][0] += w4.z * hA; acc[2][1] += w4.z * hB;
      acc[3][0] += w4.w * hA; acc[3][1] += w4.w * hB;
    }
    #pragma unroll
    for (int i = 0; i < 4; ++i) {
      const int c = c0 + i;
      const float sN = nrm[c], t2 = nrm[64 + c], b = l2b[c];
      float xA = s_x[qA][c] + acc[i][0] + b;
      float xB = s_x[qB][c] + acc[i][1] + b;
      s_x[qA][c] = xA * sN + t2;
      s_x[qB][c] = xB * sN + t2;
    }
  }
  __syncthreads();

  {
    const int cq = tid & 15, qg = tid >> 4;
    const int co0 = cq * 4;
    const int qA = qg * 2, qB = qg * 2 + 1;
    float acc[4][2];
    #pragma unroll
    for (int i = 0; i < 4; ++i) { acc[i][0] = 0.f; acc[i][1] = 0.f; }
    #pragma unroll 4
    for (int c = 0; c < 64; ++c) {
      const float4 w4 = *reinterpret_cast<const float4*>(&oT[c * 64 + co0]);
      const float xA = s_x[qA][c];
      const float xB = s_x[qB][c];
      acc[0][0] += w4.x * xA; acc[0][1] += w4.x * xB;
      acc[1][0] += w4.y * xA; acc[1][1] += w4.y * xB;
      acc[2][0] += w4.z * xA; acc[2][1] += w4.z * xB;
      acc[3][0] += w4.w * xA; acc[3][1] += w4.w * xB;
    }
    #pragma unroll
    for (int j = 0; j < 2; ++j) {
      const int q = (j == 0) ? qA : qB;
      if (q < nq) {
        float4 y;
        y.x = fmaxf((acc[0][j] + ob[co0 + 0]) * bn2[co0 + 0] + bn2[64 + co0 + 0], 0.f);
        y.y = fmaxf((acc[1][j] + ob[co0 + 1]) * bn2[co0 + 1] + bn2[64 + co0 + 1], 0.f);
        y.z = fmaxf((acc[2][j] + ob[co0 + 2]) * bn2[co0 + 2] + bn2[64 + co0 + 2], 0.f);
        y.w = fmaxf((acc[3][j] + ob[co0 + 3]) * bn2[co0 + 3] + bn2[64 + co0 + 3], 0.f);
        *reinterpret_cast<float4*>(&inout[(size_t)(q0 + q) * 64 + co0]) = y;
      }
    }
  }
}

extern "C" void kernel_launch(void* const* d_in, const int* in_sizes, int n_in,
                              void* d_out, int out_size, void* d_ws, size_t ws_size,
                              hipStream_t stream) {
  const float* vfeat  = (const float*)d_in[0];
  const float* vcoord = (const float*)d_in[1];
  const float* qcoord = (const float*)d_in[2];
  const int*   kidx   = (const int*)d_in[3];
  const unsigned char* km8  = (const unsigned char*)d_in[4];
  const int*           km32 = (const int*)d_in[4];
  const float* qpw = (const float*)d_in[5];
  const float* qpb = (const float*)d_in[6];
  const float* kpw = (const float*)d_in[7];
  const float* kpb = (const float*)d_in[8];
  const float* ipw = (const float*)d_in[9];
  const float* ipb = (const float*)d_in[10];
  const float* opw = (const float*)d_in[11];
  const float* opb = (const float*)d_in[12];
  const float* l1w = (const float*)d_in[13];
  const float* l1b = (const float*)d_in[14];
  const float* l2w = (const float*)d_in[15];
  const float* l2b = (const float*)d_in[16];
  const float* ng  = (const float*)d_in[17];
  const float* nb  = (const float*)d_in[18];
  const float* nm  = (const float*)d_in[19];
  const float* nv  = (const float*)d_in[20];
  const float* ow  = (const float*)d_in[21];
  const float* ob  = (const float*)d_in[22];
  const float* b2g = (const float*)d_in[23];
  const float* b2b = (const float*)d_in[24];
  const float* b2m = (const float*)d_in[25];
  const float* b2v = (const float*)d_in[26];

  const int M = in_sizes[2] / 3;
  float* ws  = (float*)d_ws;
  float* out = (float*)d_out;
  int* flag = (int*)(ws + WS_FLAG);

  detect_mask_kernel<<<1, 256, 0, stream>>>(km8, flag);
  prep_kernel<<<193, 256, 0, stream>>>(ipw, opw, l1w, l2w, ow,
                                       ng, nb, nm, nv, b2g, b2b, b2m, b2v, ws);
  attn_kernel<<<(M + QPB - 1) / QPB, 256, 0, stream>>>(
      vfeat, vcoord, qcoord, kidx, km8, km32, flag,
      qpw, qpb, kpw, kpb, ipw, ipb, opw, opb, out, M);
  mlp_kernel<<<(M + 31) / 32, 256, 0, stream>>>(out,
                                                ws + 12288, l1b,
                                                ws + 28672, l2b,
                                                ws + 45056, ob,
                                                ws + 49152, ws + 49280, M);
}

// Round 4
// 258.587 us; speedup vs baseline: 1.4921x; 1.4921x over previous
//
#include <hip/hip_runtime.h>
#include <math.h>

#define CC 64
#define KK 48
#define HH 4
#define DD 16
#define FF 256

#define WS_FLAG 49408

// Single-wave-per-block attention state, 9296 B -> ~16 blocks/CU.
struct __align__(16) QState {
  unsigned short kin[KK][72];  // bf16 k_in; row stride 144 B (16B-aligned, bank-rotating)
  float rel[KK][4];            // xyz rel + idx bits; later overlaid by softmax weights
  float vec[CC];               // q_in, later o
  float q[CC];
  float qw[HH][68];            // folded q·wk; later overlaid by t[4][68]
  float qb[HH];
};

__device__ __forceinline__ unsigned short f2bf(float f) {
  unsigned u = __float_as_uint(f);
  unsigned r = (u + 0x7fffu + ((u >> 16) & 1u)) >> 16;  // RNE
  return (unsigned short)r;
}

// ---------------- mask dtype detection ----------------
__global__ __launch_bounds__(256) void detect_mask_kernel(
    const unsigned char* __restrict__ km, int* __restrict__ flag)
{
  int any = 0;
  for (int i = threadIdx.x; i < 4096; i += 256)
    if ((i & 3) && km[i]) any = 1;
  __shared__ int s;
  if (threadIdx.x == 0) s = 0;
  __syncthreads();
  if (any) atomicOr(&s, 1);
  __syncthreads();
  if (threadIdx.x == 0) *flag = s;
}

// ---------------- prep: transposes + BN folds into d_ws (mlp consumables) ----------------
__global__ __launch_bounds__(256) void prep_kernel(
    const float* __restrict__ l1w, const float* __restrict__ l2w,
    const float* __restrict__ ow,
    const float* __restrict__ ng, const float* __restrict__ nb,
    const float* __restrict__ nm, const float* __restrict__ nv,
    const float* __restrict__ b2g, const float* __restrict__ b2b,
    const float* __restrict__ b2m, const float* __restrict__ b2v,
    float* __restrict__ ws)
{
  int t = blockIdx.x * 256 + threadIdx.x;
  float* l1T = ws + 12288;
  float* l2T = ws + 28672;
  float* oT  = ws + 45056;
  float* nrm = ws + 49152;
  float* bn2 = ws + 49280;
  if (t >= 12288 && t < 28672) { int i = t - 12288; int c = i >> 8, f = i & 255; l1T[i] = l1w[f * CC + c]; }
  else if (t >= 28672 && t < 45056) { int i = t - 28672; int f = i >> 6, c = i & 63; l2T[i] = l2w[c * FF + f]; }
  else if (t >= 45056 && t < 49152) { int i = t - 45056; int c = i >> 6, co = i & 63; oT[i] = ow[co * CC + c]; }
  else if (t >= 49152 && t < 49216) { int c = t - 49152; float s = ng[c] / sqrtf(nv[c] + 1e-5f); nrm[c] = s; nrm[64 + c] = nb[c] - nm[c] * s; }
  else if (t >= 49216 && t < 49280) { int c = t - 49216; float s = b2g[c] / sqrtf(b2v[c] + 1e-5f); bn2[c] = s; bn2[64 + c] = b2b[c] - b2m[c] * s; }
}

// ---------------- attention: one 64-thread (single-wave) block per query ----------------
// __syncthreads in a single-wave workgroup costs only a waitcnt; the compiler
// keeps full freedom to pipeline the gather loads (round-2 behavior) while
// bf16 LDS halves the footprint -> ~16 blocks/CU.
__global__ __launch_bounds__(64, 4) void attn_kernel(
    const float* __restrict__ vfeat, const float* __restrict__ vcoord,
    const float* __restrict__ qcoord, const int* __restrict__ kidx,
    const unsigned char* __restrict__ km8, const int* __restrict__ km32,
    const int* __restrict__ maskfmt,
    const float* __restrict__ qpw, const float* __restrict__ qpb,
    const float* __restrict__ kpw, const float* __restrict__ kpb,
    const float* __restrict__ ipw, const float* __restrict__ ipb,
    const float* __restrict__ opw, const float* __restrict__ opb,
    float* __restrict__ attend)
{
  __shared__ QState s;
  const int m = blockIdx.x;
  const int l = threadIdx.x;
  const int is_u8 = *maskfmt;

  const float qx = qcoord[m * 3 + 0], qy = qcoord[m * 3 + 1], qz = qcoord[m * 3 + 2];
  const float kw0 = kpw[l * 3 + 0], kw1 = kpw[l * 3 + 1], kw2 = kpw[l * 3 + 2];
  const float kbias = kpb[l];

  // ---- P1: q_in, key indices / rel coords / mask ----
  {
    float v = qpw[l * 3 + 0] * qx + qpw[l * 3 + 1] * qy + qpw[l * 3 + 2] * qz + qpb[l];
    s.vec[l] = fmaxf(v, 0.f);
  }
  unsigned char msk = 0;
  if (l < KK) {
    int idx = kidx[m * KK + l];
    msk = is_u8 ? km8[m * KK + l] : (unsigned char)(km32[m * KK + l] != 0);
    s.rel[l][0] = vcoord[idx * 3 + 0] - qx;
    s.rel[l][1] = vcoord[idx * 3 + 1] - qy;
    s.rel[l][2] = vcoord[idx * 3 + 2] - qz;
    s.rel[l][3] = __int_as_float(idx);
  }
  __syncthreads();

  // ---- P2: q = (q_in @ wq.T + bq) * d^-0.5  (lane reads own wq row) ----
  {
    float acc = ipb[l];
    const float4* wrow = reinterpret_cast<const float4*>(ipw + (size_t)l * CC);
    #pragma unroll
    for (int j4 = 0; j4 < 16; ++j4) {
      float4 wv4 = wrow[j4];
      acc += wv4.x * s.vec[j4 * 4 + 0] + wv4.y * s.vec[j4 * 4 + 1]
           + wv4.z * s.vec[j4 * 4 + 2] + wv4.w * s.vec[j4 * 4 + 3];
    }
    s.q[l] = acc * 0.25f;
  }
  __syncthreads();

  // ---- P3: fold q into wk: qw[h][c] = sum_d q[h*16+d]*wk[h*16+d][c]  (coalesced) ----
  #pragma unroll
  for (int h = 0; h < HH; ++h) {
    float acc = 0.f;
    #pragma unroll
    for (int d = 0; d < DD; ++d)
      acc += s.q[h * DD + d] * ipw[(size_t)(CC + h * DD + d) * CC + l];
    s.qw[h][l] = acc;
  }
  if (l < HH) {
    float acc = 0.f;
    #pragma unroll
    for (int d = 0; d < DD; ++d) acc += s.q[l * DD + d] * ipb[CC + l * DD + d];
    s.qb[l] = acc;
  }

  // ---- P5: k_in = gather + relu(kpos), bf16 store; batched so ~16 loads in flight ----
  #pragma unroll
  for (int kb = 0; kb < 3; ++kb) {
    float fv[16];
    #pragma unroll
    for (int j = 0; j < 16; ++j) {
      int idx = __float_as_int(s.rel[kb * 16 + j][3]);  // LDS broadcast
      fv[j] = vfeat[(size_t)idx * CC + l];              // coalesced 256B per key
    }
    #pragma unroll
    for (int j = 0; j < 16; ++j) {
      int k = kb * 16 + j;
      float4 r = *reinterpret_cast<const float4*>(&s.rel[k][0]);
      float pos = fmaxf(kw0 * r.x + kw1 * r.y + kw2 * r.z + kbias, 0.f);
      s.kin[k][l] = f2bf(fv[j] + pos);
    }
  }
  __syncthreads();

  // ---- P6: scores (lane = key) + wave softmax ----
  float scv[HH] = {-1e9f, -1e9f, -1e9f, -1e9f};
  if (l < KK && !msk) {
    float a0 = s.qb[0], a1 = s.qb[1], a2 = s.qb[2], a3 = s.qb[3];
    const uint4* row = reinterpret_cast<const uint4*>(&s.kin[l][0]);
    #pragma unroll
    for (int c8 = 0; c8 < 8; ++c8) {
      uint4 ch = row[c8];
      float f0 = __uint_as_float(ch.x << 16), f1 = __uint_as_float(ch.x & 0xffff0000u);
      float f2 = __uint_as_float(ch.y << 16), f3 = __uint_as_float(ch.y & 0xffff0000u);
      float f4 = __uint_as_float(ch.z << 16), f5 = __uint_as_float(ch.z & 0xffff0000u);
      float f6 = __uint_as_float(ch.w << 16), f7 = __uint_as_float(ch.w & 0xffff0000u);
      #pragma unroll
      for (int h = 0; h < HH; ++h) {
        const float4 qa = *reinterpret_cast<const float4*>(&s.qw[h][c8 * 8]);
        const float4 qb4 = *reinterpret_cast<const float4*>(&s.qw[h][c8 * 8 + 4]);
        float part = qa.x * f0 + qa.y * f1 + qa.z * f2 + qa.w * f3
                   + qb4.x * f4 + qb4.y * f5 + qb4.z * f6 + qb4.w * f7;
        if (h == 0) a0 += part; else if (h == 1) a1 += part;
        else if (h == 2) a2 += part; else a3 += part;
      }
    }
    scv[0] = a0; scv[1] = a1; scv[2] = a2; scv[3] = a3;
  }
  float wgt[HH];
  #pragma unroll
  for (int h = 0; h < HH; ++h) {
    float v = scv[h];
    float mx = v;
    #pragma unroll
    for (int off = 32; off > 0; off >>= 1) mx = fmaxf(mx, __shfl_xor(mx, off, 64));
    float e = __expf(v - mx);
    float sm = e;
    #pragma unroll
    for (int off = 32; off > 0; off >>= 1) sm += __shfl_xor(sm, off, 64);
    wgt[h] = e / sm;
  }
  __syncthreads();                      // qw reads done -> safe to overlay below
  if (l < KK)
    *reinterpret_cast<float4*>(&s.rel[l][0]) = make_float4(wgt[0], wgt[1], wgt[2], wgt[3]);
  __syncthreads();

  // ---- P7: t[h][c] = sum_k a[h][k] * k_in[k][c]   (lane = c; t overlays qw) ----
  {
    float tv0 = 0.f, tv1 = 0.f, tv2 = 0.f, tv3 = 0.f;
    #pragma unroll 8
    for (int k = 0; k < KK; ++k) {
      float4 a = *reinterpret_cast<const float4*>(&s.rel[k][0]);  // broadcast
      float v = __uint_as_float(((unsigned)s.kin[k][l]) << 16);
      tv0 += a.x * v; tv1 += a.y * v; tv2 += a.z * v; tv3 += a.w * v;
    }
    float* tt = &s.qw[0][0];
    tt[0 * 68 + l] = tv0; tt[1 * 68 + l] = tv1;
    tt[2 * 68 + l] = tv2; tt[3 * 68 + l] = tv3;
  }
  __syncthreads();

  // ---- P8: o[c] = wv[c]·t[h(c)] + bv[c]  (lane reads own wv row) ----
  {
    const float* trow = &s.qw[0][0] + (l >> 4) * 68;
    float acc = ipb[2 * CC + l];
    const float4* wrow = reinterpret_cast<const float4*>(ipw + (size_t)(2 * CC + l) * CC);
    #pragma unroll
    for (int j4 = 0; j4 < 16; ++j4) {
      float4 wv4 = wrow[j4];
      acc += wv4.x * trow[j4 * 4 + 0] + wv4.y * trow[j4 * 4 + 1]
           + wv4.z * trow[j4 * 4 + 2] + wv4.w * trow[j4 * 4 + 3];
    }
    s.vec[l] = acc;
  }
  __syncthreads();

  // ---- P9: attend[c] = op[c]·o + opb[c] ----
  {
    float acc = opb[l];
    const float4* wrow = reinterpret_cast<const float4*>(opw + (size_t)l * CC);
    #pragma unroll
    for (int j4 = 0; j4 < 16; ++j4) {
      float4 wv4 = wrow[j4];
      acc += wv4.x * s.vec[j4 * 4 + 0] + wv4.y * s.vec[j4 * 4 + 1]
           + wv4.z * s.vec[j4 * 4 + 2] + wv4.w * s.vec[j4 * 4 + 3];
    }
    attend[(size_t)m * CC + l] = acc;
  }
}

// ---------------- MLP chain: 32 queries per block, in-place on d_out ----------------
__global__ __launch_bounds__(256) void mlp_kernel(
    float* __restrict__ inout,
    const float* __restrict__ l1T, const float* __restrict__ l1b,
    const float* __restrict__ l2T, const float* __restrict__ l2b,
    const float* __restrict__ oT,  const float* __restrict__ ob,
    const float* __restrict__ nrm, const float* __restrict__ bn2,
    int M)
{
  const int q0 = blockIdx.x * 32;
  const int tid = threadIdx.x;
  __shared__ float s_x[32][68];
  __shared__ float s_h1[32][257];
  const int nq = min(32, M - q0);

  for (int i = tid; i < 32 * 64; i += 256) {
    int q = i >> 6, c = i & 63;
    s_x[q][c] = (q < nq) ? inout[(size_t)(q0 + q) * 64 + c] : 0.f;
  }
  __syncthreads();

  {
    float w[64];
    #pragma unroll
    for (int c = 0; c < 64; ++c) w[c] = l1T[c * 256 + tid];
    const float bf = l1b[tid];
    for (int q = 0; q < 32; ++q) {
      float acc = bf;
      const float4* a4 = reinterpret_cast<const float4*>(&s_x[q][0]);
      #pragma unroll
      for (int c4 = 0; c4 < 16; ++c4) {
        float4 v = a4[c4];
        acc += w[c4 * 4 + 0] * v.x + w[c4 * 4 + 1] * v.y + w[c4 * 4 + 2] * v.z + w[c4 * 4 + 3] * v.w;
      }
      s_h1[q][tid] = fmaxf(acc, 0.f);
    }
  }
  __syncthreads();

  {
    const int cq = tid & 15, qg = tid >> 4;
    const int c0 = cq * 4;
    const int qA = qg * 2, qB = qg * 2 + 1;
    float acc[4][2];
    #pragma unroll
    for (int i = 0; i < 4; ++i) { acc[i][0] = 0.f; acc[i][1] = 0.f; }
    #pragma unroll 4
    for (int f = 0; f < 256; ++f) {
      const float4 w4 = *reinterpret_cast<const float4*>(&l2T[f * 64 + c0]);
      const float hA = s_h1[qA][f];
      const float hB = s_h1[qB][f];
      acc[0][0] += w4.x * hA; acc[0][1] += w4.x * hB;
      acc[1][0] += w4.y * hA; acc[1][1] += w4.y * hB;
      acc[2][0] += w4.z * hA; acc[2][1] += w4.z * hB;
      acc[3][0] += w4.w * hA; acc[3][1] += w4.w * hB;
    }
    #pragma unroll
    for (int i = 0; i < 4; ++i) {
      const int c = c0 + i;
      const float sN = nrm[c], t2 = nrm[64 + c], b = l2b[c];
      float xA = s_x[qA][c] + acc[i][0] + b;
      float xB = s_x[qB][c] + acc[i][1] + b;
      s_x[qA][c] = xA * sN + t2;
      s_x[qB][c] = xB * sN + t2;
    }
  }
  __syncthreads();

  {
    const int cq = tid & 15, qg = tid >> 4;
    const int co0 = cq * 4;
    const int qA = qg * 2, qB = qg * 2 + 1;
    float acc[4][2];
    #pragma unroll
    for (int i = 0; i < 4; ++i) { acc[i][0] = 0.f; acc[i][1] = 0.f; }
    #pragma unroll 4
    for (int c = 0; c < 64; ++c) {
      const float4 w4 = *reinterpret_cast<const float4*>(&oT[c * 64 + co0]);
      const float xA = s_x[qA][c];
      const float xB = s_x[qB][c];
      acc[0][0] += w4.x * xA; acc[0][1] += w4.x * xB;
      acc[1][0] += w4.y * xA; acc[1][1] += w4.y * xB;
      acc[2][0] += w4.z * xA; acc[2][1] += w4.z * xB;
      acc[3][0] += w4.w * xA; acc[3][1] += w4.w * xB;
    }
    #pragma unroll
    for (int j = 0; j < 2; ++j) {
      const int q = (j == 0) ? qA : qB;
      if (q < nq) {
        float4 y;
        y.x = fmaxf((acc[0][j] + ob[co0 + 0]) * bn2[co0 + 0] + bn2[64 + co0 + 0], 0.f);
        y.y = fmaxf((acc[1][j] + ob[co0 + 1]) * bn2[co0 + 1] + bn2[64 + co0 + 1], 0.f);
        y.z = fmaxf((acc[2][j] + ob[co0 + 2]) * bn2[co0 + 2] + bn2[64 + co0 + 2], 0.f);
        y.w = fmaxf((acc[3][j] + ob[co0 + 3]) * bn2[co0 + 3] + bn2[64 + co0 + 3], 0.f);
        *reinterpret_cast<float4*>(&inout[(size_t)(q0 + q) * 64 + co0]) = y;
      }
    }
  }
}

extern "C" void kernel_launch(void* const* d_in, const int* in_sizes, int n_in,
                              void* d_out, int out_size, void* d_ws, size_t ws_size,
                              hipStream_t stream) {
  const float* vfeat  = (const float*)d_in[0];
  const float* vcoord = (const float*)d_in[1];
  const float* qcoord = (const float*)d_in[2];
  const int*   kidx   = (const int*)d_in[3];
  const unsigned char* km8  = (const unsigned char*)d_in[4];
  const int*           km32 = (const int*)d_in[4];
  const float* qpw = (const float*)d_in[5];
  const float* qpb = (const float*)d_in[6];
  const float* kpw = (const float*)d_in[7];
  const float* kpb = (const float*)d_in[8];
  const float* ipw = (const float*)d_in[9];
  const float* ipb = (const float*)d_in[10];
  const float* opw = (const float*)d_in[11];
  const float* opb = (const float*)d_in[12];
  const float* l1w = (const float*)d_in[13];
  const float* l1b = (const float*)d_in[14];
  const float* l2w = (const float*)d_in[15];
  const float* l2b = (const float*)d_in[16];
  const float* ng  = (const float*)d_in[17];
  const float* nb  = (const float*)d_in[18];
  const float* nm  = (const float*)d_in[19];
  const float* nv  = (const float*)d_in[20];
  const float* ow  = (const float*)d_in[21];
  const float* ob  = (const float*)d_in[22];
  const float* b2g = (const float*)d_in[23];
  const float* b2b = (const float*)d_in[24];
  const float* b2m = (const float*)d_in[25];
  const float* b2v = (const float*)d_in[26];

  const int M = in_sizes[2] / 3;
  float* ws  = (float*)d_ws;
  float* out = (float*)d_out;
  int* flag = (int*)(ws + WS_FLAG);

  detect_mask_kernel<<<1, 256, 0, stream>>>(km8, flag);
  prep_kernel<<<193, 256, 0, stream>>>(l1w, l2w, ow,
                                       ng, nb, nm, nv, b2g, b2b, b2m, b2v, ws);
  attn_kernel<<<M, 64, 0, stream>>>(vfeat, vcoord, qcoord, kidx, km8, km32, flag,
                                    qpw, qpb, kpw, kpb, ipw, ipb, opw, opb, out);
  mlp_kernel<<<(M + 31) / 32, 256, 0, stream>>>(out,
                                                ws + 12288, l1b,
                                                ws + 28672, l2b,
                                                ws + 45056, ob,
                                                ws + 49152, ws + 49280, M);
}

// Round 5
// 161.751 us; speedup vs baseline: 2.3854x; 1.5987x over previous
//
#include <hip/hip_runtime.h>
#include <math.h>

#define CC 64
#define KK 48
#define HH 4
#define DD 16
#define FF 256

typedef __attribute__((ext_vector_type(8))) short s16x8;
typedef __attribute__((ext_vector_type(4))) short s16x4;
typedef __attribute__((ext_vector_type(4))) float f32x4;

// ws layout:
//  ushort view: [0,4096) opw_bf | [4096,20480) l1_bf | [20480,36864) l2_bf | [36864,40960) ow_bf
//  float view:  [20480,20608) nrm s[64],t[64] | [20608,20736) bn2 s[64],t[64] | [20736] flag
#define WSF_NRM  20480
#define WSF_BN2  20608
#define WSF_FLAG 20736

__device__ __forceinline__ unsigned short f2bf(float f) {
  unsigned u = __float_as_uint(f);
  return (unsigned short)((u + 0x7fffu + ((u >> 16) & 1u)) >> 16);  // RNE
}
__device__ __forceinline__ float bf2f(unsigned short h) {
  return __uint_as_float(((unsigned)h) << 16);
}

// ---------------- prep: bf16 weight casts + BN folds + mask-dtype detect ----------------
__global__ __launch_bounds__(256) void prep_kernel(
    const float* __restrict__ opw, const float* __restrict__ l1w,
    const float* __restrict__ l2w, const float* __restrict__ ow,
    const float* __restrict__ ng, const float* __restrict__ nb,
    const float* __restrict__ nm, const float* __restrict__ nv,
    const float* __restrict__ b2g, const float* __restrict__ b2b,
    const float* __restrict__ b2m, const float* __restrict__ b2v,
    const unsigned char* __restrict__ km,
    float* __restrict__ ws)
{
  unsigned short* wsu = (unsigned short*)ws;
  if (blockIdx.x == 161) {  // mask dtype detect: int32-bool has all bytes at i%4!=0 zero
    int any = 0;
    for (int i = threadIdx.x; i < 4096; i += 256)
      if ((i & 3) && km[i]) any = 1;
    __shared__ int sh;
    if (threadIdx.x == 0) sh = 0;
    __syncthreads();
    if (any) atomicOr(&sh, 1);
    __syncthreads();
    if (threadIdx.x == 0) ((int*)ws)[WSF_FLAG] = sh;
    return;
  }
  int e = blockIdx.x * 256 + threadIdx.x;
  if (e < 4096)       wsu[e] = f2bf(opw[e]);
  else if (e < 20480) wsu[e] = f2bf(l1w[e - 4096]);
  else if (e < 36864) wsu[e] = f2bf(l2w[e - 20480]);
  else if (e < 40960) wsu[e] = f2bf(ow[e - 36864]);
  else if (e < 41024) { int c = e - 40960; float s = ng[c] / sqrtf(nv[c] + 1e-5f);
                        ws[WSF_NRM + c] = s; ws[WSF_NRM + 64 + c] = nb[c] - nm[c] * s; }
  else if (e < 41088) { int c = e - 41024; float s = b2g[c] / sqrtf(b2v[c] + 1e-5f);
                        ws[WSF_BN2 + c] = s; ws[WSF_BN2 + 64 + c] = b2b[c] - b2m[c] * s; }
}

// ---------------- attention: one wave per query; scores via MFMA ----------------
// kin LDS layout: bf16, u16-index (k*64 + c) ^ ((k&7)<<3)  (byte XOR ((k&7)<<4), G4 swizzle)
struct __align__(16) QState {
  short kin[KK * CC];       // 6144 B, swizzled
  short qw[HH][CC];         // folded q·wk, bf16 (B-frag source)     512 B
  float rel[KK][4];         // xyz rel + idx bits                    768 B
  float a[KK][4];           // softmax weights [key][head]           768 B
  float vec[CC];            // q_in                                  256 B
  float q[CC];              //                                       256 B
  float tt[HH][68];         // t                                    1088 B
};                          // total 9792 B -> 16 blocks/CU

__global__ __launch_bounds__(64, 4) void attn_kernel(
    const float* __restrict__ vfeat, const float* __restrict__ vcoord,
    const float* __restrict__ qcoord, const int* __restrict__ kidx,
    const unsigned char* __restrict__ km8, const int* __restrict__ km32,
    const int* __restrict__ maskfmt,
    const float* __restrict__ qpw, const float* __restrict__ qpb,
    const float* __restrict__ kpw, const float* __restrict__ kpb,
    const float* __restrict__ ipw, const float* __restrict__ ipb,
    float* __restrict__ out)
{
  __shared__ QState s;
  const int m = blockIdx.x;
  const int l = threadIdx.x;
  const int is_u8 = *maskfmt;

  const float qx = qcoord[m * 3 + 0], qy = qcoord[m * 3 + 1], qz = qcoord[m * 3 + 2];
  const float kw0 = kpw[l * 3 + 0], kw1 = kpw[l * 3 + 1], kw2 = kpw[l * 3 + 2];
  const float kbias = kpb[l];

  // ---- P1: q_in, key indices / rel coords / mask ----
  {
    float v = qpw[l * 3 + 0] * qx + qpw[l * 3 + 1] * qy + qpw[l * 3 + 2] * qz + qpb[l];
    s.vec[l] = fmaxf(v, 0.f);
  }
  unsigned char msk = 0;
  if (l < KK) {
    int idx = kidx[m * KK + l];
    msk = is_u8 ? km8[m * KK + l] : (unsigned char)(km32[m * KK + l] != 0);
    s.rel[l][0] = vcoord[idx * 3 + 0] - qx;
    s.rel[l][1] = vcoord[idx * 3 + 1] - qy;
    s.rel[l][2] = vcoord[idx * 3 + 2] - qz;
    s.rel[l][3] = __int_as_float(idx);
  }
  const unsigned long long bm = __ballot(l < KK && msk);   // masked-key bitmask
  __syncthreads();

  // ---- P2: q = (q_in @ wq.T + bq) * d^-0.5 ----
  {
    float acc = ipb[l];
    const float4* wrow = reinterpret_cast<const float4*>(ipw + (size_t)l * CC);
    #pragma unroll
    for (int j4 = 0; j4 < 16; ++j4) {
      float4 wv4 = wrow[j4];
      acc += wv4.x * s.vec[j4 * 4 + 0] + wv4.y * s.vec[j4 * 4 + 1]
           + wv4.z * s.vec[j4 * 4 + 2] + wv4.w * s.vec[j4 * 4 + 3];
    }
    s.q[l] = acc * 0.25f;
  }
  __syncthreads();

  // ---- P3: fold q into wk (bf16) — key bias bk dropped: per-head constant,
  //          softmax is shift-invariant per head ----
  #pragma unroll
  for (int h = 0; h < HH; ++h) {
    float acc = 0.f;
    #pragma unroll
    for (int d = 0; d < DD; ++d)
      acc += s.q[h * DD + d] * ipw[(size_t)(CC + h * DD + d) * CC + l];
    s.qw[h][l] = (short)f2bf(acc);
  }

  // ---- P5: k_in = gather + relu(kpos), bf16 store, XOR-swizzled ----
  #pragma unroll
  for (int k = 0; k < KK; ++k) {
    int idx = __float_as_int(s.rel[k][3]);          // LDS broadcast
    float fv = vfeat[(size_t)idx * CC + l];         // coalesced 256B/key
    float4 r = *reinterpret_cast<const float4*>(&s.rel[k][0]);
    float pos = fmaxf(kw0 * r.x + kw1 * r.y + kw2 * r.z + kbias, 0.f);
    s.kin[(k * CC + l) ^ ((k & 7) << 3)] = (short)f2bf(fv + pos);
  }
  __syncthreads();

  // ---- P6: scores via MFMA.  C layout: col=lane&15 (head), row=(lane>>4)*4+reg (key) ----
  const int col = l & 15, lg = l >> 4;
  f32x4 acc0 = {0.f, 0.f, 0.f, 0.f}, acc1 = acc0, acc2 = acc0;
  #pragma unroll
  for (int kst = 0; kst < 2; ++kst) {
    const s16x8 b = *reinterpret_cast<const s16x8*>(&s.qw[col & 3][kst * 32 + lg * 8]);
    {
      int row = 0 * 16 + col;
      const s16x8 a = *reinterpret_cast<const s16x8*>(
          &s.kin[(row * CC + kst * 32 + lg * 8) ^ ((row & 7) << 3)]);
      acc0 = __builtin_amdgcn_mfma_f32_16x16x32_bf16(a, b, acc0, 0, 0, 0);
    }
    {
      int row = 1 * 16 + col;
      const s16x8 a = *reinterpret_cast<const s16x8*>(
          &s.kin[(row * CC + kst * 32 + lg * 8) ^ ((row & 7) << 3)]);
      acc1 = __builtin_amdgcn_mfma_f32_16x16x32_bf16(a, b, acc1, 0, 0, 0);
    }
    {
      int row = 2 * 16 + col;
      const s16x8 a = *reinterpret_cast<const s16x8*>(
          &s.kin[(row * CC + kst * 32 + lg * 8) ^ ((row & 7) << 3)]);
      acc2 = __builtin_amdgcn_mfma_f32_16x16x32_bf16(a, b, acc2, 0, 0, 0);
    }
  }

  // ---- softmax in C-fragment layout (lanes sharing col differ by 16/32) ----
  float sv[12];
  float mx = -INFINITY;
  #pragma unroll
  for (int mt = 0; mt < 3; ++mt) {
    #pragma unroll
    for (int r = 0; r < 4; ++r) {
      int key = mt * 16 + lg * 4 + r;
      float v = (mt == 0) ? acc0[r] : (mt == 1) ? acc1[r] : acc2[r];
      if ((bm >> key) & 1ull) v = -INFINITY;
      sv[mt * 4 + r] = v;
      mx = fmaxf(mx, v);
    }
  }
  mx = fmaxf(mx, __shfl_xor(mx, 16, 64));
  mx = fmaxf(mx, __shfl_xor(mx, 32, 64));
  float sum = 0.f;
  #pragma unroll
  for (int i = 0; i < 12; ++i) { float e = __expf(sv[i] - mx); sv[i] = e; sum += e; }
  sum += __shfl_xor(sum, 16, 64);
  sum += __shfl_xor(sum, 32, 64);
  const float inv = 1.f / sum;
  if (col < HH) {
    #pragma unroll
    for (int mt = 0; mt < 3; ++mt)
      #pragma unroll
      for (int r = 0; r < 4; ++r)
        s.a[mt * 16 + lg * 4 + r][col] = sv[mt * 4 + r] * inv;
  }
  __syncthreads();

  // ---- P7: t[h][c] = sum_k a[h][k] * k_in[k][c]   (lane = c) ----
  {
    float tv0 = 0.f, tv1 = 0.f, tv2 = 0.f, tv3 = 0.f;
    #pragma unroll 8
    for (int k = 0; k < KK; ++k) {
      float4 av = *reinterpret_cast<const float4*>(&s.a[k][0]);  // broadcast
      float v = bf2f((unsigned short)s.kin[(k * CC + l) ^ ((k & 7) << 3)]);
      tv0 += av.x * v; tv1 += av.y * v; tv2 += av.z * v; tv3 += av.w * v;
    }
    s.tt[0][l] = tv0; s.tt[1][l] = tv1; s.tt[2][l] = tv2; s.tt[3][l] = tv3;
  }
  __syncthreads();

  // ---- P8: o[c] = wv[c]·t[h(c)] + bv[c]  ->  d_out (op-proj moved to chain kernel) ----
  {
    const float* trow = &s.tt[l >> 4][0];
    float acc = ipb[2 * CC + l];
    const float4* wrow = reinterpret_cast<const float4*>(ipw + (size_t)(2 * CC + l) * CC);
    #pragma unroll
    for (int j4 = 0; j4 < 16; ++j4) {
      float4 wv4 = wrow[j4];
      acc += wv4.x * trow[j4 * 4 + 0] + wv4.y * trow[j4 * 4 + 1]
           + wv4.z * trow[j4 * 4 + 2] + wv4.w * trow[j4 * 4 + 3];
    }
    out[(size_t)m * CC + l] = acc;
  }
}

// ---------------- chain: o -> attend -> FFN -> BN -> out layer, all MFMA ----------------
// 4 waves x 16 rows each, wave-private LDS, no barriers.
__global__ __launch_bounds__(256, 2) void chain_kernel(
    float* __restrict__ inout, const unsigned short* __restrict__ wsu,
    const float* __restrict__ opb, const float* __restrict__ l1b,
    const float* __restrict__ l2b, const float* __restrict__ ob,
    const float* __restrict__ nrm, const float* __restrict__ bn2, int M)
{
  __shared__ short lds[4][5120];      // per wave: XH [16][256] @0 (XA [16][64] overlays), XB [16][64] @4096
  const int w = threadIdx.x >> 6;
  const int l = threadIdx.x & 63;
  const int col = l & 15, lg = l >> 4;
  const int r0 = blockIdx.x * 64 + w * 16;

  short* XH = &lds[w][0];
  short* XB = &lds[w][4096];
  const unsigned short* opw_bf = wsu;
  const unsigned short* l1_bf  = wsu + 4096;
  const unsigned short* l2_bf  = wsu + 20480;
  const unsigned short* ow_bf  = wsu + 36864;

  // ---- stage o (fp32 d_out) -> XA bf16 [16][64], swizzled ----
  #pragma unroll
  for (int i = 0; i < 4; ++i) {
    int row = i * 4 + lg, c0 = col * 4;
    float4 v = make_float4(0.f, 0.f, 0.f, 0.f);
    if (r0 + row < M) v = *reinterpret_cast<const float4*>(&inout[(size_t)(r0 + row) * 64 + c0]);
    s16x4 p; p[0] = (short)f2bf(v.x); p[1] = (short)f2bf(v.y);
    p[2] = (short)f2bf(v.z); p[3] = (short)f2bf(v.w);
    *reinterpret_cast<s16x4*>(&XH[(row * 64 + c0) ^ ((row & 7) << 3)]) = p;
  }

  // ---- G1: attend = o @ opw^T + opb   (K=64,N=64); keep frags, also -> XB bf16 ----
  s16x8 afa[2];
  #pragma unroll
  for (int kst = 0; kst < 2; ++kst)
    afa[kst] = *reinterpret_cast<const s16x8*>(&XH[(col * 64 + kst * 32 + lg * 8) ^ ((col & 7) << 3)]);
  f32x4 att[4];
  #pragma unroll
  for (int nt = 0; nt < 4; ++nt) {
    f32x4 acc = {0.f, 0.f, 0.f, 0.f};
    #pragma unroll
    for (int kst = 0; kst < 2; ++kst) {
      const s16x8 b = *reinterpret_cast<const s16x8*>(&opw_bf[(nt * 16 + col) * 64 + kst * 32 + lg * 8]);
      acc = __builtin_amdgcn_mfma_f32_16x16x32_bf16(afa[kst], b, acc, 0, 0, 0);
    }
    float bias = opb[nt * 16 + col];
    #pragma unroll
    for (int r = 0; r < 4; ++r) {
      acc[r] += bias;
      int row = lg * 4 + r;
      XB[(row * 64 + nt * 16 + col) ^ ((row & 7) << 3)] = (short)f2bf(acc[r]);
    }
    att[nt] = acc;
  }

  // ---- G2: h1 = relu(attend @ l1^T + l1b)   (K=64,N=256) -> XH bf16 ----
  s16x8 afb[2];
  #pragma unroll
  for (int kst = 0; kst < 2; ++kst)
    afb[kst] = *reinterpret_cast<const s16x8*>(&XB[(col * 64 + kst * 32 + lg * 8) ^ ((col & 7) << 3)]);
  #pragma unroll
  for (int nt = 0; nt < 16; ++nt) {
    f32x4 acc = {0.f, 0.f, 0.f, 0.f};
    #pragma unroll
    for (int kst = 0; kst < 2; ++kst) {
      const s16x8 b = *reinterpret_cast<const s16x8*>(&l1_bf[(nt * 16 + col) * 64 + kst * 32 + lg * 8]);
      acc = __builtin_amdgcn_mfma_f32_16x16x32_bf16(afb[kst], b, acc, 0, 0, 0);
    }
    float bias = l1b[nt * 16 + col];
    #pragma unroll
    for (int r = 0; r < 4; ++r) {
      float h = fmaxf(acc[r] + bias, 0.f);
      int row = lg * 4 + r;
      XH[(row * 256 + nt * 16 + col) ^ ((row & 7) << 3)] = (short)f2bf(h);
    }
  }

  // ---- G3: x = BN1(attend + h1 @ l2^T + l2b)   (K=256,N=64) -> XB bf16 ----
  s16x8 afh[8];
  #pragma unroll
  for (int kst = 0; kst < 8; ++kst)
    afh[kst] = *reinterpret_cast<const s16x8*>(&XH[(col * 256 + kst * 32 + lg * 8) ^ ((col & 7) << 3)]);
  #pragma unroll
  for (int nt = 0; nt < 4; ++nt) {
    f32x4 acc = {0.f, 0.f, 0.f, 0.f};
    #pragma unroll
    for (int kst = 0; kst < 8; ++kst) {
      const s16x8 b = *reinterpret_cast<const s16x8*>(&l2_bf[(nt * 16 + col) * 256 + kst * 32 + lg * 8]);
      acc = __builtin_amdgcn_mfma_f32_16x16x32_bf16(afh[kst], b, acc, 0, 0, 0);
    }
    int nc = nt * 16 + col;
    float bias = l2b[nc], sN = nrm[nc], tN = nrm[64 + nc];
    #pragma unroll
    for (int r = 0; r < 4; ++r) {
      float x = (att[nt][r] + acc[r] + bias) * sN + tN;
      int row = lg * 4 + r;
      XB[(row * 64 + nc) ^ ((row & 7) << 3)] = (short)f2bf(x);
    }
  }

  // ---- G4: y = relu(BN2(x @ ow^T + ob))   (K=64,N=64) -> d_out ----
  s16x8 afx[2];
  #pragma unroll
  for (int kst = 0; kst < 2; ++kst)
    afx[kst] = *reinterpret_cast<const s16x8*>(&XB[(col * 64 + kst * 32 + lg * 8) ^ ((col & 7) << 3)]);
  #pragma unroll
  for (int nt = 0; nt < 4; ++nt) {
    f32x4 acc = {0.f, 0.f, 0.f, 0.f};
    #pragma unroll
    for (int kst = 0; kst < 2; ++kst) {
      const s16x8 b = *reinterpret_cast<const s16x8*>(&ow_bf[(nt * 16 + col) * 64 + kst * 32 + lg * 8]);
      acc = __builtin_amdgcn_mfma_f32_16x16x32_bf16(afx[kst], b, acc, 0, 0, 0);
    }
    int nc = nt * 16 + col;
    float bias = ob[nc], sB = bn2[nc], tB = bn2[64 + nc];
    #pragma unroll
    for (int r = 0; r < 4; ++r) {
      float y = fmaxf((acc[r] + bias) * sB + tB, 0.f);
      int row = lg * 4 + r;
      if (r0 + row < M) inout[(size_t)(r0 + row) * 64 + nc] = y;
    }
  }
}

extern "C" void kernel_launch(void* const* d_in, const int* in_sizes, int n_in,
                              void* d_out, int out_size, void* d_ws, size_t ws_size,
                              hipStream_t stream) {
  const float* vfeat  = (const float*)d_in[0];
  const float* vcoord = (const float*)d_in[1];
  const float* qcoord = (const float*)d_in[2];
  const int*   kidx   = (const int*)d_in[3];
  const unsigned char* km8  = (const unsigned char*)d_in[4];
  const int*           km32 = (const int*)d_in[4];
  const float* qpw = (const float*)d_in[5];
  const float* qpb = (const float*)d_in[6];
  const float* kpw = (const float*)d_in[7];
  const float* kpb = (const float*)d_in[8];
  const float* ipw = (const float*)d_in[9];
  const float* ipb = (const float*)d_in[10];
  const float* opw = (const float*)d_in[11];
  const float* opb = (const float*)d_in[12];
  const float* l1w = (const float*)d_in[13];
  const float* l1b = (const float*)d_in[14];
  const float* l2w = (const float*)d_in[15];
  const float* l2b = (const float*)d_in[16];
  const float* ng  = (const float*)d_in[17];
  const float* nb  = (const float*)d_in[18];
  const float* nm  = (const float*)d_in[19];
  const float* nv  = (const float*)d_in[20];
  const float* ow  = (const float*)d_in[21];
  const float* ob  = (const float*)d_in[22];
  const float* b2g = (const float*)d_in[23];
  const float* b2b = (const float*)d_in[24];
  const float* b2m = (const float*)d_in[25];
  const float* b2v = (const float*)d_in[26];

  const int M = in_sizes[2] / 3;
  float* ws  = (float*)d_ws;
  float* out = (float*)d_out;
  const int* flag = (const int*)(ws + WSF_FLAG);
  const unsigned short* wsu = (const unsigned short*)ws;

  prep_kernel<<<162, 256, 0, stream>>>(opw, l1w, l2w, ow,
                                       ng, nb, nm, nv, b2g, b2b, b2m, b2v, km8, ws);
  attn_kernel<<<M, 64, 0, stream>>>(vfeat, vcoord, qcoord, kidx, km8, km32, flag,
                                    qpw, qpb, kpw, kpb, ipw, ipb, out);
  chain_kernel<<<(M + 63) / 64, 256, 0, stream>>>(out, wsu, opb, l1b, l2b, ob,
                                                  ws + WSF_NRM, ws + WSF_BN2, M);
}

// Round 6
// 154.504 us; speedup vs baseline: 2.4973x; 1.0469x over previous
//
#include <hip/hip_runtime.h>
#include <math.h>

#define CC 64
#define KK 48
#define HH 4

typedef __attribute__((ext_vector_type(8))) short s16x8;
typedef __attribute__((ext_vector_type(4))) short s16x4;
typedef __attribute__((ext_vector_type(4))) float f32x4;

// ws u16 layout: [0,4096) wq_bf [c][j] | [4096,8192) wkT_bf [c][j] | [8192,12288) opw_bf
//                [12288,28672) l1_bf | [28672,45056) l2_bf | [45056,49152) ow_bf
// ws f32 layout: [24576,24704) nrm s,t | [24704,24832) bn2 s,t | [24832] flag(int)

// round-half-up f32 -> bf16 (2 ops; bias vs RNE negligible here)
__device__ __forceinline__ unsigned short f2bf(float f) {
  return (unsigned short)((__float_as_uint(f) + 0x8000u) >> 16);
}

// ---------------- prep: bf16 weight casts/transposes + BN folds + mask detect ----------------
__global__ __launch_bounds__(256) void prep_kernel(
    const float* __restrict__ ipw, const float* __restrict__ opw,
    const float* __restrict__ l1w, const float* __restrict__ l2w,
    const float* __restrict__ ow,
    const float* __restrict__ ng, const float* __restrict__ nb,
    const float* __restrict__ nm, const float* __restrict__ nv,
    const float* __restrict__ b2g, const float* __restrict__ b2b,
    const float* __restrict__ b2m, const float* __restrict__ b2v,
    const unsigned char* __restrict__ km,
    float* __restrict__ ws)
{
  unsigned short* wsu = (unsigned short*)ws;
  if (blockIdx.x == 193) {  // mask dtype detect: int32-bool has all bytes at i%4!=0 zero
    int any = 0;
    for (int i = threadIdx.x; i < 4096; i += 256)
      if ((i & 3) && km[i]) any = 1;
    __shared__ int sb;
    if (threadIdx.x == 0) sb = 0;
    __syncthreads();
    if (any) atomicOr(&sb, 1);
    __syncthreads();
    if (threadIdx.x == 0) ((int*)ws)[24832] = sb;
    return;
  }
  int e = blockIdx.x * 256 + threadIdx.x;
  if (e < 4096)        wsu[e] = f2bf(ipw[e]);                                   // wq rows 0-63
  else if (e < 8192)  { int i = e - 4096; int c = i >> 6, j = i & 63;
                        wsu[e] = f2bf(ipw[(64 + j) * 64 + c]); }                // wkT[c][j]=wk[j][c]
  else if (e < 12288)  wsu[e] = f2bf(opw[e - 8192]);
  else if (e < 28672)  wsu[e] = f2bf(l1w[e - 12288]);
  else if (e < 45056)  wsu[e] = f2bf(l2w[e - 28672]);
  else if (e < 49152)  wsu[e] = f2bf(ow[e - 45056]);
  else if (e < 49216) { int c = e - 49152; float s = ng[c] / sqrtf(nv[c] + 1e-5f);
                        ws[24576 + c] = s; ws[24576 + 64 + c] = nb[c] - nm[c] * s; }
  else if (e < 49280) { int c = e - 49216; float s = b2g[c] / sqrtf(b2v[c] + 1e-5f);
                        ws[24704 + c] = s; ws[24704 + 64 + c] = b2b[c] - b2m[c] * s; }
}

// ---------------- attention: one wave per query; all dense phases via MFMA ----------------
// LDS (u16 idx): kin [0,3072) swizzled (k*64+c)^((k&7)<<3) | qw [3072,3328) | qbuf [3328,3392)
//   rel f32[48][4] [3392,3776) | aT bf16[4][64] [3584,3840) (overlays rel tail, post-P5)
//   tt f32[4][64] @ u16 3072 (overlays qw+qbuf+rel head, post-P6)
__global__ __launch_bounds__(64, 4) void attn_kernel(
    const float* __restrict__ vfeat, const float* __restrict__ vcoord,
    const float* __restrict__ qcoord, const int* __restrict__ kidx,
    const unsigned char* __restrict__ km8, const int* __restrict__ km32,
    const int* __restrict__ maskfmt,
    const float* __restrict__ qpw, const float* __restrict__ qpb,
    const float* __restrict__ kpw, const float* __restrict__ kpb,
    const float* __restrict__ ipw, const float* __restrict__ ipb,
    const unsigned short* __restrict__ wq_bf,
    const unsigned short* __restrict__ wkT_bf,
    float* __restrict__ out)
{
  __shared__ __align__(16) unsigned short sh[3840];
  const int m = blockIdx.x, l = threadIdx.x;
  const int col = l & 15, lg = l >> 4;
  const int is_u8 = *maskfmt;
  float* relf = (float*)sh + 1696;
  float* ttf  = (float*)sh + 1536;

  const float qx = qcoord[m * 3 + 0], qy = qcoord[m * 3 + 1], qz = qcoord[m * 3 + 2];
  const float kw0 = kpw[l * 3 + 0], kw1 = kpw[l * 3 + 1], kw2 = kpw[l * 3 + 2];
  const float kbias = kpb[l];

  // ---- P1: q_in (bf16), key rel coords / indices / mask ----
  {
    float v = qpw[l * 3 + 0] * qx + qpw[l * 3 + 1] * qy + qpw[l * 3 + 2] * qz + qpb[l];
    sh[3328 + l] = f2bf(fmaxf(v, 0.f));
  }
  unsigned char msk = 0;
  if (l < KK) {
    int idx = kidx[m * KK + l];
    msk = is_u8 ? km8[m * KK + l] : (unsigned char)(km32[m * KK + l] != 0);
    relf[l * 4 + 0] = vcoord[idx * 3 + 0] - qx;
    relf[l * 4 + 1] = vcoord[idx * 3 + 1] - qy;
    relf[l * 4 + 2] = vcoord[idx * 3 + 2] - qz;
    relf[l * 4 + 3] = __int_as_float(idx);
  }
  const unsigned long long bm = __ballot(l < KK && msk);
  __syncthreads();

  // ---- P2: q = (q_in @ wq^T + bq)*0.25 via MFMA (row 0 of C valid) ----
  f32x4 qacc[4];
  #pragma unroll
  for (int nt = 0; nt < 4; ++nt) qacc[nt] = (f32x4){0.f, 0.f, 0.f, 0.f};
  #pragma unroll
  for (int kst = 0; kst < 2; ++kst) {
    const s16x8 a = *(const s16x8*)&sh[3328 + kst * 32 + lg * 8];  // A[m][k]=qin[k] all m
    #pragma unroll
    for (int nt = 0; nt < 4; ++nt) {
      const s16x8 b = *(const s16x8*)(wq_bf + (nt * 16 + col) * 64 + kst * 32 + lg * 8);
      qacc[nt] = __builtin_amdgcn_mfma_f32_16x16x32_bf16(a, b, qacc[nt], 0, 0, 0);
    }
  }
  __syncthreads();
  if (lg == 0) {  // C[0][n] lives in lanes 0-15, reg 0
    #pragma unroll
    for (int nt = 0; nt < 4; ++nt)
      sh[3328 + nt * 16 + col] = f2bf((qacc[nt][0] + ipb[nt * 16 + col]) * 0.25f);
  }
  __syncthreads();

  // ---- P3: qw[h][c] = sum_j Qh[h][j]*wk[j][c] via MFMA (block-diag A) ----
  {
    f32x4 wacc[4];
    #pragma unroll
    for (int nt = 0; nt < 4; ++nt) wacc[nt] = (f32x4){0.f, 0.f, 0.f, 0.f};
    #pragma unroll
    for (int kst = 0; kst < 2; ++kst) {
      const int hblk = kst * 2 + (lg >> 1);   // head owning this k-slice
      s16x8 a = {0, 0, 0, 0, 0, 0, 0, 0};
      if (col == hblk) a = *(const s16x8*)&sh[3328 + kst * 32 + lg * 8];
      #pragma unroll
      for (int nt = 0; nt < 4; ++nt) {
        const s16x8 b = *(const s16x8*)(wkT_bf + (nt * 16 + col) * 64 + kst * 32 + lg * 8);
        wacc[nt] = __builtin_amdgcn_mfma_f32_16x16x32_bf16(a, b, wacc[nt], 0, 0, 0);
      }
    }
    if (lg == 0) {  // rows 0-3 = heads
      #pragma unroll
      for (int nt = 0; nt < 4; ++nt)
        #pragma unroll
        for (int r = 0; r < 4; ++r)
          sh[3072 + r * 64 + nt * 16 + col] = f2bf(wacc[nt][r]);
    }
  }

  // ---- P5: k_in = gather + relu(kpos), bf16 swizzled store ----
  #pragma unroll
  for (int k = 0; k < KK; ++k) {
    const float4 r = *(const float4*)(relf + k * 4);       // broadcast
    const float fv = vfeat[(size_t)__float_as_int(r.w) * CC + l];
    const float pos = fmaxf(kw0 * r.x + kw1 * r.y + kw2 * r.z + kbias, 0.f);
    sh[(k * 64 + l) ^ ((k & 7) << 3)] = f2bf(fv + pos);
  }
  __syncthreads();

  // ---- P6: scores via MFMA (A=kin rows, B=qw). C: row=key, col=head ----
  f32x4 sc[3];
  sc[0] = sc[1] = sc[2] = (f32x4){0.f, 0.f, 0.f, 0.f};
  #pragma unroll
  for (int kst = 0; kst < 2; ++kst) {
    const s16x8 b = *(const s16x8*)&sh[3072 + (col & 3) * 64 + kst * 32 + lg * 8];
    #pragma unroll
    for (int mt = 0; mt < 3; ++mt) {
      const int row = mt * 16 + col;
      const s16x8 a = *(const s16x8*)&sh[(row * 64 + kst * 32 + lg * 8) ^ ((row & 7) << 3)];
      sc[mt] = __builtin_amdgcn_mfma_f32_16x16x32_bf16(a, b, sc[mt], 0, 0, 0);
    }
  }

  // ---- softmax over keys, per head; write aT bf16 [h][key] (packed b64) ----
  {
    float sv[12];
    float mx = -INFINITY;
    #pragma unroll
    for (int mt = 0; mt < 3; ++mt)
      #pragma unroll
      for (int r = 0; r < 4; ++r) {
        const int key = mt * 16 + lg * 4 + r;
        float v = sc[mt][r];
        if ((bm >> key) & 1ull) v = -1e30f;
        sv[mt * 4 + r] = v;
        mx = fmaxf(mx, v);
      }
    mx = fmaxf(mx, __shfl_xor(mx, 16, 64));
    mx = fmaxf(mx, __shfl_xor(mx, 32, 64));
    float sum = 0.f;
    #pragma unroll
    for (int i = 0; i < 12; ++i) { float e = __expf(sv[i] - mx); sv[i] = e; sum += e; }
    sum += __shfl_xor(sum, 16, 64);
    sum += __shfl_xor(sum, 32, 64);
    const float inv = 1.f / sum;
    if (col < HH) {
      #pragma unroll
      for (int mt = 0; mt < 3; ++mt) {
        s16x4 p;
        #pragma unroll
        for (int r = 0; r < 4; ++r) p[r] = (short)f2bf(sv[mt * 4 + r] * inv);
        *(s16x4*)&sh[3584 + col * 64 + mt * 16 + lg * 4] = p;
      }
    }
  }
  __syncthreads();

  // ---- t-GEMM: t[h][c] = sum_k aT[h][k]*kin[k][c] via MFMA ----
  {
    f32x4 tacc[4];
    #pragma unroll
    for (int nt = 0; nt < 4; ++nt) tacc[nt] = (f32x4){0.f, 0.f, 0.f, 0.f};
    #pragma unroll
    for (int kst = 0; kst < 2; ++kst) {
      s16x8 a = {0, 0, 0, 0, 0, 0, 0, 0};   // keys>=48: BOTH operands zeroed (no 0*NaN)
      if (kst == 0 || lg < 2)
        a = *(const s16x8*)&sh[3584 + col * 64 + kst * 32 + lg * 8];
      #pragma unroll
      for (int nt = 0; nt < 4; ++nt) {
        s16x8 b = {0, 0, 0, 0, 0, 0, 0, 0};
        if (kst == 0 || lg < 2) {
          const int n = nt * 16 + col;
          #pragma unroll
          for (int j = 0; j < 8; ++j) {
            const int key = kst * 32 + lg * 8 + j;
            ((unsigned short*)&b)[j] = sh[(key * 64 + n) ^ ((key & 7) << 3)];
          }
        }
        tacc[nt] = __builtin_amdgcn_mfma_f32_16x16x32_bf16(a, b, tacc[nt], 0, 0, 0);
      }
    }
    __syncthreads();
    if (lg == 0) {  // rows 0-3 = heads -> tt f32
      #pragma unroll
      for (int nt = 0; nt < 4; ++nt)
        #pragma unroll
        for (int r = 0; r < 4; ++r)
          ttf[r * 64 + nt * 16 + col] = tacc[nt][r];
    }
  }
  __syncthreads();

  // ---- P8: o[c] = wv[c]·t[h(c)] + bv[c] -> d_out ----
  {
    const float* trow = ttf + lg * 64;
    float acc = ipb[2 * CC + l];
    const float4* wrow = (const float4*)(ipw + (size_t)(2 * CC + l) * CC);
    #pragma unroll
    for (int j4 = 0; j4 < 16; ++j4) {
      const float4 w4 = wrow[j4];
      const float4 t4 = *(const float4*)(trow + j4 * 4);
      acc += w4.x * t4.x + w4.y * t4.y + w4.z * t4.z + w4.w * t4.w;
    }
    out[(size_t)m * CC + l] = acc;
  }
}

// ---------------- chain: o -> attend -> FFN -> BN -> out layer, all MFMA ----------------
__global__ __launch_bounds__(256, 2) void chain_kernel(
    float* __restrict__ inout, const unsigned short* __restrict__ wsu,
    const float* __restrict__ opb, const float* __restrict__ l1b,
    const float* __restrict__ l2b, const float* __restrict__ ob,
    const float* __restrict__ nrm, const float* __restrict__ bn2, int M)
{
  __shared__ short lds[4][5120];
  const int w = threadIdx.x >> 6;
  const int l = threadIdx.x & 63;
  const int col = l & 15, lg = l >> 4;
  const int r0 = blockIdx.x * 64 + w * 16;

  short* XH = &lds[w][0];
  short* XB = &lds[w][4096];
  const unsigned short* opw_bf = wsu + 8192;
  const unsigned short* l1_bf  = wsu + 12288;
  const unsigned short* l2_bf  = wsu + 28672;
  const unsigned short* ow_bf  = wsu + 45056;

  #pragma unroll
  for (int i = 0; i < 4; ++i) {
    int row = i * 4 + lg, c0 = col * 4;
    float4 v = make_float4(0.f, 0.f, 0.f, 0.f);
    if (r0 + row < M) v = *(const float4*)(&inout[(size_t)(r0 + row) * 64 + c0]);
    s16x4 p; p[0] = (short)f2bf(v.x); p[1] = (short)f2bf(v.y);
    p[2] = (short)f2bf(v.z); p[3] = (short)f2bf(v.w);
    *(s16x4*)&XH[(row * 64 + c0) ^ ((row & 7) << 3)] = p;
  }

  s16x8 afa[2];
  #pragma unroll
  for (int kst = 0; kst < 2; ++kst)
    afa[kst] = *(const s16x8*)&XH[(col * 64 + kst * 32 + lg * 8) ^ ((col & 7) << 3)];
  f32x4 att[4];
  #pragma unroll
  for (int nt = 0; nt < 4; ++nt) {
    f32x4 acc = {0.f, 0.f, 0.f, 0.f};
    #pragma unroll
    for (int kst = 0; kst < 2; ++kst) {
      const s16x8 b = *(const s16x8*)&opw_bf[(nt * 16 + col) * 64 + kst * 32 + lg * 8];
      acc = __builtin_amdgcn_mfma_f32_16x16x32_bf16(afa[kst], b, acc, 0, 0, 0);
    }
    float bias = opb[nt * 16 + col];
    #pragma unroll
    for (int r = 0; r < 4; ++r) {
      acc[r] += bias;
      int row = lg * 4 + r;
      XB[(row * 64 + nt * 16 + col) ^ ((row & 7) << 3)] = (short)f2bf(acc[r]);
    }
    att[nt] = acc;
  }

  s16x8 afb[2];
  #pragma unroll
  for (int kst = 0; kst < 2; ++kst)
    afb[kst] = *(const s16x8*)&XB[(col * 64 + kst * 32 + lg * 8) ^ ((col & 7) << 3)];
  #pragma unroll
  for (int nt = 0; nt < 16; ++nt) {
    f32x4 acc = {0.f, 0.f, 0.f, 0.f};
    #pragma unroll
    for (int kst = 0; kst < 2; ++kst) {
      const s16x8 b = *(const s16x8*)&l1_bf[(nt * 16 + col) * 64 + kst * 32 + lg * 8];
      acc = __builtin_amdgcn_mfma_f32_16x16x32_bf16(afb[kst], b, acc, 0, 0, 0);
    }
    float bias = l1b[nt * 16 + col];
    #pragma unroll
    for (int r = 0; r < 4; ++r) {
      float h = fmaxf(acc[r] + bias, 0.f);
      int row = lg * 4 + r;
      XH[(row * 256 + nt * 16 + col) ^ ((row & 7) << 3)] = (short)f2bf(h);
    }
  }

  s16x8 afh[8];
  #pragma unroll
  for (int kst = 0; kst < 8; ++kst)
    afh[kst] = *(const s16x8*)&XH[(col * 256 + kst * 32 + lg * 8) ^ ((col & 7) << 3)];
  #pragma unroll
  for (int nt = 0; nt < 4; ++nt) {
    f32x4 acc = {0.f, 0.f, 0.f, 0.f};
    #pragma unroll
    for (int kst = 0; kst < 8; ++kst) {
      const s16x8 b = *(const s16x8*)&l2_bf[(nt * 16 + col) * 256 + kst * 32 + lg * 8];
      acc = __builtin_amdgcn_mfma_f32_16x16x32_bf16(afh[kst], b, acc, 0, 0, 0);
    }
    int nc = nt * 16 + col;
    float bias = l2b[nc], sN = nrm[nc], tN = nrm[64 + nc];
    #pragma unroll
    for (int r = 0; r < 4; ++r) {
      float x = (att[nt][r] + acc[r] + bias) * sN + tN;
      int row = lg * 4 + r;
      XB[(row * 64 + nc) ^ ((row & 7) << 3)] = (short)f2bf(x);
    }
  }

  s16x8 afx[2];
  #pragma unroll
  for (int kst = 0; kst < 2; ++kst)
    afx[kst] = *(const s16x8*)&XB[(col * 64 + kst * 32 + lg * 8) ^ ((col & 7) << 3)];
  #pragma unroll
  for (int nt = 0; nt < 4; ++nt) {
    f32x4 acc = {0.f, 0.f, 0.f, 0.f};
    #pragma unroll
    for (int kst = 0; kst < 2; ++kst) {
      const s16x8 b = *(const s16x8*)&ow_bf[(nt * 16 + col) * 64 + kst * 32 + lg * 8];
      acc = __builtin_amdgcn_mfma_f32_16x16x32_bf16(afx[kst], b, acc, 0, 0, 0);
    }
    int nc = nt * 16 + col;
    float bias = ob[nc], sB = bn2[nc], tB = bn2[64 + nc];
    #pragma unroll
    for (int r = 0; r < 4; ++r) {
      float y = fmaxf((acc[r] + bias) * sB + tB, 0.f);
      int row = lg * 4 + r;
      if (r0 + row < M) inout[(size_t)(r0 + row) * 64 + nc] = y;
    }
  }
}

extern "C" void kernel_launch(void* const* d_in, const int* in_sizes, int n_in,
                              void* d_out, int out_size, void* d_ws, size_t ws_size,
                              hipStream_t stream) {
  const float* vfeat  = (const float*)d_in[0];
  const float* vcoord = (const float*)d_in[1];
  const float* qcoord = (const float*)d_in[2];
  const int*   kidx   = (const int*)d_in[3];
  const unsigned char* km8  = (const unsigned char*)d_in[4];
  const int*           km32 = (const int*)d_in[4];
  const float* qpw = (const float*)d_in[5];
  const float* qpb = (const float*)d_in[6];
  const float* kpw = (const float*)d_in[7];
  const float* kpb = (const float*)d_in[8];
  const float* ipw = (const float*)d_in[9];
  const float* ipb = (const float*)d_in[10];
  const float* opw = (const float*)d_in[11];
  const float* opb = (const float*)d_in[12];
  const float* l1w = (const float*)d_in[13];
  const float* l1b = (const float*)d_in[14];
  const float* l2w = (const float*)d_in[15];
  const float* l2b = (const float*)d_in[16];
  const float* ng  = (const float*)d_in[17];
  const float* nb  = (const float*)d_in[18];
  const float* nm  = (const float*)d_in[19];
  const float* nv  = (const float*)d_in[20];
  const float* ow  = (const float*)d_in[21];
  const float* ob  = (const float*)d_in[22];
  const float* b2g = (const float*)d_in[23];
  const float* b2b = (const float*)d_in[24];
  const float* b2m = (const float*)d_in[25];
  const float* b2v = (const float*)d_in[26];

  const int M = in_sizes[2] / 3;
  float* ws  = (float*)d_ws;
  float* out = (float*)d_out;
  const unsigned short* wsu = (const unsigned short*)ws;
  const int* flag = (const int*)ws + 24832;

  prep_kernel<<<194, 256, 0, stream>>>(ipw, opw, l1w, l2w, ow,
                                       ng, nb, nm, nv, b2g, b2b, b2m, b2v, km8, ws);
  attn_kernel<<<M, 64, 0, stream>>>(vfeat, vcoord, qcoord, kidx, km8, km32, flag,
                                    qpw, qpb, kpw, kpb, ipw, ipb,
                                    wsu /*wq_bf*/, wsu + 4096 /*wkT_bf*/, out);
  chain_kernel<<<(M + 63) / 64, 256, 0, stream>>>(out, wsu, opb, l1b, l2b, ob,
                                                  ws + 24576, ws + 24704, M);
}

// Round 7
// 122.764 us; speedup vs baseline: 3.1429x; 1.2585x over previous
//
#include <hip/hip_runtime.h>
#include <math.h>

#define CC 64
#define KK 48
#define HH 4

typedef __attribute__((ext_vector_type(8))) short s16x8;
typedef __attribute__((ext_vector_type(4))) short s16x4;
typedef __attribute__((ext_vector_type(4))) float f32x4;

// ws u16 layout: [0,4096) wq_bf | [4096,8192) wkT_bf | [8192,12288) wv_bf
//   [12288,16384) opw_bf | [16384,32768) l1_bf | [32768,49152) l2_bf | [49152,53248) ow_bf
// ws f32 layout: [26624,26752) nrm s,t | [26752,26880) bn2 s,t | [26880] flag(int)

__device__ __forceinline__ unsigned short f2bf(float f) {
  return (unsigned short)((__float_as_uint(f) + 0x8000u) >> 16);  // round-half-up
}

// ---------------- prep: bf16 weight casts/transposes + BN folds + mask detect ----------------
__global__ __launch_bounds__(256) void prep_kernel(
    const float* __restrict__ ipw, const float* __restrict__ opw,
    const float* __restrict__ l1w, const float* __restrict__ l2w,
    const float* __restrict__ ow,
    const float* __restrict__ ng, const float* __restrict__ nb,
    const float* __restrict__ nm, const float* __restrict__ nv,
    const float* __restrict__ b2g, const float* __restrict__ b2b,
    const float* __restrict__ b2m, const float* __restrict__ b2v,
    const unsigned char* __restrict__ km,
    float* __restrict__ ws)
{
  unsigned short* wsu = (unsigned short*)ws;
  if (blockIdx.x == 209) {  // mask dtype detect: int32-bool has all bytes at i%4!=0 zero
    int any = 0;
    for (int i = threadIdx.x; i < 4096; i += 256)
      if ((i & 3) && km[i]) any = 1;
    __shared__ int sb;
    if (threadIdx.x == 0) sb = 0;
    __syncthreads();
    if (any) atomicOr(&sb, 1);
    __syncthreads();
    if (threadIdx.x == 0) ((int*)ws)[26880] = sb;
    return;
  }
  int e = blockIdx.x * 256 + threadIdx.x;
  if (e < 4096)        wsu[e] = f2bf(ipw[e]);                      // wq rows 0-63
  else if (e < 8192)  { int i = e - 4096; int c = i >> 6, j = i & 63;
                        wsu[e] = f2bf(ipw[(64 + j) * 64 + c]); }   // wkT[c][j]=wk[j][c]
  else if (e < 12288)  wsu[e] = f2bf(ipw[e]);                      // wv rows 128-191 (8192+i)
  else if (e < 16384)  wsu[e] = f2bf(opw[e - 12288]);
  else if (e < 32768)  wsu[e] = f2bf(l1w[e - 16384]);
  else if (e < 49152)  wsu[e] = f2bf(l2w[e - 32768]);
  else if (e < 53248)  wsu[e] = f2bf(ow[e - 49152]);
  else if (e < 53312) { int c = e - 53248; float s = ng[c] / sqrtf(nv[c] + 1e-5f);
                        ws[26624 + c] = s; ws[26624 + 64 + c] = nb[c] - nm[c] * s; }
  else if (e < 53376) { int c = e - 53312; float s = b2g[c] / sqrtf(b2v[c] + 1e-5f);
                        ws[26752 + c] = s; ws[26752 + 64 + c] = b2b[c] - b2m[c] * s; }
}

// ---------------- attention: one wave per query ----------------
// LDS (u16 idx): kin [0,3072) swizzled (k*64+c)^((k&7)<<3) | qw [3072,3328)
//   qbuf [3328,3392) | rel f32[48][4] @u16 [3392,3776).  Total 7552 B.
__global__ __launch_bounds__(64, 4) void attn_kernel(
    const float* __restrict__ vfeat, const float* __restrict__ vcoord,
    const float* __restrict__ qcoord, const int* __restrict__ kidx,
    const unsigned char* __restrict__ km8, const int* __restrict__ km32,
    const int* __restrict__ maskfmt,
    const float* __restrict__ qpw, const float* __restrict__ qpb,
    const float* __restrict__ kpw, const float* __restrict__ kpb,
    const float* __restrict__ ipb,
    const unsigned short* __restrict__ wq_bf,
    const unsigned short* __restrict__ wkT_bf,
    const unsigned short* __restrict__ wv_bf,
    float* __restrict__ out)
{
  __shared__ __align__(16) unsigned short sh[3776];
  const int m = blockIdx.x, l = threadIdx.x;
  const int col = l & 15, lg = l >> 4;
  const int is_u8 = *maskfmt;
  float* relf = (float*)sh + 1696;   // u16 3392

  const float qx = qcoord[m * 3 + 0], qy = qcoord[m * 3 + 1], qz = qcoord[m * 3 + 2];
  // per-lane k_pos weights for 4 channels c0..c0+3 (3 float4 = channels' 12 weights)
  const int c0 = col * 4;
  const float4 kwA = *(const float4*)(kpw + c0 * 3);
  const float4 kwB = *(const float4*)(kpw + c0 * 3 + 4);
  const float4 kwC = *(const float4*)(kpw + c0 * 3 + 8);
  const float4 kbv = *(const float4*)(kpb + c0);

  // ---- P1: q_in (bf16), key rel coords / indices / mask ----
  {
    float v = qpw[l * 3 + 0] * qx + qpw[l * 3 + 1] * qy + qpw[l * 3 + 2] * qz + qpb[l];
    sh[3328 + l] = f2bf(fmaxf(v, 0.f));
  }
  unsigned char msk = 0;
  if (l < KK) {
    int idx = kidx[m * KK + l];
    msk = is_u8 ? km8[m * KK + l] : (unsigned char)(km32[m * KK + l] != 0);
    relf[l * 4 + 0] = vcoord[idx * 3 + 0] - qx;
    relf[l * 4 + 1] = vcoord[idx * 3 + 1] - qy;
    relf[l * 4 + 2] = vcoord[idx * 3 + 2] - qz;
    relf[l * 4 + 3] = __int_as_float(idx);
  }
  const unsigned long long bm = __ballot(l < KK && msk);
  __syncthreads();

  // ---- P2: q = (q_in @ wq^T + bq)*0.25 via MFMA (row 0 of C valid) ----
  {
    f32x4 qacc[4];
    #pragma unroll
    for (int nt = 0; nt < 4; ++nt) qacc[nt] = (f32x4){0.f, 0.f, 0.f, 0.f};
    #pragma unroll
    for (int kst = 0; kst < 2; ++kst) {
      const s16x8 a = *(const s16x8*)&sh[3328 + kst * 32 + lg * 8];
      #pragma unroll
      for (int nt = 0; nt < 4; ++nt) {
        const s16x8 b = *(const s16x8*)(wq_bf + (nt * 16 + col) * 64 + kst * 32 + lg * 8);
        qacc[nt] = __builtin_amdgcn_mfma_f32_16x16x32_bf16(a, b, qacc[nt], 0, 0, 0);
      }
    }
    __syncthreads();
    if (lg == 0) {
      #pragma unroll
      for (int nt = 0; nt < 4; ++nt)
        sh[3328 + nt * 16 + col] = f2bf((qacc[nt][0] + ipb[nt * 16 + col]) * 0.25f);
    }
  }
  __syncthreads();

  // ---- P3: qw[h][c] = sum_j Qh[h][j]*wk[j][c] via MFMA (block-diag A); bk dropped ----
  {
    f32x4 wacc[4];
    #pragma unroll
    for (int nt = 0; nt < 4; ++nt) wacc[nt] = (f32x4){0.f, 0.f, 0.f, 0.f};
    #pragma unroll
    for (int kst = 0; kst < 2; ++kst) {
      const int hblk = kst * 2 + (lg >> 1);
      s16x8 a = {0, 0, 0, 0, 0, 0, 0, 0};
      if (col == hblk) a = *(const s16x8*)&sh[3328 + kst * 32 + lg * 8];
      #pragma unroll
      for (int nt = 0; nt < 4; ++nt) {
        const s16x8 b = *(const s16x8*)(wkT_bf + (nt * 16 + col) * 64 + kst * 32 + lg * 8);
        wacc[nt] = __builtin_amdgcn_mfma_f32_16x16x32_bf16(a, b, wacc[nt], 0, 0, 0);
      }
    }
    if (lg == 0) {
      #pragma unroll
      for (int nt = 0; nt < 4; ++nt)
        #pragma unroll
        for (int r = 0; r < 4; ++r)
          sh[3072 + r * 64 + nt * 16 + col] = f2bf(wacc[nt][r]);
    }
  }

  // ---- P5: k_in gather, 4-wide: lane (col,lg) covers channels c0..c0+3 of key it*4+lg ----
  #pragma unroll
  for (int half = 0; half < 2; ++half) {
    float4 ra[6], va[6];
    #pragma unroll
    for (int j = 0; j < 6; ++j) {
      const int k = half * 24 + j * 4 + lg;
      ra[j] = *(const float4*)(relf + k * 4);                       // broadcast per lg-group
      va[j] = *(const float4*)(vfeat + (size_t)__float_as_int(ra[j].w) * 64 + c0);
    }
    #pragma unroll
    for (int j = 0; j < 6; ++j) {
      const int k = half * 24 + j * 4 + lg;
      const float p0 = fmaxf(kwA.x * ra[j].x + kwA.y * ra[j].y + kwA.z * ra[j].z + kbv.x, 0.f);
      const float p1 = fmaxf(kwA.w * ra[j].x + kwB.x * ra[j].y + kwB.y * ra[j].z + kbv.y, 0.f);
      const float p2 = fmaxf(kwB.z * ra[j].x + kwB.w * ra[j].y + kwC.x * ra[j].z + kbv.z, 0.f);
      const float p3 = fmaxf(kwC.y * ra[j].x + kwC.z * ra[j].y + kwC.w * ra[j].z + kbv.w, 0.f);
      s16x4 p;
      p[0] = (short)f2bf(va[j].x + p0); p[1] = (short)f2bf(va[j].y + p1);
      p[2] = (short)f2bf(va[j].z + p2); p[3] = (short)f2bf(va[j].w + p3);
      *(s16x4*)&sh[(k * 64 + c0) ^ ((k & 7) << 3)] = p;
    }
  }
  __syncthreads();

  // ---- P6: scores via MFMA; A-frags kept for the vv GEMM ----
  s16x8 af[3][2];
  #pragma unroll
  for (int mt = 0; mt < 3; ++mt)
    #pragma unroll
    for (int kst = 0; kst < 2; ++kst) {
      const int row = mt * 16 + col;
      af[mt][kst] = *(const s16x8*)&sh[(row * 64 + kst * 32 + lg * 8) ^ ((row & 7) << 3)];
    }
  f32x4 sc[3];
  sc[0] = sc[1] = sc[2] = (f32x4){0.f, 0.f, 0.f, 0.f};
  #pragma unroll
  for (int kst = 0; kst < 2; ++kst) {
    const s16x8 b = *(const s16x8*)&sh[3072 + (col & 3) * 64 + kst * 32 + lg * 8];
    #pragma unroll
    for (int mt = 0; mt < 3; ++mt)
      sc[mt] = __builtin_amdgcn_mfma_f32_16x16x32_bf16(af[mt][kst], b, sc[mt], 0, 0, 0);
  }

  // ---- softmax (f32 weights stay in regs; head = col&3 per lane) ----
  float sv[12];
  {
    float mx = -INFINITY;
    #pragma unroll
    for (int mt = 0; mt < 3; ++mt)
      #pragma unroll
      for (int r = 0; r < 4; ++r) {
        const int key = mt * 16 + lg * 4 + r;
        float v = sc[mt][r];
        if ((bm >> key) & 1ull) v = -1e30f;
        sv[mt * 4 + r] = v;
        mx = fmaxf(mx, v);
      }
    mx = fmaxf(mx, __shfl_xor(mx, 16, 64));
    mx = fmaxf(mx, __shfl_xor(mx, 32, 64));
    float sum = 0.f;
    #pragma unroll
    for (int i = 0; i < 12; ++i) { float e = __expf(sv[i] - mx); sv[i] = e; sum += e; }
    sum += __shfl_xor(sum, 16, 64);
    sum += __shfl_xor(sum, 32, 64);
    const float inv = 1.f / sum;
    #pragma unroll
    for (int i = 0; i < 12; ++i) sv[i] *= inv;
  }

  // ---- vv = kin @ wv^T (reusing af), then o[c] = sum_k a[h(c)][k]*vv[k][c] + bv ----
  float op[4];
  #pragma unroll
  for (int nt = 0; nt < 4; ++nt) {
    f32x4 vv0 = {0.f, 0.f, 0.f, 0.f}, vv1 = vv0, vv2 = vv0;
    #pragma unroll
    for (int kst = 0; kst < 2; ++kst) {
      const s16x8 b = *(const s16x8*)(wv_bf + (nt * 16 + col) * 64 + kst * 32 + lg * 8);
      vv0 = __builtin_amdgcn_mfma_f32_16x16x32_bf16(af[0][kst], b, vv0, 0, 0, 0);
      vv1 = __builtin_amdgcn_mfma_f32_16x16x32_bf16(af[1][kst], b, vv1, 0, 0, 0);
      vv2 = __builtin_amdgcn_mfma_f32_16x16x32_bf16(af[2][kst], b, vv2, 0, 0, 0);
    }
    const int src = lg * 16 + nt;    // lane holding a[head=nt][key=mt*16+lg*4+r]
    float o = 0.f;
    #pragma unroll
    for (int mt = 0; mt < 3; ++mt)
      #pragma unroll
      for (int r = 0; r < 4; ++r) {
        const float a = __shfl(sv[mt * 4 + r], src, 64);
        const float v = (mt == 0) ? vv0[r] : (mt == 1) ? vv1[r] : vv2[r];
        o += a * v;
      }
    op[nt] = o;
  }
  #pragma unroll
  for (int nt = 0; nt < 4; ++nt) {
    op[nt] += __shfl_xor(op[nt], 16, 64);
    op[nt] += __shfl_xor(op[nt], 32, 64);
  }
  {
    float oo = (lg == 0) ? op[0] : (lg == 1) ? op[1] : (lg == 2) ? op[2] : op[3];
    oo += ipb[2 * CC + lg * 16 + col];
    out[(size_t)m * CC + lg * 16 + col] = oo;
  }
}

// ---------------- chain: o -> attend -> FFN -> BN -> out layer, all MFMA ----------------
__global__ __launch_bounds__(256, 2) void chain_kernel(
    float* __restrict__ inout, const unsigned short* __restrict__ wsu,
    const float* __restrict__ opb, const float* __restrict__ l1b,
    const float* __restrict__ l2b, const float* __restrict__ ob,
    const float* __restrict__ nrm, const float* __restrict__ bn2, int M)
{
  __shared__ short lds[4][5120];
  const int w = threadIdx.x >> 6;
  const int l = threadIdx.x & 63;
  const int col = l & 15, lg = l >> 4;
  const int r0 = blockIdx.x * 64 + w * 16;

  short* XH = &lds[w][0];
  short* XB = &lds[w][4096];
  const unsigned short* opw_bf = wsu + 12288;
  const unsigned short* l1_bf  = wsu + 16384;
  const unsigned short* l2_bf  = wsu + 32768;
  const unsigned short* ow_bf  = wsu + 49152;

  #pragma unroll
  for (int i = 0; i < 4; ++i) {
    int row = i * 4 + lg, cb = col * 4;
    float4 v = make_float4(0.f, 0.f, 0.f, 0.f);
    if (r0 + row < M) v = *(const float4*)(&inout[(size_t)(r0 + row) * 64 + cb]);
    s16x4 p; p[0] = (short)f2bf(v.x); p[1] = (short)f2bf(v.y);
    p[2] = (short)f2bf(v.z); p[3] = (short)f2bf(v.w);
    *(s16x4*)&XH[(row * 64 + cb) ^ ((row & 7) << 3)] = p;
  }

  s16x8 afa[2];
  #pragma unroll
  for (int kst = 0; kst < 2; ++kst)
    afa[kst] = *(const s16x8*)&XH[(col * 64 + kst * 32 + lg * 8) ^ ((col & 7) << 3)];
  f32x4 att[4];
  #pragma unroll
  for (int nt = 0; nt < 4; ++nt) {
    f32x4 acc = {0.f, 0.f, 0.f, 0.f};
    #pragma unroll
    for (int kst = 0; kst < 2; ++kst) {
      const s16x8 b = *(const s16x8*)&opw_bf[(nt * 16 + col) * 64 + kst * 32 + lg * 8];
      acc = __builtin_amdgcn_mfma_f32_16x16x32_bf16(afa[kst], b, acc, 0, 0, 0);
    }
    float bias = opb[nt * 16 + col];
    #pragma unroll
    for (int r = 0; r < 4; ++r) {
      acc[r] += bias;
      int row = lg * 4 + r;
      XB[(row * 64 + nt * 16 + col) ^ ((row & 7) << 3)] = (short)f2bf(acc[r]);
    }
    att[nt] = acc;
  }

  s16x8 afb[2];
  #pragma unroll
  for (int kst = 0; kst < 2; ++kst)
    afb[kst] = *(const s16x8*)&XB[(col * 64 + kst * 32 + lg * 8) ^ ((col & 7) << 3)];
  #pragma unroll
  for (int nt = 0; nt < 16; ++nt) {
    f32x4 acc = {0.f, 0.f, 0.f, 0.f};
    #pragma unroll
    for (int kst = 0; kst < 2; ++kst) {
      const s16x8 b = *(const s16x8*)&l1_bf[(nt * 16 + col) * 64 + kst * 32 + lg * 8];
      acc = __builtin_amdgcn_mfma_f32_16x16x32_bf16(afb[kst], b, acc, 0, 0, 0);
    }
    float bias = l1b[nt * 16 + col];
    #pragma unroll
    for (int r = 0; r < 4; ++r) {
      float h = fmaxf(acc[r] + bias, 0.f);
      int row = lg * 4 + r;
      XH[(row * 256 + nt * 16 + col) ^ ((row & 7) << 3)] = (short)f2bf(h);
    }
  }

  s16x8 afh[8];
  #pragma unroll
  for (int kst = 0; kst < 8; ++kst)
    afh[kst] = *(const s16x8*)&XH[(col * 256 + kst * 32 + lg * 8) ^ ((col & 7) << 3)];
  #pragma unroll
  for (int nt = 0; nt < 4; ++nt) {
    f32x4 acc = {0.f, 0.f, 0.f, 0.f};
    #pragma unroll
    for (int kst = 0; kst < 8; ++kst) {
      const s16x8 b = *(const s16x8*)&l2_bf[(nt * 16 + col) * 256 + kst * 32 + lg * 8];
      acc = __builtin_amdgcn_mfma_f32_16x16x32_bf16(afh[kst], b, acc, 0, 0, 0);
    }
    int nc = nt * 16 + col;
    float bias = l2b[nc], sN = nrm[nc], tN = nrm[64 + nc];
    #pragma unroll
    for (int r = 0; r < 4; ++r) {
      float x = (att[nt][r] + acc[r] + bias) * sN + tN;
      int row = lg * 4 + r;
      XB[(row * 64 + nc) ^ ((row & 7) << 3)] = (short)f2bf(x);
    }
  }

  s16x8 afx[2];
  #pragma unroll
  for (int kst = 0; kst < 2; ++kst)
    afx[kst] = *(const s16x8*)&XB[(col * 64 + kst * 32 + lg * 8) ^ ((col & 7) << 3)];
  #pragma unroll
  for (int nt = 0; nt < 4; ++nt) {
    f32x4 acc = {0.f, 0.f, 0.f, 0.f};
    #pragma unroll
    for (int kst = 0; kst < 2; ++kst) {
      const s16x8 b = *(const s16x8*)&ow_bf[(nt * 16 + col) * 64 + kst * 32 + lg * 8];
      acc = __builtin_amdgcn_mfma_f32_16x16x32_bf16(afx[kst], b, acc, 0, 0, 0);
    }
    int nc = nt * 16 + col;
    float bias = ob[nc], sB = bn2[nc], tB = bn2[64 + nc];
    #pragma unroll
    for (int r = 0; r < 4; ++r) {
      float y = fmaxf((acc[r] + bias) * sB + tB, 0.f);
      int row = lg * 4 + r;
      if (r0 + row < M) inout[(size_t)(r0 + row) * 64 + nc] = y;
    }
  }
}

extern "C" void kernel_launch(void* const* d_in, const int* in_sizes, int n_in,
                              void* d_out, int out_size, void* d_ws, size_t ws_size,
                              hipStream_t stream) {
  const float* vfeat  = (const float*)d_in[0];
  const float* vcoord = (const float*)d_in[1];
  const float* qcoord = (const float*)d_in[2];
  const int*   kidx   = (const int*)d_in[3];
  const unsigned char* km8  = (const unsigned char*)d_in[4];
  const int*           km32 = (const int*)d_in[4];
  const float* qpw = (const float*)d_in[5];
  const float* qpb = (const float*)d_in[6];
  const float* kpw = (const float*)d_in[7];
  const float* kpb = (const float*)d_in[8];
  const float* ipw = (const float*)d_in[9];
  const float* ipb = (const float*)d_in[10];
  const float* opw = (const float*)d_in[11];
  const float* opb = (const float*)d_in[12];
  const float* l1w = (const float*)d_in[13];
  const float* l1b = (const float*)d_in[14];
  const float* l2w = (const float*)d_in[15];
  const float* l2b = (const float*)d_in[16];
  const float* ng  = (const float*)d_in[17];
  const float* nb  = (const float*)d_in[18];
  const float* nm  = (const float*)d_in[19];
  const float* nv  = (const float*)d_in[20];
  const float* ow  = (const float*)d_in[21];
  const float* ob  = (const float*)d_in[22];
  const float* b2g = (const float*)d_in[23];
  const float* b2b = (const float*)d_in[24];
  const float* b2m = (const float*)d_in[25];
  const float* b2v = (const float*)d_in[26];

  const int M = in_sizes[2] / 3;
  float* ws  = (float*)d_ws;
  float* out = (float*)d_out;
  const unsigned short* wsu = (const unsigned short*)ws;
  const int* flag = (const int*)ws + 26880;

  prep_kernel<<<210, 256, 0, stream>>>(ipw, opw, l1w, l2w, ow,
                                       ng, nb, nm, nv, b2g, b2b, b2m, b2v, km8, ws);
  attn_kernel<<<M, 64, 0, stream>>>(vfeat, vcoord, qcoord, kidx, km8, km32, flag,
                                    qpw, qpb, kpw, kpb, ipb,
                                    wsu /*wq_bf*/, wsu + 4096 /*wkT_bf*/,
                                    wsu + 8192 /*wv_bf*/, out);
  chain_kernel<<<(M + 63) / 64, 256, 0, stream>>>(out, wsu, opb, l1b, l2b, ob,
                                                  ws + 26624, ws + 26752, M);
}

// Round 8
// 108.213 us; speedup vs baseline: 3.5655x; 1.1345x over previous
//
#include <hip/hip_runtime.h>
#include <math.h>

#define CC 64
#define KK 48
#define HH 4

typedef __attribute__((ext_vector_type(8))) short s16x8;
typedef __attribute__((ext_vector_type(4))) short s16x4;
typedef __attribute__((ext_vector_type(4))) float f32x4;

// ws u16 layout: [0,4096) wq_bf | [4096,8192) wk2T_bf [4][64][16] | [8192,12288) wv_bf
//   [12288,16384) opw_bf | [16384,32768) l1_bf | [32768,49152) l2_bf | [49152,53248) ow_bf
// ws f32 layout: [26624,26752) nrm s,t | [26752,26880) bn2 s,t | [26880] flag(int)
// qw buffer: u16 offset 57344 (byte 114688), [M][4][64] bf16
#define QW_OFF_U16 57344

__device__ __forceinline__ unsigned short f2bf(float f) {
  return (unsigned short)((__float_as_uint(f) + 0x8000u) >> 16);  // round-half-up
}

// ---------------- prep: bf16 weight casts/transposes + BN folds + mask detect ----------------
__global__ __launch_bounds__(256) void prep_kernel(
    const float* __restrict__ ipw, const float* __restrict__ opw,
    const float* __restrict__ l1w, const float* __restrict__ l2w,
    const float* __restrict__ ow,
    const float* __restrict__ ng, const float* __restrict__ nb,
    const float* __restrict__ nm, const float* __restrict__ nv,
    const float* __restrict__ b2g, const float* __restrict__ b2b,
    const float* __restrict__ b2m, const float* __restrict__ b2v,
    const unsigned char* __restrict__ km,
    float* __restrict__ ws)
{
  unsigned short* wsu = (unsigned short*)ws;
  if (blockIdx.x == 209) {  // mask dtype detect: int32-bool has all bytes at i%4!=0 zero
    int any = 0;
    for (int i = threadIdx.x; i < 4096; i += 256)
      if ((i & 3) && km[i]) any = 1;
    __shared__ int sb;
    if (threadIdx.x == 0) sb = 0;
    __syncthreads();
    if (any) atomicOr(&sb, 1);
    __syncthreads();
    if (threadIdx.x == 0) ((int*)ws)[26880] = sb;
    return;
  }
  int e = blockIdx.x * 256 + threadIdx.x;
  if (e < 4096)        wsu[e] = f2bf(ipw[e]);                      // wq rows 0-63
  else if (e < 8192)  { int i = e - 4096; int h = i >> 10, c = (i >> 4) & 63, d = i & 15;
                        wsu[e] = f2bf(ipw[(size_t)(64 + h * 16 + d) * 64 + c]); }  // wk2T[h][c][d]
  else if (e < 12288)  wsu[e] = f2bf(ipw[e]);                      // wv rows 128-191
  else if (e < 16384)  wsu[e] = f2bf(opw[e - 12288]);
  else if (e < 32768)  wsu[e] = f2bf(l1w[e - 16384]);
  else if (e < 49152)  wsu[e] = f2bf(l2w[e - 32768]);
  else if (e < 53248)  wsu[e] = f2bf(ow[e - 49152]);
  else if (e < 53312) { int c = e - 53248; float s = ng[c] / sqrtf(nv[c] + 1e-5f);
                        ws[26624 + c] = s; ws[26624 + 64 + c] = nb[c] - nm[c] * s; }
  else if (e < 53376) { int c = e - 53312; float s = b2g[c] / sqrtf(b2v[c] + 1e-5f);
                        ws[26752 + c] = s; ws[26752 + 64 + c] = b2b[c] - b2m[c] * s; }
}

// ---------------- qprep: batched q_in -> q -> qw for all queries ----------------
// 64 queries/block, 4 waves x 16 rows. Weights read once per 16-row tile.
__global__ __launch_bounds__(256, 2) void qprep_kernel(
    const float* __restrict__ qcoord, const float* __restrict__ qpw,
    const float* __restrict__ qpb, const float* __restrict__ ipb,
    const unsigned short* __restrict__ wq_bf,
    const unsigned short* __restrict__ wk2T_bf,
    unsigned short* __restrict__ qw_out, int M)
{
  __shared__ __align__(16) unsigned short xa[4][1024];
  __shared__ float qc[4][48];
  const int w = threadIdx.x >> 6, l = threadIdx.x & 63;
  const int col = l & 15, lg = l >> 4;
  const int r0 = blockIdx.x * 64 + w * 16;

  if (l < 48) {
    int gi = r0 * 3 + l;
    qc[w][l] = (gi < M * 3) ? qcoord[gi] : 0.f;
  }
  const int c0 = col * 4;
  const float4 wA = *(const float4*)(qpw + c0 * 3);
  const float4 wB = *(const float4*)(qpw + c0 * 3 + 4);
  const float4 wC = *(const float4*)(qpw + c0 * 3 + 8);
  const float4 bq4 = *(const float4*)(qpb + c0);
  __syncthreads();

  // q_in = relu(qc @ qpw^T + qpb), bf16 swizzled
  #pragma unroll
  for (int i = 0; i < 4; ++i) {
    const int row = i * 4 + lg;
    const float x = qc[w][row * 3 + 0], y = qc[w][row * 3 + 1], z = qc[w][row * 3 + 2];
    s16x4 p;
    p[0] = (short)f2bf(fmaxf(wA.x * x + wA.y * y + wA.z * z + bq4.x, 0.f));
    p[1] = (short)f2bf(fmaxf(wA.w * x + wB.x * y + wB.y * z + bq4.y, 0.f));
    p[2] = (short)f2bf(fmaxf(wB.z * x + wB.w * y + wC.x * z + bq4.z, 0.f));
    p[3] = (short)f2bf(fmaxf(wC.y * x + wC.z * y + wC.w * z + bq4.w, 0.f));
    *(s16x4*)&xa[w][(row * 64 + c0) ^ ((row & 7) << 3)] = p;
  }
  __syncthreads();

  // GEMM1: q = (q_in @ wq^T + bq)*0.25 -> bf16 swizzled (overwrites xa)
  {
    s16x8 af0 = *(const s16x8*)&xa[w][(col * 64 + 0 + lg * 8) ^ ((col & 7) << 3)];
    s16x8 af1 = *(const s16x8*)&xa[w][(col * 64 + 32 + lg * 8) ^ ((col & 7) << 3)];
    f32x4 qv[4];
    #pragma unroll
    for (int nt = 0; nt < 4; ++nt) {
      f32x4 acc = {0.f, 0.f, 0.f, 0.f};
      acc = __builtin_amdgcn_mfma_f32_16x16x32_bf16(af0,
              *(const s16x8*)(wq_bf + (nt * 16 + col) * 64 + 0 + lg * 8), acc, 0, 0, 0);
      acc = __builtin_amdgcn_mfma_f32_16x16x32_bf16(af1,
              *(const s16x8*)(wq_bf + (nt * 16 + col) * 64 + 32 + lg * 8), acc, 0, 0, 0);
      qv[nt] = acc;
    }
    __syncthreads();
    #pragma unroll
    for (int nt = 0; nt < 4; ++nt) {
      const int n = nt * 16 + col;
      const float b = ipb[n];
      #pragma unroll
      for (int r = 0; r < 4; ++r) {
        const int row = lg * 4 + r;
        xa[w][(row * 64 + n) ^ ((row & 7) << 3)] = f2bf((qv[nt][r] + b) * 0.25f);
      }
    }
  }
  __syncthreads();

  // GEMM2 per head: qw[h][c] = sum_d q[h*16+d]*wk[h*16+d][c]
  #pragma unroll
  for (int h = 0; h < HH; ++h) {
    s16x8 a = {0, 0, 0, 0, 0, 0, 0, 0};
    if (lg < 2)
      a = *(const s16x8*)&xa[w][(col * 64 + h * 16 + lg * 8) ^ ((col & 7) << 3)];
    #pragma unroll
    for (int nt = 0; nt < 4; ++nt) {
      s16x8 b = {0, 0, 0, 0, 0, 0, 0, 0};
      if (lg < 2)
        b = *(const s16x8*)(wk2T_bf + h * 1024 + (nt * 16 + col) * 16 + lg * 8);
      f32x4 acc = {0.f, 0.f, 0.f, 0.f};
      acc = __builtin_amdgcn_mfma_f32_16x16x32_bf16(a, b, acc, 0, 0, 0);
      #pragma unroll
      for (int r = 0; r < 4; ++r) {
        const int m = lg * 4 + r;
        if (r0 + m < M)
          qw_out[(size_t)(r0 + m) * 256 + h * 64 + nt * 16 + col] = f2bf(acc[r]);
      }
    }
  }
}

// ---------------- attention: one wave per query ----------------
// LDS (u16 idx): kin [0,3072) swizzled (k*64+c)^((k&7)<<3) | qw [3072,3328)
//   qbuf [3328,3392) | rel f32[48][4] @u16 [3392,3776).
__global__ __launch_bounds__(64, 4) void attn_kernel(
    const float* __restrict__ vfeat, const float* __restrict__ vcoord,
    const float* __restrict__ qcoord, const int* __restrict__ kidx,
    const unsigned char* __restrict__ km8, const int* __restrict__ km32,
    const int* __restrict__ maskfmt,
    const float* __restrict__ qpw, const float* __restrict__ qpb,
    const float* __restrict__ kpw, const float* __restrict__ kpb,
    const float* __restrict__ ipb,
    const unsigned short* __restrict__ wq_bf,
    const unsigned short* __restrict__ wk2T_bf,
    const unsigned short* __restrict__ wv_bf,
    const unsigned short* __restrict__ qw_pre, const int pre,
    float* __restrict__ out)
{
  __shared__ __align__(16) unsigned short sh[3776];
  const int m = blockIdx.x, l = threadIdx.x;
  const int col = l & 15, lg = l >> 4;
  const int is_u8 = *maskfmt;
  float* relf = (float*)sh + 1696;   // u16 3392

  const float qx = qcoord[m * 3 + 0], qy = qcoord[m * 3 + 1], qz = qcoord[m * 3 + 2];
  const int c0 = col * 4;
  const float4 kwA = *(const float4*)(kpw + c0 * 3);
  const float4 kwB = *(const float4*)(kpw + c0 * 3 + 4);
  const float4 kwC = *(const float4*)(kpw + c0 * 3 + 8);
  const float4 kbv = *(const float4*)(kpb + c0);

  // ---- P1: rel coords / indices / mask (+ q_in only in fallback) ----
  if (!pre) {
    float v = qpw[l * 3 + 0] * qx + qpw[l * 3 + 1] * qy + qpw[l * 3 + 2] * qz + qpb[l];
    sh[3328 + l] = f2bf(fmaxf(v, 0.f));
  }
  unsigned char msk = 0;
  if (l < KK) {
    int idx = kidx[m * KK + l];
    msk = is_u8 ? km8[m * KK + l] : (unsigned char)(km32[m * KK + l] != 0);
    relf[l * 4 + 0] = vcoord[idx * 3 + 0] - qx;
    relf[l * 4 + 1] = vcoord[idx * 3 + 1] - qy;
    relf[l * 4 + 2] = vcoord[idx * 3 + 2] - qz;
    relf[l * 4 + 3] = __int_as_float(idx);
  }
  const unsigned long long bm = __ballot(l < KK && msk);
  __syncthreads();

  if (!pre) {
    // ---- P2: q = (q_in @ wq^T + bq)*0.25 via MFMA ----
    f32x4 qacc[4];
    #pragma unroll
    for (int nt = 0; nt < 4; ++nt) qacc[nt] = (f32x4){0.f, 0.f, 0.f, 0.f};
    #pragma unroll
    for (int kst = 0; kst < 2; ++kst) {
      const s16x8 a = *(const s16x8*)&sh[3328 + kst * 32 + lg * 8];
      #pragma unroll
      for (int nt = 0; nt < 4; ++nt) {
        const s16x8 b = *(const s16x8*)(wq_bf + (nt * 16 + col) * 64 + kst * 32 + lg * 8);
        qacc[nt] = __builtin_amdgcn_mfma_f32_16x16x32_bf16(a, b, qacc[nt], 0, 0, 0);
      }
    }
    __syncthreads();
    if (lg == 0) {
      #pragma unroll
      for (int nt = 0; nt < 4; ++nt)
        sh[3328 + nt * 16 + col] = f2bf((qacc[nt][0] + ipb[nt * 16 + col]) * 0.25f);
    }
    __syncthreads();
    // ---- P3: qw[h][c] via MFMA (block-diag A); B remapped to wk2T layout ----
    f32x4 wacc[4];
    #pragma unroll
    for (int nt = 0; nt < 4; ++nt) wacc[nt] = (f32x4){0.f, 0.f, 0.f, 0.f};
    #pragma unroll
    for (int kst = 0; kst < 2; ++kst) {
      const int hblk = kst * 2 + (lg >> 1);
      s16x8 a = {0, 0, 0, 0, 0, 0, 0, 0};
      if (col == hblk) a = *(const s16x8*)&sh[3328 + kst * 32 + lg * 8];
      #pragma unroll
      for (int nt = 0; nt < 4; ++nt) {
        const s16x8 b = *(const s16x8*)(wk2T_bf + hblk * 1024 + (nt * 16 + col) * 16 + (lg & 1) * 8);
        wacc[nt] = __builtin_amdgcn_mfma_f32_16x16x32_bf16(a, b, wacc[nt], 0, 0, 0);
      }
    }
    if (lg == 0) {
      #pragma unroll
      for (int nt = 0; nt < 4; ++nt)
        #pragma unroll
        for (int r = 0; r < 4; ++r)
          sh[3072 + r * 64 + nt * 16 + col] = f2bf(wacc[nt][r]);
    }
  }

  // ---- P5: k_in gather, 4-wide ----
  #pragma unroll
  for (int half = 0; half < 2; ++half) {
    float4 ra[6], va[6];
    #pragma unroll
    for (int j = 0; j < 6; ++j) {
      const int k = half * 24 + j * 4 + lg;
      ra[j] = *(const float4*)(relf + k * 4);
      va[j] = *(const float4*)(vfeat + (size_t)__float_as_int(ra[j].w) * 64 + c0);
    }
    #pragma unroll
    for (int j = 0; j < 6; ++j) {
      const int k = half * 24 + j * 4 + lg;
      const float p0 = fmaxf(kwA.x * ra[j].x + kwA.y * ra[j].y + kwA.z * ra[j].z + kbv.x, 0.f);
      const float p1 = fmaxf(kwA.w * ra[j].x + kwB.x * ra[j].y + kwB.y * ra[j].z + kbv.y, 0.f);
      const float p2 = fmaxf(kwB.z * ra[j].x + kwB.w * ra[j].y + kwC.x * ra[j].z + kbv.z, 0.f);
      const float p3 = fmaxf(kwC.y * ra[j].x + kwC.z * ra[j].y + kwC.w * ra[j].z + kbv.w, 0.f);
      s16x4 p;
      p[0] = (short)f2bf(va[j].x + p0); p[1] = (short)f2bf(va[j].y + p1);
      p[2] = (short)f2bf(va[j].z + p2); p[3] = (short)f2bf(va[j].w + p3);
      *(s16x4*)&sh[(k * 64 + c0) ^ ((k & 7) << 3)] = p;
    }
  }
  __syncthreads();

  // ---- P6: scores via MFMA; A-frags kept for the vv GEMM ----
  s16x8 af[3][2];
  #pragma unroll
  for (int mt = 0; mt < 3; ++mt)
    #pragma unroll
    for (int kst = 0; kst < 2; ++kst) {
      const int row = mt * 16 + col;
      af[mt][kst] = *(const s16x8*)&sh[(row * 64 + kst * 32 + lg * 8) ^ ((row & 7) << 3)];
    }
  f32x4 sc[3];
  sc[0] = sc[1] = sc[2] = (f32x4){0.f, 0.f, 0.f, 0.f};
  #pragma unroll
  for (int kst = 0; kst < 2; ++kst) {
    s16x8 b;
    if (pre) b = *(const s16x8*)(qw_pre + (size_t)m * 256 + (col & 3) * 64 + kst * 32 + lg * 8);
    else     b = *(const s16x8*)&sh[3072 + (col & 3) * 64 + kst * 32 + lg * 8];
    #pragma unroll
    for (int mt = 0; mt < 3; ++mt)
      sc[mt] = __builtin_amdgcn_mfma_f32_16x16x32_bf16(af[mt][kst], b, sc[mt], 0, 0, 0);
  }

  // ---- softmax (f32 weights in regs; head = col&3 per lane) ----
  float sv[12];
  {
    float mx = -INFINITY;
    #pragma unroll
    for (int mt = 0; mt < 3; ++mt)
      #pragma unroll
      for (int r = 0; r < 4; ++r) {
        const int key = mt * 16 + lg * 4 + r;
        float v = sc[mt][r];
        if ((bm >> key) & 1ull) v = -1e30f;
        sv[mt * 4 + r] = v;
        mx = fmaxf(mx, v);
      }
    mx = fmaxf(mx, __shfl_xor(mx, 16, 64));
    mx = fmaxf(mx, __shfl_xor(mx, 32, 64));
    float sum = 0.f;
    #pragma unroll
    for (int i = 0; i < 12; ++i) { float e = __expf(sv[i] - mx); sv[i] = e; sum += e; }
    sum += __shfl_xor(sum, 16, 64);
    sum += __shfl_xor(sum, 32, 64);
    const float inv = 1.f / sum;
    #pragma unroll
    for (int i = 0; i < 12; ++i) sv[i] *= inv;
  }

  // ---- vv = kin @ wv^T (reusing af), then o[c] = sum_k a[h(c)][k]*vv[k][c] + bv ----
  float op[4];
  #pragma unroll
  for (int nt = 0; nt < 4; ++nt) {
    f32x4 vv0 = {0.f, 0.f, 0.f, 0.f}, vv1 = vv0, vv2 = vv0;
    #pragma unroll
    for (int kst = 0; kst < 2; ++kst) {
      const s16x8 b = *(const s16x8*)(wv_bf + (nt * 16 + col) * 64 + kst * 32 + lg * 8);
      vv0 = __builtin_amdgcn_mfma_f32_16x16x32_bf16(af[0][kst], b, vv0, 0, 0, 0);
      vv1 = __builtin_amdgcn_mfma_f32_16x16x32_bf16(af[1][kst], b, vv1, 0, 0, 0);
      vv2 = __builtin_amdgcn_mfma_f32_16x16x32_bf16(af[2][kst], b, vv2, 0, 0, 0);
    }
    const int src = lg * 16 + nt;
    float o = 0.f;
    #pragma unroll
    for (int mt = 0; mt < 3; ++mt)
      #pragma unroll
      for (int r = 0; r < 4; ++r) {
        const float a = __shfl(sv[mt * 4 + r], src, 64);
        const float v = (mt == 0) ? vv0[r] : (mt == 1) ? vv1[r] : vv2[r];
        o += a * v;
      }
    op[nt] = o;
  }
  #pragma unroll
  for (int nt = 0; nt < 4; ++nt) {
    op[nt] += __shfl_xor(op[nt], 16, 64);
    op[nt] += __shfl_xor(op[nt], 32, 64);
  }
  {
    float oo = (lg == 0) ? op[0] : (lg == 1) ? op[1] : (lg == 2) ? op[2] : op[3];
    oo += ipb[2 * CC + lg * 16 + col];
    out[(size_t)m * CC + lg * 16 + col] = oo;
  }
}

// ---------------- chain: o -> attend -> FFN -> BN -> out layer, all MFMA ----------------
__global__ __launch_bounds__(256, 2) void chain_kernel(
    float* __restrict__ inout, const unsigned short* __restrict__ wsu,
    const float* __restrict__ opb, const float* __restrict__ l1b,
    const float* __restrict__ l2b, const float* __restrict__ ob,
    const float* __restrict__ nrm, const float* __restrict__ bn2, int M)
{
  __shared__ short lds[4][5120];
  const int w = threadIdx.x >> 6;
  const int l = threadIdx.x & 63;
  const int col = l & 15, lg = l >> 4;
  const int r0 = blockIdx.x * 64 + w * 16;

  short* XH = &lds[w][0];
  short* XB = &lds[w][4096];
  const unsigned short* opw_bf = wsu + 12288;
  const unsigned short* l1_bf  = wsu + 16384;
  const unsigned short* l2_bf  = wsu + 32768;
  const unsigned short* ow_bf  = wsu + 49152;

  #pragma unroll
  for (int i = 0; i < 4; ++i) {
    int row = i * 4 + lg, cb = col * 4;
    float4 v = make_float4(0.f, 0.f, 0.f, 0.f);
    if (r0 + row < M) v = *(const float4*)(&inout[(size_t)(r0 + row) * 64 + cb]);
    s16x4 p; p[0] = (short)f2bf(v.x); p[1] = (short)f2bf(v.y);
    p[2] = (short)f2bf(v.z); p[3] = (short)f2bf(v.w);
    *(s16x4*)&XH[(row * 64 + cb) ^ ((row & 7) << 3)] = p;
  }

  s16x8 afa[2];
  #pragma unroll
  for (int kst = 0; kst < 2; ++kst)
    afa[kst] = *(const s16x8*)&XH[(col * 64 + kst * 32 + lg * 8) ^ ((col & 7) << 3)];
  f32x4 att[4];
  #pragma unroll
  for (int nt = 0; nt < 4; ++nt) {
    f32x4 acc = {0.f, 0.f, 0.f, 0.f};
    #pragma unroll
    for (int kst = 0; kst < 2; ++kst) {
      const s16x8 b = *(const s16x8*)&opw_bf[(nt * 16 + col) * 64 + kst * 32 + lg * 8];
      acc = __builtin_amdgcn_mfma_f32_16x16x32_bf16(afa[kst], b, acc, 0, 0, 0);
    }
    float bias = opb[nt * 16 + col];
    #pragma unroll
    for (int r = 0; r < 4; ++r) {
      acc[r] += bias;
      int row = lg * 4 + r;
      XB[(row * 64 + nt * 16 + col) ^ ((row & 7) << 3)] = (short)f2bf(acc[r]);
    }
    att[nt] = acc;
  }

  s16x8 afb[2];
  #pragma unroll
  for (int kst = 0; kst < 2; ++kst)
    afb[kst] = *(const s16x8*)&XB[(col * 64 + kst * 32 + lg * 8) ^ ((col & 7) << 3)];
  #pragma unroll
  for (int nt = 0; nt < 16; ++nt) {
    f32x4 acc = {0.f, 0.f, 0.f, 0.f};
    #pragma unroll
    for (int kst = 0; kst < 2; ++kst) {
      const s16x8 b = *(const s16x8*)&l1_bf[(nt * 16 + col) * 64 + kst * 32 + lg * 8];
      acc = __builtin_amdgcn_mfma_f32_16x16x32_bf16(afb[kst], b, acc, 0, 0, 0);
    }
    float bias = l1b[nt * 16 + col];
    #pragma unroll
    for (int r = 0; r < 4; ++r) {
      float h = fmaxf(acc[r] + bias, 0.f);
      int row = lg * 4 + r;
      XH[(row * 256 + nt * 16 + col) ^ ((row & 7) << 3)] = (short)f2bf(h);
    }
  }

  s16x8 afh[8];
  #pragma unroll
  for (int kst = 0; kst < 8; ++kst)
    afh[kst] = *(const s16x8*)&XH[(col * 256 + kst * 32 + lg * 8) ^ ((col & 7) << 3)];
  #pragma unroll
  for (int nt = 0; nt < 4; ++nt) {
    f32x4 acc = {0.f, 0.f, 0.f, 0.f};
    #pragma unroll
    for (int kst = 0; kst < 8; ++kst) {
      const s16x8 b = *(const s16x8*)&l2_bf[(nt * 16 + col) * 256 + kst * 32 + lg * 8];
      acc = __builtin_amdgcn_mfma_f32_16x16x32_bf16(afh[kst], b, acc, 0, 0, 0);
    }
    int nc = nt * 16 + col;
    float bias = l2b[nc], sN = nrm[nc], tN = nrm[64 + nc];
    #pragma unroll
    for (int r = 0; r < 4; ++r) {
      float x = (att[nt][r] + acc[r] + bias) * sN + tN;
      int row = lg * 4 + r;
      XB[(row * 64 + nc) ^ ((row & 7) << 3)] = (short)f2bf(x);
    }
  }

  s16x8 afx[2];
  #pragma unroll
  for (int kst = 0; kst < 2; ++kst)
    afx[kst] = *(const s16x8*)&XB[(col * 64 + kst * 32 + lg * 8) ^ ((col & 7) << 3)];
  #pragma unroll
  for (int nt = 0; nt < 4; ++nt) {
    f32x4 acc = {0.f, 0.f, 0.f, 0.f};
    #pragma unroll
    for (int kst = 0; kst < 2; ++kst) {
      const s16x8 b = *(const s16x8*)&ow_bf[(nt * 16 + col) * 64 + kst * 32 + lg * 8];
      acc = __builtin_amdgcn_mfma_f32_16x16x32_bf16(afx[kst], b, acc, 0, 0, 0);
    }
    int nc = nt * 16 + col;
    float bias = ob[nc], sB = bn2[nc], tB = bn2[64 + nc];
    #pragma unroll
    for (int r = 0; r < 4; ++r) {
      float y = fmaxf((acc[r] + bias) * sB + tB, 0.f);
      int row = lg * 4 + r;
      if (r0 + row < M) inout[(size_t)(r0 + row) * 64 + nc] = y;
    }
  }
}

extern "C" void kernel_launch(void* const* d_in, const int* in_sizes, int n_in,
                              void* d_out, int out_size, void* d_ws, size_t ws_size,
                              hipStream_t stream) {
  const float* vfeat  = (const float*)d_in[0];
  const float* vcoord = (const float*)d_in[1];
  const float* qcoord = (const float*)d_in[2];
  const int*   kidx   = (const int*)d_in[3];
  const unsigned char* km8  = (const unsigned char*)d_in[4];
  const int*           km32 = (const int*)d_in[4];
  const float* qpw = (const float*)d_in[5];
  const float* qpb = (const float*)d_in[6];
  const float* kpw = (const float*)d_in[7];
  const float* kpb = (const float*)d_in[8];
  const float* ipw = (const float*)d_in[9];
  const float* ipb = (const float*)d_in[10];
  const float* opw = (const float*)d_in[11];
  const float* opb = (const float*)d_in[12];
  const float* l1w = (const float*)d_in[13];
  const float* l1b = (const float*)d_in[14];
  const float* l2w = (const float*)d_in[15];
  const float* l2b = (const float*)d_in[16];
  const float* ng  = (const float*)d_in[17];
  const float* nb  = (const float*)d_in[18];
  const float* nm  = (const float*)d_in[19];
  const float* nv  = (const float*)d_in[20];
  const float* ow  = (const float*)d_in[21];
  const float* ob  = (const float*)d_in[22];
  const float* b2g = (const float*)d_in[23];
  const float* b2b = (const float*)d_in[24];
  const float* b2m = (const float*)d_in[25];
  const float* b2v = (const float*)d_in[26];

  const int M = in_sizes[2] / 3;
  float* ws  = (float*)d_ws;
  float* out = (float*)d_out;
  unsigned short* wsu = (unsigned short*)ws;
  const int* flag = (const int*)ws + 26880;

  const int pre = (ws_size >= (size_t)114688 + (size_t)M * 512) ? 1 : 0;
  unsigned short* qw = wsu + QW_OFF_U16;

  prep_kernel<<<210, 256, 0, stream>>>(ipw, opw, l1w, l2w, ow,
                                       ng, nb, nm, nv, b2g, b2b, b2m, b2v, km8, ws);
  if (pre)
    qprep_kernel<<<(M + 63) / 64, 256, 0, stream>>>(qcoord, qpw, qpb, ipb,
                                                    wsu, wsu + 4096, qw, M);
  attn_kernel<<<M, 64, 0, stream>>>(vfeat, vcoord, qcoord, kidx, km8, km32, flag,
                                    qpw, qpb, kpw, kpb, ipb,
                                    wsu /*wq_bf*/, wsu + 4096 /*wk2T_bf*/,
                                    wsu + 8192 /*wv_bf*/, qw, pre, out);
  chain_kernel<<<(M + 63) / 64, 256, 0, stream>>>(out, wsu, opb, l1b, l2b, ob,
                                                  ws + 26624, ws + 26752, M);
}

// Round 9
// 100.544 us; speedup vs baseline: 3.8375x; 1.0763x over previous
//
#include <hip/hip_runtime.h>
#include <math.h>

#define CC 64
#define KK 48
#define HH 4

typedef __attribute__((ext_vector_type(8))) short s16x8;
typedef __attribute__((ext_vector_type(4))) short s16x4;
typedef __attribute__((ext_vector_type(4))) float f32x4;

// ws u16 layout: [0,4096) wq_bf | [4096,8192) wk2T_bf [4][64][16] | [8192,12288) wv_bf
//   [12288,16384) opw_bf | [16384,32768) l1_bf | [32768,49152) l2_bf | [49152,53248) ow_bf
// ws f32 layout: [26624,26752) nrm s,t | [26752,26880) bn2 s,t | [26880] flag(int)
// qw buffer: u16 off 57344, [M][4][64] bf16.  vfeat_bf: u16 off 57344+M*256, [NV][64] bf16.
#define QW_OFF_U16 57344

__device__ __forceinline__ unsigned short f2bf(float f) {
  return (unsigned short)((__float_as_uint(f) + 0x8000u) >> 16);  // round-half-up
}
__device__ __forceinline__ float bf2f(unsigned short h) {
  return __uint_as_float(((unsigned)h) << 16);
}

// ---------------- prep: bf16 weight casts/transposes + BN folds + mask detect ----------------
__global__ __launch_bounds__(256) void prep_kernel(
    const float* __restrict__ ipw, const float* __restrict__ opw,
    const float* __restrict__ l1w, const float* __restrict__ l2w,
    const float* __restrict__ ow,
    const float* __restrict__ ng, const float* __restrict__ nb,
    const float* __restrict__ nm, const float* __restrict__ nv,
    const float* __restrict__ b2g, const float* __restrict__ b2b,
    const float* __restrict__ b2m, const float* __restrict__ b2v,
    const unsigned char* __restrict__ km,
    float* __restrict__ ws)
{
  unsigned short* wsu = (unsigned short*)ws;
  if (blockIdx.x == 209) {  // mask dtype detect: int32-bool has all bytes at i%4!=0 zero
    int any = 0;
    for (int i = threadIdx.x; i < 4096; i += 256)
      if ((i & 3) && km[i]) any = 1;
    __shared__ int sb;
    if (threadIdx.x == 0) sb = 0;
    __syncthreads();
    if (any) atomicOr(&sb, 1);
    __syncthreads();
    if (threadIdx.x == 0) ((int*)ws)[26880] = sb;
    return;
  }
  int e = blockIdx.x * 256 + threadIdx.x;
  if (e < 4096)        wsu[e] = f2bf(ipw[e]);                      // wq rows 0-63
  else if (e < 8192)  { int i = e - 4096; int h = i >> 10, c = (i >> 4) & 63, d = i & 15;
                        wsu[e] = f2bf(ipw[(size_t)(64 + h * 16 + d) * 64 + c]); }  // wk2T[h][c][d]
  else if (e < 12288)  wsu[e] = f2bf(ipw[e]);                      // wv rows 128-191
  else if (e < 16384)  wsu[e] = f2bf(opw[e - 12288]);
  else if (e < 32768)  wsu[e] = f2bf(l1w[e - 16384]);
  else if (e < 49152)  wsu[e] = f2bf(l2w[e - 32768]);
  else if (e < 53248)  wsu[e] = f2bf(ow[e - 49152]);
  else if (e < 53312) { int c = e - 53248; float s = ng[c] / sqrtf(nv[c] + 1e-5f);
                        ws[26624 + c] = s; ws[26624 + 64 + c] = nb[c] - nm[c] * s; }
  else if (e < 53376) { int c = e - 53312; float s = b2g[c] / sqrtf(b2v[c] + 1e-5f);
                        ws[26752 + c] = s; ws[26752 + 64 + c] = b2b[c] - b2m[c] * s; }
}

// ---------------- castv: vfeat f32 -> bf16 table (halves gather traffic) ----------------
__global__ __launch_bounds__(256) void castv_kernel(
    const float* __restrict__ vf, unsigned short* __restrict__ vfb, int n4)
{
  int i = blockIdx.x * 256 + threadIdx.x;
  const int stride = gridDim.x * 256;
  for (; i < n4; i += stride) {
    const float4 v = *(const float4*)(vf + (size_t)i * 4);
    s16x4 p; p[0] = (short)f2bf(v.x); p[1] = (short)f2bf(v.y);
    p[2] = (short)f2bf(v.z); p[3] = (short)f2bf(v.w);
    *(s16x4*)(vfb + (size_t)i * 4) = p;
  }
}

// ---------------- qprep: batched q_in -> q -> qw for all queries ----------------
__global__ __launch_bounds__(256, 2) void qprep_kernel(
    const float* __restrict__ qcoord, const float* __restrict__ qpw,
    const float* __restrict__ qpb, const float* __restrict__ ipb,
    const unsigned short* __restrict__ wq_bf,
    const unsigned short* __restrict__ wk2T_bf,
    unsigned short* __restrict__ qw_out, int M)
{
  __shared__ __align__(16) unsigned short xa[4][1024];
  __shared__ float qc[4][48];
  const int w = threadIdx.x >> 6, l = threadIdx.x & 63;
  const int col = l & 15, lg = l >> 4;
  const int r0 = blockIdx.x * 64 + w * 16;

  if (l < 48) {
    int gi = r0 * 3 + l;
    qc[w][l] = (gi < M * 3) ? qcoord[gi] : 0.f;
  }
  const int c0 = col * 4;
  const float4 wA = *(const float4*)(qpw + c0 * 3);
  const float4 wB = *(const float4*)(qpw + c0 * 3 + 4);
  const float4 wC = *(const float4*)(qpw + c0 * 3 + 8);
  const float4 bq4 = *(const float4*)(qpb + c0);
  __syncthreads();

  #pragma unroll
  for (int i = 0; i < 4; ++i) {
    const int row = i * 4 + lg;
    const float x = qc[w][row * 3 + 0], y = qc[w][row * 3 + 1], z = qc[w][row * 3 + 2];
    s16x4 p;
    p[0] = (short)f2bf(fmaxf(wA.x * x + wA.y * y + wA.z * z + bq4.x, 0.f));
    p[1] = (short)f2bf(fmaxf(wA.w * x + wB.x * y + wB.y * z + bq4.y, 0.f));
    p[2] = (short)f2bf(fmaxf(wB.z * x + wB.w * y + wC.x * z + bq4.z, 0.f));
    p[3] = (short)f2bf(fmaxf(wC.y * x + wC.z * y + wC.w * z + bq4.w, 0.f));
    *(s16x4*)&xa[w][(row * 64 + c0) ^ ((row & 7) << 3)] = p;
  }
  __syncthreads();

  {
    s16x8 af0 = *(const s16x8*)&xa[w][(col * 64 + 0 + lg * 8) ^ ((col & 7) << 3)];
    s16x8 af1 = *(const s16x8*)&xa[w][(col * 64 + 32 + lg * 8) ^ ((col & 7) << 3)];
    f32x4 qv[4];
    #pragma unroll
    for (int nt = 0; nt < 4; ++nt) {
      f32x4 acc = {0.f, 0.f, 0.f, 0.f};
      acc = __builtin_amdgcn_mfma_f32_16x16x32_bf16(af0,
              *(const s16x8*)(wq_bf + (nt * 16 + col) * 64 + 0 + lg * 8), acc, 0, 0, 0);
      acc = __builtin_amdgcn_mfma_f32_16x16x32_bf16(af1,
              *(const s16x8*)(wq_bf + (nt * 16 + col) * 64 + 32 + lg * 8), acc, 0, 0, 0);
      qv[nt] = acc;
    }
    __syncthreads();
    #pragma unroll
    for (int nt = 0; nt < 4; ++nt) {
      const int n = nt * 16 + col;
      const float b = ipb[n];
      #pragma unroll
      for (int r = 0; r < 4; ++r) {
        const int row = lg * 4 + r;
        xa[w][(row * 64 + n) ^ ((row & 7) << 3)] = f2bf((qv[nt][r] + b) * 0.25f);
      }
    }
  }
  __syncthreads();

  #pragma unroll
  for (int h = 0; h < HH; ++h) {
    s16x8 a = {0, 0, 0, 0, 0, 0, 0, 0};
    if (lg < 2)
      a = *(const s16x8*)&xa[w][(col * 64 + h * 16 + lg * 8) ^ ((col & 7) << 3)];
    #pragma unroll
    for (int nt = 0; nt < 4; ++nt) {
      s16x8 b = {0, 0, 0, 0, 0, 0, 0, 0};
      if (lg < 2)
        b = *(const s16x8*)(wk2T_bf + h * 1024 + (nt * 16 + col) * 16 + lg * 8);
      f32x4 acc = {0.f, 0.f, 0.f, 0.f};
      acc = __builtin_amdgcn_mfma_f32_16x16x32_bf16(a, b, acc, 0, 0, 0);
      #pragma unroll
      for (int r = 0; r < 4; ++r) {
        const int m = lg * 4 + r;
        if (r0 + m < M)
          qw_out[(size_t)(r0 + m) * 256 + h * 64 + nt * 16 + col] = f2bf(acc[r]);
      }
    }
  }
}

// ---------------- attention: 4 waves/block, one query each; wv staged in LDS ----------------
// per-query LDS (u16 idx): kin [0,3072) swizzled | qw [3072,3328) | qbuf [3328,3392)
//   rel f32[48][4] @u16 [3392,3776).   Shared: wvl[4096] swizzled.
__global__ __launch_bounds__(256, 4) void attn_kernel(
    const float* __restrict__ vfeat, const unsigned short* __restrict__ vfb,
    const float* __restrict__ vcoord,
    const float* __restrict__ qcoord, const int* __restrict__ kidx,
    const unsigned char* __restrict__ km8, const int* __restrict__ km32,
    const int* __restrict__ maskfmt,
    const float* __restrict__ qpw, const float* __restrict__ qpb,
    const float* __restrict__ kpw, const float* __restrict__ kpb,
    const float* __restrict__ ipb,
    const unsigned short* __restrict__ wq_bf,
    const unsigned short* __restrict__ wk2T_bf,
    const unsigned short* __restrict__ wv_bf,
    const unsigned short* __restrict__ qw_pre, const int pre, const int pre2,
    float* __restrict__ out, int M)
{
  __shared__ __align__(16) unsigned short shq[4][3776];
  __shared__ __align__(16) unsigned short wvl[4096];
  const int w = threadIdx.x >> 6, l = threadIdx.x & 63;
  const int col = l & 15, lg = l >> 4;
  int m = blockIdx.x * 4 + w;
  if (m >= M) m = M - 1;                 // benign duplicate of last query
  unsigned short* sh = shq[w];
  const int is_u8 = *maskfmt;
  float* relf = (float*)sh + 1696;       // u16 3392

  // stage wv into swizzled LDS (once per block)
  #pragma unroll
  for (int i = 0; i < 2; ++i) {
    const int ch = threadIdx.x * 2 + i;  // 512 chunks of 16B
    const int n = ch >> 3, g = ch & 7;
    const s16x8 v = *(const s16x8*)(wv_bf + n * 64 + g * 8);
    *(s16x8*)&wvl[n * 64 + ((g ^ (n & 7)) << 3)] = v;
  }

  const float qx = qcoord[m * 3 + 0], qy = qcoord[m * 3 + 1], qz = qcoord[m * 3 + 2];
  const int c0 = col * 4;
  const float4 kwA = *(const float4*)(kpw + c0 * 3);
  const float4 kwB = *(const float4*)(kpw + c0 * 3 + 4);
  const float4 kwC = *(const float4*)(kpw + c0 * 3 + 8);
  const float4 kbv = *(const float4*)(kpb + c0);

  // ---- P1: rel coords / indices / mask (+ q_in only in fallback) ----
  if (!pre) {
    float v = qpw[l * 3 + 0] * qx + qpw[l * 3 + 1] * qy + qpw[l * 3 + 2] * qz + qpb[l];
    sh[3328 + l] = f2bf(fmaxf(v, 0.f));
  }
  unsigned char msk = 0;
  if (l < KK) {
    int idx = kidx[m * KK + l];
    msk = is_u8 ? km8[m * KK + l] : (unsigned char)(km32[m * KK + l] != 0);
    relf[l * 4 + 0] = vcoord[idx * 3 + 0] - qx;
    relf[l * 4 + 1] = vcoord[idx * 3 + 1] - qy;
    relf[l * 4 + 2] = vcoord[idx * 3 + 2] - qz;
    relf[l * 4 + 3] = __int_as_float(idx);
  }
  const unsigned long long bm = __ballot(l < KK && msk);   // per-wave mask
  __syncthreads();

  if (!pre) {
    // ---- P2: q = (q_in @ wq^T + bq)*0.25 via MFMA ----
    f32x4 qacc[4];
    #pragma unroll
    for (int nt = 0; nt < 4; ++nt) qacc[nt] = (f32x4){0.f, 0.f, 0.f, 0.f};
    #pragma unroll
    for (int kst = 0; kst < 2; ++kst) {
      const s16x8 a = *(const s16x8*)&sh[3328 + kst * 32 + lg * 8];
      #pragma unroll
      for (int nt = 0; nt < 4; ++nt) {
        const s16x8 b = *(const s16x8*)(wq_bf + (nt * 16 + col) * 64 + kst * 32 + lg * 8);
        qacc[nt] = __builtin_amdgcn_mfma_f32_16x16x32_bf16(a, b, qacc[nt], 0, 0, 0);
      }
    }
    __syncthreads();
    if (lg == 0) {
      #pragma unroll
      for (int nt = 0; nt < 4; ++nt)
        sh[3328 + nt * 16 + col] = f2bf((qacc[nt][0] + ipb[nt * 16 + col]) * 0.25f);
    }
    __syncthreads();
    // ---- P3: qw[h][c] via MFMA (block-diag A) ----
    f32x4 wacc[4];
    #pragma unroll
    for (int nt = 0; nt < 4; ++nt) wacc[nt] = (f32x4){0.f, 0.f, 0.f, 0.f};
    #pragma unroll
    for (int kst = 0; kst < 2; ++kst) {
      const int hblk = kst * 2 + (lg >> 1);
      s16x8 a = {0, 0, 0, 0, 0, 0, 0, 0};
      if (col == hblk) a = *(const s16x8*)&sh[3328 + kst * 32 + lg * 8];
      #pragma unroll
      for (int nt = 0; nt < 4; ++nt) {
        const s16x8 b = *(const s16x8*)(wk2T_bf + hblk * 1024 + (nt * 16 + col) * 16 + (lg & 1) * 8);
        wacc[nt] = __builtin_amdgcn_mfma_f32_16x16x32_bf16(a, b, wacc[nt], 0, 0, 0);
      }
    }
    if (lg == 0) {
      #pragma unroll
      for (int nt = 0; nt < 4; ++nt)
        #pragma unroll
        for (int r = 0; r < 4; ++r)
          sh[3072 + r * 64 + nt * 16 + col] = f2bf(wacc[nt][r]);
    }
  }

  // ---- P5: k_in gather (bf16 table if pre2), 4-wide ----
  if (pre2) {
    #pragma unroll
    for (int half = 0; half < 2; ++half) {
      float4 ra[6]; s16x4 va[6];
      #pragma unroll
      for (int j = 0; j < 6; ++j) {
        const int k = half * 24 + j * 4 + lg;
        ra[j] = *(const float4*)(relf + k * 4);
        va[j] = *(const s16x4*)(vfb + (size_t)__float_as_int(ra[j].w) * 64 + c0);
      }
      #pragma unroll
      for (int j = 0; j < 6; ++j) {
        const int k = half * 24 + j * 4 + lg;
        const float p0 = fmaxf(kwA.x * ra[j].x + kwA.y * ra[j].y + kwA.z * ra[j].z + kbv.x, 0.f);
        const float p1 = fmaxf(kwA.w * ra[j].x + kwB.x * ra[j].y + kwB.y * ra[j].z + kbv.y, 0.f);
        const float p2 = fmaxf(kwB.z * ra[j].x + kwB.w * ra[j].y + kwC.x * ra[j].z + kbv.z, 0.f);
        const float p3 = fmaxf(kwC.y * ra[j].x + kwC.z * ra[j].y + kwC.w * ra[j].z + kbv.w, 0.f);
        s16x4 p;
        p[0] = (short)f2bf(bf2f((unsigned short)va[j][0]) + p0);
        p[1] = (short)f2bf(bf2f((unsigned short)va[j][1]) + p1);
        p[2] = (short)f2bf(bf2f((unsigned short)va[j][2]) + p2);
        p[3] = (short)f2bf(bf2f((unsigned short)va[j][3]) + p3);
        *(s16x4*)&sh[(k * 64 + c0) ^ ((k & 7) << 3)] = p;
      }
    }
  } else {
    #pragma unroll
    for (int half = 0; half < 2; ++half) {
      float4 ra[6], va[6];
      #pragma unroll
      for (int j = 0; j < 6; ++j) {
        const int k = half * 24 + j * 4 + lg;
        ra[j] = *(const float4*)(relf + k * 4);
        va[j] = *(const float4*)(vfeat + (size_t)__float_as_int(ra[j].w) * 64 + c0);
      }
      #pragma unroll
      for (int j = 0; j < 6; ++j) {
        const int k = half * 24 + j * 4 + lg;
        const float p0 = fmaxf(kwA.x * ra[j].x + kwA.y * ra[j].y + kwA.z * ra[j].z + kbv.x, 0.f);
        const float p1 = fmaxf(kwA.w * ra[j].x + kwB.x * ra[j].y + kwB.y * ra[j].z + kbv.y, 0.f);
        const float p2 = fmaxf(kwB.z * ra[j].x + kwB.w * ra[j].y + kwC.x * ra[j].z + kbv.z, 0.f);
        const float p3 = fmaxf(kwC.y * ra[j].x + kwC.z * ra[j].y + kwC.w * ra[j].z + kbv.w, 0.f);
        s16x4 p;
        p[0] = (short)f2bf(va[j].x + p0); p[1] = (short)f2bf(va[j].y + p1);
        p[2] = (short)f2bf(va[j].z + p2); p[3] = (short)f2bf(va[j].w + p3);
        *(s16x4*)&sh[(k * 64 + c0) ^ ((k & 7) << 3)] = p;
      }
    }
  }
  __syncthreads();

  // ---- P6: scores via MFMA; A-frags kept for the vv GEMM ----
  s16x8 af[3][2];
  #pragma unroll
  for (int mt = 0; mt < 3; ++mt)
    #pragma unroll
    for (int kst = 0; kst < 2; ++kst) {
      const int row = mt * 16 + col;
      af[mt][kst] = *(const s16x8*)&sh[(row * 64 + kst * 32 + lg * 8) ^ ((row & 7) << 3)];
    }
  f32x4 sc[3];
  sc[0] = sc[1] = sc[2] = (f32x4){0.f, 0.f, 0.f, 0.f};
  #pragma unroll
  for (int kst = 0; kst < 2; ++kst) {
    s16x8 b;
    if (pre) b = *(const s16x8*)(qw_pre + (size_t)m * 256 + (col & 3) * 64 + kst * 32 + lg * 8);
    else     b = *(const s16x8*)&sh[3072 + (col & 3) * 64 + kst * 32 + lg * 8];
    #pragma unroll
    for (int mt = 0; mt < 3; ++mt)
      sc[mt] = __builtin_amdgcn_mfma_f32_16x16x32_bf16(af[mt][kst], b, sc[mt], 0, 0, 0);
  }

  // ---- softmax (f32 weights in regs; head = col&3 per lane) ----
  float sv[12];
  {
    float mx = -INFINITY;
    #pragma unroll
    for (int mt = 0; mt < 3; ++mt)
      #pragma unroll
      for (int r = 0; r < 4; ++r) {
        const int key = mt * 16 + lg * 4 + r;
        float v = sc[mt][r];
        if ((bm >> key) & 1ull) v = -1e30f;
        sv[mt * 4 + r] = v;
        mx = fmaxf(mx, v);
      }
    mx = fmaxf(mx, __shfl_xor(mx, 16, 64));
    mx = fmaxf(mx, __shfl_xor(mx, 32, 64));
    float sum = 0.f;
    #pragma unroll
    for (int i = 0; i < 12; ++i) { float e = __expf(sv[i] - mx); sv[i] = e; sum += e; }
    sum += __shfl_xor(sum, 16, 64);
    sum += __shfl_xor(sum, 32, 64);
    const float inv = 1.f / sum;
    #pragma unroll
    for (int i = 0; i < 12; ++i) sv[i] *= inv;
  }

  // ---- vv = kin @ wv^T (B from LDS), then o[c] = sum_k a[h(c)][k]*vv[k][c] + bv ----
  float op[4];
  #pragma unroll
  for (int nt = 0; nt < 4; ++nt) {
    const int n = nt * 16 + col;
    f32x4 vv0 = {0.f, 0.f, 0.f, 0.f}, vv1 = vv0, vv2 = vv0;
    #pragma unroll
    for (int kst = 0; kst < 2; ++kst) {
      const s16x8 b = *(const s16x8*)&wvl[(n * 64 + kst * 32 + lg * 8) ^ ((n & 7) << 3)];
      vv0 = __builtin_amdgcn_mfma_f32_16x16x32_bf16(af[0][kst], b, vv0, 0, 0, 0);
      vv1 = __builtin_amdgcn_mfma_f32_16x16x32_bf16(af[1][kst], b, vv1, 0, 0, 0);
      vv2 = __builtin_amdgcn_mfma_f32_16x16x32_bf16(af[2][kst], b, vv2, 0, 0, 0);
    }
    const int src = lg * 16 + nt;
    float o = 0.f;
    #pragma unroll
    for (int mt = 0; mt < 3; ++mt)
      #pragma unroll
      for (int r = 0; r < 4; ++r) {
        const float a = __shfl(sv[mt * 4 + r], src, 64);
        const float v = (mt == 0) ? vv0[r] : (mt == 1) ? vv1[r] : vv2[r];
        o += a * v;
      }
    op[nt] = o;
  }
  #pragma unroll
  for (int nt = 0; nt < 4; ++nt) {
    op[nt] += __shfl_xor(op[nt], 16, 64);
    op[nt] += __shfl_xor(op[nt], 32, 64);
  }
  {
    float oo = (lg == 0) ? op[0] : (lg == 1) ? op[1] : (lg == 2) ? op[2] : op[3];
    oo += ipb[2 * CC + lg * 16 + col];
    out[(size_t)m * CC + lg * 16 + col] = oo;
  }
}

// ---------------- chain: o -> attend -> FFN -> BN -> out layer, all MFMA ----------------
__global__ __launch_bounds__(256, 2) void chain_kernel(
    float* __restrict__ inout, const unsigned short* __restrict__ wsu,
    const float* __restrict__ opb, const float* __restrict__ l1b,
    const float* __restrict__ l2b, const float* __restrict__ ob,
    const float* __restrict__ nrm, const float* __restrict__ bn2, int M)
{
  __shared__ short lds[4][5120];
  const int w = threadIdx.x >> 6;
  const int l = threadIdx.x & 63;
  const int col = l & 15, lg = l >> 4;
  const int r0 = blockIdx.x * 64 + w * 16;

  short* XH = &lds[w][0];
  short* XB = &lds[w][4096];
  const unsigned short* opw_bf = wsu + 12288;
  const unsigned short* l1_bf  = wsu + 16384;
  const unsigned short* l2_bf  = wsu + 32768;
  const unsigned short* ow_bf  = wsu + 49152;

  #pragma unroll
  for (int i = 0; i < 4; ++i) {
    int row = i * 4 + lg, cb = col * 4;
    float4 v = make_float4(0.f, 0.f, 0.f, 0.f);
    if (r0 + row < M) v = *(const float4*)(&inout[(size_t)(r0 + row) * 64 + cb]);
    s16x4 p; p[0] = (short)f2bf(v.x); p[1] = (short)f2bf(v.y);
    p[2] = (short)f2bf(v.z); p[3] = (short)f2bf(v.w);
    *(s16x4*)&XH[(row * 64 + cb) ^ ((row & 7) << 3)] = p;
  }

  s16x8 afa[2];
  #pragma unroll
  for (int kst = 0; kst < 2; ++kst)
    afa[kst] = *(const s16x8*)&XH[(col * 64 + kst * 32 + lg * 8) ^ ((col & 7) << 3)];
  f32x4 att[4];
  #pragma unroll
  for (int nt = 0; nt < 4; ++nt) {
    f32x4 acc = {0.f, 0.f, 0.f, 0.f};
    #pragma unroll
    for (int kst = 0; kst < 2; ++kst) {
      const s16x8 b = *(const s16x8*)&opw_bf[(nt * 16 + col) * 64 + kst * 32 + lg * 8];
      acc = __builtin_amdgcn_mfma_f32_16x16x32_bf16(afa[kst], b, acc, 0, 0, 0);
    }
    float bias = opb[nt * 16 + col];
    #pragma unroll
    for (int r = 0; r < 4; ++r) {
      acc[r] += bias;
      int row = lg * 4 + r;
      XB[(row * 64 + nt * 16 + col) ^ ((row & 7) << 3)] = (short)f2bf(acc[r]);
    }
    att[nt] = acc;
  }

  s16x8 afb[2];
  #pragma unroll
  for (int kst = 0; kst < 2; ++kst)
    afb[kst] = *(const s16x8*)&XB[(col * 64 + kst * 32 + lg * 8) ^ ((col & 7) << 3)];
  #pragma unroll
  for (int nt = 0; nt < 16; ++nt) {
    f32x4 acc = {0.f, 0.f, 0.f, 0.f};
    #pragma unroll
    for (int kst = 0; kst < 2; ++kst) {
      const s16x8 b = *(const s16x8*)&l1_bf[(nt * 16 + col) * 64 + kst * 32 + lg * 8];
      acc = __builtin_amdgcn_mfma_f32_16x16x32_bf16(afb[kst], b, acc, 0, 0, 0);
    }
    float bias = l1b[nt * 16 + col];
    #pragma unroll
    for (int r = 0; r < 4; ++r) {
      float h = fmaxf(acc[r] + bias, 0.f);
      int row = lg * 4 + r;
      XH[(row * 256 + nt * 16 + col) ^ ((row & 7) << 3)] = (short)f2bf(h);
    }
  }

  s16x8 afh[8];
  #pragma unroll
  for (int kst = 0; kst < 8; ++kst)
    afh[kst] = *(const s16x8*)&XH[(col * 256 + kst * 32 + lg * 8) ^ ((col & 7) << 3)];
  #pragma unroll
  for (int nt = 0; nt < 4; ++nt) {
    f32x4 acc = {0.f, 0.f, 0.f, 0.f};
    #pragma unroll
    for (int kst = 0; kst < 8; ++kst) {
      const s16x8 b = *(const s16x8*)&l2_bf[(nt * 16 + col) * 256 + kst * 32 + lg * 8];
      acc = __builtin_amdgcn_mfma_f32_16x16x32_bf16(afh[kst], b, acc, 0, 0, 0);
    }
    int nc = nt * 16 + col;
    float bias = l2b[nc], sN = nrm[nc], tN = nrm[64 + nc];
    #pragma unroll
    for (int r = 0; r < 4; ++r) {
      float x = (att[nt][r] + acc[r] + bias) * sN + tN;
      int row = lg * 4 + r;
      XB[(row * 64 + nc) ^ ((row & 7) << 3)] = (short)f2bf(x);
    }
  }

  s16x8 afx[2];
  #pragma unroll
  for (int kst = 0; kst < 2; ++kst)
    afx[kst] = *(const s16x8*)&XB[(col * 64 + kst * 32 + lg * 8) ^ ((col & 7) << 3)];
  #pragma unroll
  for (int nt = 0; nt < 4; ++nt) {
    f32x4 acc = {0.f, 0.f, 0.f, 0.f};
    #pragma unroll
    for (int kst = 0; kst < 2; ++kst) {
      const s16x8 b = *(const s16x8*)&ow_bf[(nt * 16 + col) * 64 + kst * 32 + lg * 8];
      acc = __builtin_amdgcn_mfma_f32_16x16x32_bf16(afx[kst], b, acc, 0, 0, 0);
    }
    int nc = nt * 16 + col;
    float bias = ob[nc], sB = bn2[nc], tB = bn2[64 + nc];
    #pragma unroll
    for (int r = 0; r < 4; ++r) {
      float y = fmaxf((acc[r] + bias) * sB + tB, 0.f);
      int row = lg * 4 + r;
      if (r0 + row < M) inout[(size_t)(r0 + row) * 64 + nc] = y;
    }
  }
}

extern "C" void kernel_launch(void* const* d_in, const int* in_sizes, int n_in,
                              void* d_out, int out_size, void* d_ws, size_t ws_size,
                              hipStream_t stream) {
  const float* vfeat  = (const float*)d_in[0];
  const float* vcoord = (const float*)d_in[1];
  const float* qcoord = (const float*)d_in[2];
  const int*   kidx   = (const int*)d_in[3];
  const unsigned char* km8  = (const unsigned char*)d_in[4];
  const int*           km32 = (const int*)d_in[4];
  const float* qpw = (const float*)d_in[5];
  const float* qpb = (const float*)d_in[6];
  const float* kpw = (const float*)d_in[7];
  const float* kpb = (const float*)d_in[8];
  const float* ipw = (const float*)d_in[9];
  const float* ipb = (const float*)d_in[10];
  const float* opw = (const float*)d_in[11];
  const float* opb = (const float*)d_in[12];
  const float* l1w = (const float*)d_in[13];
  const float* l1b = (const float*)d_in[14];
  const float* l2w = (const float*)d_in[15];
  const float* l2b = (const float*)d_in[16];
  const float* ng  = (const float*)d_in[17];
  const float* nb  = (const float*)d_in[18];
  const float* nm  = (const float*)d_in[19];
  const float* nv  = (const float*)d_in[20];
  const float* ow  = (const float*)d_in[21];
  const float* ob  = (const float*)d_in[22];
  const float* b2g = (const float*)d_in[23];
  const float* b2b = (const float*)d_in[24];
  const float* b2m = (const float*)d_in[25];
  const float* b2v = (const float*)d_in[26];

  const int M  = in_sizes[2] / 3;
  const int NV = in_sizes[0] / 64;
  float* ws  = (float*)d_ws;
  float* out = (float*)d_out;
  unsigned short* wsu = (unsigned short*)ws;
  const int* flag = (const int*)ws + 26880;

  const size_t need_qw = (size_t)114688 + (size_t)M * 512;
  const int pre  = (ws_size >= need_qw) ? 1 : 0;
  const int pre2 = (pre && ws_size >= need_qw + (size_t)NV * 128) ? 1 : 0;
  unsigned short* qw  = wsu + QW_OFF_U16;
  unsigned short* vfb = wsu + QW_OFF_U16 + (size_t)M * 256;

  prep_kernel<<<210, 256, 0, stream>>>(ipw, opw, l1w, l2w, ow,
                                       ng, nb, nm, nv, b2g, b2b, b2m, b2v, km8, ws);
  if (pre2)
    castv_kernel<<<2048, 256, 0, stream>>>(vfeat, vfb, NV * 16);
  if (pre)
    qprep_kernel<<<(M + 63) / 64, 256, 0, stream>>>(qcoord, qpw, qpb, ipb,
                                                    wsu, wsu + 4096, qw, M);
  attn_kernel<<<(M + 3) / 4, 256, 0, stream>>>(vfeat, vfb, vcoord, qcoord, kidx,
                                               km8, km32, flag,
                                               qpw, qpb, kpw, kpb, ipb,
                                               wsu, wsu + 4096, wsu + 8192,
                                               qw, pre, pre2, out, M);
  chain_kernel<<<(M + 63) / 64, 256, 0, stream>>>(out, wsu, opb, l1b, l2b, ob,
                                                  ws + 26624, ws + 26752, M);
}

// Round 10
// 98.077 us; speedup vs baseline: 3.9340x; 1.0251x over previous
//
#include <hip/hip_runtime.h>
#include <math.h>

#define CC 64
#define KK 48
#define HH 4

typedef __attribute__((ext_vector_type(8))) short s16x8;
typedef __attribute__((ext_vector_type(4))) short s16x4;
typedef __attribute__((ext_vector_type(4))) float f32x4;

// ws u16 layout: [0,4096) wq_bf | [4096,8192) wk2T_bf [4][64][16] | [8192,12288) wv_bf
//   [12288,16384) opw_bf | [16384,32768) l1_bf | [32768,49152) l2_bf | [49152,53248) ow_bf
// ws f32: [26624,26752) nrm s,t | [26752,26880) bn2 s,t | [26880] flag(int)
// qw: u16 off 57344 [M][4][64] | vfb: u16 off 57344+M*256 [NV][64] | vc4: float4[NV] after vfb
#define QW_OFF_U16 57344

// wave-local LDS ordering: consumers are ds_reads (memory-ordered by the clobber)
#define WAVEFENCE() asm volatile("s_waitcnt lgkmcnt(0)" ::: "memory")

__device__ __forceinline__ unsigned short f2bf(float f) {
  return (unsigned short)((__float_as_uint(f) + 0x8000u) >> 16);  // round-half-up
}
__device__ __forceinline__ float bf2f(unsigned short h) {
  return __uint_as_float(((unsigned)h) << 16);
}

// ---------------- prep: bf16 weight casts/transposes + BN folds + mask detect ----------------
__global__ __launch_bounds__(256) void prep_kernel(
    const float* __restrict__ ipw, const float* __restrict__ opw,
    const float* __restrict__ l1w, const float* __restrict__ l2w,
    const float* __restrict__ ow,
    const float* __restrict__ ng, const float* __restrict__ nb,
    const float* __restrict__ nm, const float* __restrict__ nv,
    const float* __restrict__ b2g, const float* __restrict__ b2b,
    const float* __restrict__ b2m, const float* __restrict__ b2v,
    const unsigned char* __restrict__ km,
    float* __restrict__ ws)
{
  unsigned short* wsu = (unsigned short*)ws;
  if (blockIdx.x == 209) {  // mask dtype detect: int32-bool has all bytes at i%4!=0 zero
    int any = 0;
    for (int i = threadIdx.x; i < 4096; i += 256)
      if ((i & 3) && km[i]) any = 1;
    __shared__ int sb;
    if (threadIdx.x == 0) sb = 0;
    __syncthreads();
    if (any) atomicOr(&sb, 1);
    __syncthreads();
    if (threadIdx.x == 0) ((int*)ws)[26880] = sb;
    return;
  }
  int e = blockIdx.x * 256 + threadIdx.x;
  if (e < 4096)        wsu[e] = f2bf(ipw[e]);                      // wq rows 0-63
  else if (e < 8192)  { int i = e - 4096; int h = i >> 10, c = (i >> 4) & 63, d = i & 15;
                        wsu[e] = f2bf(ipw[(size_t)(64 + h * 16 + d) * 64 + c]); }  // wk2T[h][c][d]
  else if (e < 12288)  wsu[e] = f2bf(ipw[e]);                      // wv rows 128-191
  else if (e < 16384)  wsu[e] = f2bf(opw[e - 12288]);
  else if (e < 32768)  wsu[e] = f2bf(l1w[e - 16384]);
  else if (e < 49152)  wsu[e] = f2bf(l2w[e - 32768]);
  else if (e < 53248)  wsu[e] = f2bf(ow[e - 49152]);
  else if (e < 53312) { int c = e - 53248; float s = ng[c] / sqrtf(nv[c] + 1e-5f);
                        ws[26624 + c] = s; ws[26624 + 64 + c] = nb[c] - nm[c] * s; }
  else if (e < 53376) { int c = e - 53312; float s = b2g[c] / sqrtf(b2v[c] + 1e-5f);
                        ws[26752 + c] = s; ws[26752 + 64 + c] = b2b[c] - b2m[c] * s; }
}

// ---------------- castv: vfeat f32 -> bf16 table + packed vcoord float4 ----------------
__global__ __launch_bounds__(256) void castv_kernel(
    const float* __restrict__ vf, const float* __restrict__ vcoord,
    unsigned short* __restrict__ vfb, float4* __restrict__ vc4, int NV)
{
  const int i0 = blockIdx.x * 256 + threadIdx.x;
  const int stride = gridDim.x * 256;
  for (int i = i0; i < NV * 16; i += stride) {
    const float4 v = *(const float4*)(vf + (size_t)i * 4);
    s16x4 p; p[0] = (short)f2bf(v.x); p[1] = (short)f2bf(v.y);
    p[2] = (short)f2bf(v.z); p[3] = (short)f2bf(v.w);
    *(s16x4*)(vfb + (size_t)i * 4) = p;
  }
  for (int i = i0; i < NV; i += stride)
    vc4[i] = make_float4(vcoord[i * 3], vcoord[i * 3 + 1], vcoord[i * 3 + 2], 0.f);
}

// ---------------- qprep: batched q_in -> q -> qw for all queries ----------------
__global__ __launch_bounds__(256, 2) void qprep_kernel(
    const float* __restrict__ qcoord, const float* __restrict__ qpw,
    const float* __restrict__ qpb, const float* __restrict__ ipb,
    const unsigned short* __restrict__ wq_bf,
    const unsigned short* __restrict__ wk2T_bf,
    unsigned short* __restrict__ qw_out, int M)
{
  __shared__ __align__(16) unsigned short xa[4][1024];
  __shared__ float qc[4][48];
  const int w = threadIdx.x >> 6, l = threadIdx.x & 63;
  const int col = l & 15, lg = l >> 4;
  const int r0 = blockIdx.x * 64 + w * 16;

  if (l < 48) {
    int gi = r0 * 3 + l;
    qc[w][l] = (gi < M * 3) ? qcoord[gi] : 0.f;
  }
  const int c0 = col * 4;
  const float4 wA = *(const float4*)(qpw + c0 * 3);
  const float4 wB = *(const float4*)(qpw + c0 * 3 + 4);
  const float4 wC = *(const float4*)(qpw + c0 * 3 + 8);
  const float4 bq4 = *(const float4*)(qpb + c0);
  __syncthreads();

  #pragma unroll
  for (int i = 0; i < 4; ++i) {
    const int row = i * 4 + lg;
    const float x = qc[w][row * 3 + 0], y = qc[w][row * 3 + 1], z = qc[w][row * 3 + 2];
    s16x4 p;
    p[0] = (short)f2bf(fmaxf(wA.x * x + wA.y * y + wA.z * z + bq4.x, 0.f));
    p[1] = (short)f2bf(fmaxf(wA.w * x + wB.x * y + wB.y * z + bq4.y, 0.f));
    p[2] = (short)f2bf(fmaxf(wB.z * x + wB.w * y + wC.x * z + bq4.z, 0.f));
    p[3] = (short)f2bf(fmaxf(wC.y * x + wC.z * y + wC.w * z + bq4.w, 0.f));
    *(s16x4*)&xa[w][(row * 64 + c0) ^ ((row & 7) << 3)] = p;
  }
  __syncthreads();

  {
    s16x8 af0 = *(const s16x8*)&xa[w][(col * 64 + 0 + lg * 8) ^ ((col & 7) << 3)];
    s16x8 af1 = *(const s16x8*)&xa[w][(col * 64 + 32 + lg * 8) ^ ((col & 7) << 3)];
    f32x4 qv[4];
    #pragma unroll
    for (int nt = 0; nt < 4; ++nt) {
      f32x4 acc = {0.f, 0.f, 0.f, 0.f};
      acc = __builtin_amdgcn_mfma_f32_16x16x32_bf16(af0,
              *(const s16x8*)(wq_bf + (nt * 16 + col) * 64 + 0 + lg * 8), acc, 0, 0, 0);
      acc = __builtin_amdgcn_mfma_f32_16x16x32_bf16(af1,
              *(const s16x8*)(wq_bf + (nt * 16 + col) * 64 + 32 + lg * 8), acc, 0, 0, 0);
      qv[nt] = acc;
    }
    __syncthreads();
    #pragma unroll
    for (int nt = 0; nt < 4; ++nt) {
      const int n = nt * 16 + col;
      const float b = ipb[n];
      #pragma unroll
      for (int r = 0; r < 4; ++r) {
        const int row = lg * 4 + r;
        xa[w][(row * 64 + n) ^ ((row & 7) << 3)] = f2bf((qv[nt][r] + b) * 0.25f);
      }
    }
  }
  __syncthreads();

  #pragma unroll
  for (int h = 0; h < HH; ++h) {
    s16x8 a = {0, 0, 0, 0, 0, 0, 0, 0};
    if (lg < 2)
      a = *(const s16x8*)&xa[w][(col * 64 + h * 16 + lg * 8) ^ ((col & 7) << 3)];
    #pragma unroll
    for (int nt = 0; nt < 4; ++nt) {
      s16x8 b = {0, 0, 0, 0, 0, 0, 0, 0};
      if (lg < 2)
        b = *(const s16x8*)(wk2T_bf + h * 1024 + (nt * 16 + col) * 16 + lg * 8);
      f32x4 acc = {0.f, 0.f, 0.f, 0.f};
      acc = __builtin_amdgcn_mfma_f32_16x16x32_bf16(a, b, acc, 0, 0, 0);
      #pragma unroll
      for (int r = 0; r < 4; ++r) {
        const int m = lg * 4 + r;
        if (r0 + m < M)
          qw_out[(size_t)(r0 + m) * 256 + h * 64 + nt * 16 + col] = f2bf(acc[r]);
      }
    }
  }
}

// ---------------- attn_hot: lean path (qw/vfb/vc4 all precomputed) ----------------
// per-query LDS (u16): kin [0,3072) swizzled | rel f32[48][4] @3072 (reused as a[48][4])
__global__ __launch_bounds__(256, 4) void attn_hot(
    const unsigned short* __restrict__ vfb, const float4* __restrict__ vc4,
    const float* __restrict__ qcoord, const int* __restrict__ kidx,
    const unsigned char* __restrict__ km8, const int* __restrict__ km32,
    const int* __restrict__ maskfmt,
    const float* __restrict__ kpw, const float* __restrict__ kpb,
    const float* __restrict__ ipb,
    const unsigned short* __restrict__ wv_bf,
    const unsigned short* __restrict__ qw_pre,
    float* __restrict__ out, int M)
{
  __shared__ __align__(16) unsigned short shq[4][3456];
  __shared__ __align__(16) unsigned short wvl[4096];
  const int w = threadIdx.x >> 6, l = threadIdx.x & 63;
  const int col = l & 15, lg = l >> 4;
  int m = blockIdx.x * 4 + w;
  if (m >= M) m = M - 1;                 // benign duplicate of last query
  unsigned short* sh = shq[w];
  float* relf = (float*)(sh + 3072);     // rel, later a[key][head]
  const int is_u8 = *maskfmt;

  // stage wv into swizzled LDS (once per block)
  #pragma unroll
  for (int i = 0; i < 2; ++i) {
    const int ch = threadIdx.x * 2 + i;
    const int n = ch >> 3, g = ch & 7;
    const s16x8 v = *(const s16x8*)(wv_bf + n * 64 + g * 8);
    *(s16x8*)&wvl[n * 64 + ((g ^ (n & 7)) << 3)] = v;
  }

  const float qx = qcoord[m * 3 + 0], qy = qcoord[m * 3 + 1], qz = qcoord[m * 3 + 2];
  const int c0 = col * 4;
  const float4 kwA = *(const float4*)(kpw + c0 * 3);
  const float4 kwB = *(const float4*)(kpw + c0 * 3 + 4);
  const float4 kwC = *(const float4*)(kpw + c0 * 3 + 8);
  const float4 kbv = *(const float4*)(kpb + c0);

  // ---- P1: rel coords (one dwordx4 gather) / indices / mask ----
  unsigned char msk = 0;
  if (l < KK) {
    const int idx = kidx[m * KK + l];
    msk = is_u8 ? km8[m * KK + l] : (unsigned char)(km32[m * KK + l] != 0);
    const float4 vc = vc4[idx];
    float4 rr;
    rr.x = vc.x - qx; rr.y = vc.y - qy; rr.z = vc.z - qz;
    rr.w = __int_as_float(idx);
    *(float4*)(relf + l * 4) = rr;
  }
  const unsigned long long bm = __ballot(l < KK && msk);
  __syncthreads();                       // covers wvl (cross-wave) + relf

  // ---- P5: k_in gather (bf16 table), 4-wide ----
  #pragma unroll
  for (int half = 0; half < 2; ++half) {
    float4 ra[6]; s16x4 va[6];
    #pragma unroll
    for (int j = 0; j < 6; ++j) {
      const int k = half * 24 + j * 4 + lg;
      ra[j] = *(const float4*)(relf + k * 4);
      va[j] = *(const s16x4*)(vfb + (size_t)__float_as_int(ra[j].w) * 64 + c0);
    }
    #pragma unroll
    for (int j = 0; j < 6; ++j) {
      const int k = half * 24 + j * 4 + lg;
      const float p0 = fmaxf(kwA.x * ra[j].x + kwA.y * ra[j].y + kwA.z * ra[j].z + kbv.x, 0.f);
      const float p1 = fmaxf(kwA.w * ra[j].x + kwB.x * ra[j].y + kwB.y * ra[j].z + kbv.y, 0.f);
      const float p2 = fmaxf(kwB.z * ra[j].x + kwB.w * ra[j].y + kwC.x * ra[j].z + kbv.z, 0.f);
      const float p3 = fmaxf(kwC.y * ra[j].x + kwC.z * ra[j].y + kwC.w * ra[j].z + kbv.w, 0.f);
      s16x4 p;
      p[0] = (short)f2bf(bf2f((unsigned short)va[j][0]) + p0);
      p[1] = (short)f2bf(bf2f((unsigned short)va[j][1]) + p1);
      p[2] = (short)f2bf(bf2f((unsigned short)va[j][2]) + p2);
      p[3] = (short)f2bf(bf2f((unsigned short)va[j][3]) + p3);
      *(s16x4*)&sh[(k * 64 + c0) ^ ((k & 7) << 3)] = p;
    }
  }
  WAVEFENCE();                           // kin is wave-private: no block barrier

  // ---- P6: scores via MFMA; A-frags kept for the vv GEMM ----
  s16x8 af[3][2];
  #pragma unroll
  for (int mt = 0; mt < 3; ++mt)
    #pragma unroll
    for (int kst = 0; kst < 2; ++kst) {
      const int row = mt * 16 + col;
      af[mt][kst] = *(const s16x8*)&sh[(row * 64 + kst * 32 + lg * 8) ^ ((row & 7) << 3)];
    }
  f32x4 sc[3];
  sc[0] = sc[1] = sc[2] = (f32x4){0.f, 0.f, 0.f, 0.f};
  #pragma unroll
  for (int kst = 0; kst < 2; ++kst) {
    const s16x8 b = *(const s16x8*)(qw_pre + (size_t)m * 256 + (col & 3) * 64 + kst * 32 + lg * 8);
    #pragma unroll
    for (int mt = 0; mt < 3; ++mt)
      sc[mt] = __builtin_amdgcn_mfma_f32_16x16x32_bf16(af[mt][kst], b, sc[mt], 0, 0, 0);
  }

  // ---- softmax (head = col&3 per lane) ----
  float sv[12];
  {
    float mx = -INFINITY;
    #pragma unroll
    for (int mt = 0; mt < 3; ++mt)
      #pragma unroll
      for (int r = 0; r < 4; ++r) {
        const int key = mt * 16 + lg * 4 + r;
        float v = sc[mt][r];
        if ((bm >> key) & 1ull) v = -1e30f;
        sv[mt * 4 + r] = v;
        mx = fmaxf(mx, v);
      }
    mx = fmaxf(mx, __shfl_xor(mx, 16, 64));
    mx = fmaxf(mx, __shfl_xor(mx, 32, 64));
    float sum = 0.f;
    #pragma unroll
    for (int i = 0; i < 12; ++i) { float e = __expf(sv[i] - mx); sv[i] = e; sum += e; }
    sum += __shfl_xor(sum, 16, 64);
    sum += __shfl_xor(sum, 32, 64);
    const float inv = 1.f / sum;
    #pragma unroll
    for (int i = 0; i < 12; ++i) sv[i] *= inv;
  }
  // rel is dead: store a[key][head] f32 in its place (lanes col<4 own heads)
  if (col < HH) {
    #pragma unroll
    for (int mt = 0; mt < 3; ++mt)
      #pragma unroll
      for (int r = 0; r < 4; ++r)
        relf[(mt * 16 + lg * 4 + r) * 4 + col] = sv[mt * 4 + r];
  }
  WAVEFENCE();

  // ---- vv = kin @ wv^T (all nt), then o[c] = sum_k a[k][h(c)]*vv[k][c] + bv ----
  f32x4 vva[4][3];
  #pragma unroll
  for (int nt = 0; nt < 4; ++nt) {
    const int n = nt * 16 + col;
    vva[nt][0] = vva[nt][1] = vva[nt][2] = (f32x4){0.f, 0.f, 0.f, 0.f};
    #pragma unroll
    for (int kst = 0; kst < 2; ++kst) {
      const s16x8 b = *(const s16x8*)&wvl[(n * 64 + kst * 32 + lg * 8) ^ ((n & 7) << 3)];
      vva[nt][0] = __builtin_amdgcn_mfma_f32_16x16x32_bf16(af[0][kst], b, vva[nt][0], 0, 0, 0);
      vva[nt][1] = __builtin_amdgcn_mfma_f32_16x16x32_bf16(af[1][kst], b, vva[nt][1], 0, 0, 0);
      vva[nt][2] = __builtin_amdgcn_mfma_f32_16x16x32_bf16(af[2][kst], b, vva[nt][2], 0, 0, 0);
    }
  }
  float op[4] = {0.f, 0.f, 0.f, 0.f};
  #pragma unroll
  for (int mt = 0; mt < 3; ++mt)
    #pragma unroll
    for (int r = 0; r < 4; ++r) {
      const float4 a4 = *(const float4*)(relf + (mt * 16 + lg * 4 + r) * 4);  // broadcast
      op[0] += a4.x * vva[0][mt][r];
      op[1] += a4.y * vva[1][mt][r];
      op[2] += a4.z * vva[2][mt][r];
      op[3] += a4.w * vva[3][mt][r];
    }
  #pragma unroll
  for (int nt = 0; nt < 4; ++nt) {
    op[nt] += __shfl_xor(op[nt], 16, 64);
    op[nt] += __shfl_xor(op[nt], 32, 64);
  }
  {
    float oo = (lg == 0) ? op[0] : (lg == 1) ? op[1] : (lg == 2) ? op[2] : op[3];
    oo += ipb[2 * CC + lg * 16 + col];
    out[(size_t)m * CC + lg * 16 + col] = oo;
  }
}

// ---------------- attn_kernel: r9 full fallback (ws too small) ----------------
__global__ __launch_bounds__(256, 4) void attn_kernel(
    const float* __restrict__ vfeat, const unsigned short* __restrict__ vfb,
    const float* __restrict__ vcoord,
    const float* __restrict__ qcoord, const int* __restrict__ kidx,
    const unsigned char* __restrict__ km8, const int* __restrict__ km32,
    const int* __restrict__ maskfmt,
    const float* __restrict__ qpw, const float* __restrict__ qpb,
    const float* __restrict__ kpw, const float* __restrict__ kpb,
    const float* __restrict__ ipb,
    const unsigned short* __restrict__ wq_bf,
    const unsigned short* __restrict__ wk2T_bf,
    const unsigned short* __restrict__ wv_bf,
    const unsigned short* __restrict__ qw_pre, const int pre, const int pre2,
    float* __restrict__ out, int M)
{
  __shared__ __align__(16) unsigned short shq[4][3776];
  __shared__ __align__(16) unsigned short wvl[4096];
  const int w = threadIdx.x >> 6, l = threadIdx.x & 63;
  const int col = l & 15, lg = l >> 4;
  int m = blockIdx.x * 4 + w;
  if (m >= M) m = M - 1;
  unsigned short* sh = shq[w];
  const int is_u8 = *maskfmt;
  float* relf = (float*)sh + 1696;

  #pragma unroll
  for (int i = 0; i < 2; ++i) {
    const int ch = threadIdx.x * 2 + i;
    const int n = ch >> 3, g = ch & 7;
    const s16x8 v = *(const s16x8*)(wv_bf + n * 64 + g * 8);
    *(s16x8*)&wvl[n * 64 + ((g ^ (n & 7)) << 3)] = v;
  }

  const float qx = qcoord[m * 3 + 0], qy = qcoord[m * 3 + 1], qz = qcoord[m * 3 + 2];
  const int c0 = col * 4;
  const float4 kwA = *(const float4*)(kpw + c0 * 3);
  const float4 kwB = *(const float4*)(kpw + c0 * 3 + 4);
  const float4 kwC = *(const float4*)(kpw + c0 * 3 + 8);
  const float4 kbv = *(const float4*)(kpb + c0);

  if (!pre) {
    float v = qpw[l * 3 + 0] * qx + qpw[l * 3 + 1] * qy + qpw[l * 3 + 2] * qz + qpb[l];
    sh[3328 + l] = f2bf(fmaxf(v, 0.f));
  }
  unsigned char msk = 0;
  if (l < KK) {
    int idx = kidx[m * KK + l];
    msk = is_u8 ? km8[m * KK + l] : (unsigned char)(km32[m * KK + l] != 0);
    relf[l * 4 + 0] = vcoord[idx * 3 + 0] - qx;
    relf[l * 4 + 1] = vcoord[idx * 3 + 1] - qy;
    relf[l * 4 + 2] = vcoord[idx * 3 + 2] - qz;
    relf[l * 4 + 3] = __int_as_float(idx);
  }
  const unsigned long long bm = __ballot(l < KK && msk);
  __syncthreads();

  if (!pre) {
    f32x4 qacc[4];
    #pragma unroll
    for (int nt = 0; nt < 4; ++nt) qacc[nt] = (f32x4){0.f, 0.f, 0.f, 0.f};
    #pragma unroll
    for (int kst = 0; kst < 2; ++kst) {
      const s16x8 a = *(const s16x8*)&sh[3328 + kst * 32 + lg * 8];
      #pragma unroll
      for (int nt = 0; nt < 4; ++nt) {
        const s16x8 b = *(const s16x8*)(wq_bf + (nt * 16 + col) * 64 + kst * 32 + lg * 8);
        qacc[nt] = __builtin_amdgcn_mfma_f32_16x16x32_bf16(a, b, qacc[nt], 0, 0, 0);
      }
    }
    __syncthreads();
    if (lg == 0) {
      #pragma unroll
      for (int nt = 0; nt < 4; ++nt)
        sh[3328 + nt * 16 + col] = f2bf((qacc[nt][0] + ipb[nt * 16 + col]) * 0.25f);
    }
    __syncthreads();
    f32x4 wacc[4];
    #pragma unroll
    for (int nt = 0; nt < 4; ++nt) wacc[nt] = (f32x4){0.f, 0.f, 0.f, 0.f};
    #pragma unroll
    for (int kst = 0; kst < 2; ++kst) {
      const int hblk = kst * 2 + (lg >> 1);
      s16x8 a = {0, 0, 0, 0, 0, 0, 0, 0};
      if (col == hblk) a = *(const s16x8*)&sh[3328 + kst * 32 + lg * 8];
      #pragma unroll
      for (int nt = 0; nt < 4; ++nt) {
        const s16x8 b = *(const s16x8*)(wk2T_bf + hblk * 1024 + (nt * 16 + col) * 16 + (lg & 1) * 8);
        wacc[nt] = __builtin_amdgcn_mfma_f32_16x16x32_bf16(a, b, wacc[nt], 0, 0, 0);
      }
    }
    if (lg == 0) {
      #pragma unroll
      for (int nt = 0; nt < 4; ++nt)
        #pragma unroll
        for (int r = 0; r < 4; ++r)
          sh[3072 + r * 64 + nt * 16 + col] = f2bf(wacc[nt][r]);
    }
  }

  #pragma unroll
  for (int half = 0; half < 2; ++half) {
    float4 ra[6], va[6];
    #pragma unroll
    for (int j = 0; j < 6; ++j) {
      const int k = half * 24 + j * 4 + lg;
      ra[j] = *(const float4*)(relf + k * 4);
      va[j] = *(const float4*)(vfeat + (size_t)__float_as_int(ra[j].w) * 64 + c0);
    }
    #pragma unroll
    for (int j = 0; j < 6; ++j) {
      const int k = half * 24 + j * 4 + lg;
      const float p0 = fmaxf(kwA.x * ra[j].x + kwA.y * ra[j].y + kwA.z * ra[j].z + kbv.x, 0.f);
      const float p1 = fmaxf(kwA.w * ra[j].x + kwB.x * ra[j].y + kwB.y * ra[j].z + kbv.y, 0.f);
      const float p2 = fmaxf(kwB.z * ra[j].x + kwB.w * ra[j].y + kwC.x * ra[j].z + kbv.z, 0.f);
      const float p3 = fmaxf(kwC.y * ra[j].x + kwC.z * ra[j].y + kwC.w * ra[j].z + kbv.w, 0.f);
      s16x4 p;
      p[0] = (short)f2bf(va[j].x + p0); p[1] = (short)f2bf(va[j].y + p1);
      p[2] = (short)f2bf(va[j].z + p2); p[3] = (short)f2bf(va[j].w + p3);
      *(s16x4*)&sh[(k * 64 + c0) ^ ((k & 7) << 3)] = p;
    }
  }
  __syncthreads();

  s16x8 af[3][2];
  #pragma unroll
  for (int mt = 0; mt < 3; ++mt)
    #pragma unroll
    for (int kst = 0; kst < 2; ++kst) {
      const int row = mt * 16 + col;
      af[mt][kst] = *(const s16x8*)&sh[(row * 64 + kst * 32 + lg * 8) ^ ((row & 7) << 3)];
    }
  f32x4 sc[3];
  sc[0] = sc[1] = sc[2] = (f32x4){0.f, 0.f, 0.f, 0.f};
  #pragma unroll
  for (int kst = 0; kst < 2; ++kst) {
    s16x8 b;
    if (pre) b = *(const s16x8*)(qw_pre + (size_t)m * 256 + (col & 3) * 64 + kst * 32 + lg * 8);
    else     b = *(const s16x8*)&sh[3072 + (col & 3) * 64 + kst * 32 + lg * 8];
    #pragma unroll
    for (int mt = 0; mt < 3; ++mt)
      sc[mt] = __builtin_amdgcn_mfma_f32_16x16x32_bf16(af[mt][kst], b, sc[mt], 0, 0, 0);
  }

  float sv[12];
  {
    float mx = -INFINITY;
    #pragma unroll
    for (int mt = 0; mt < 3; ++mt)
      #pragma unroll
      for (int r = 0; r < 4; ++r) {
        const int key = mt * 16 + lg * 4 + r;
        float v = sc[mt][r];
        if ((bm >> key) & 1ull) v = -1e30f;
        sv[mt * 4 + r] = v;
        mx = fmaxf(mx, v);
      }
    mx = fmaxf(mx, __shfl_xor(mx, 16, 64));
    mx = fmaxf(mx, __shfl_xor(mx, 32, 64));
    float sum = 0.f;
    #pragma unroll
    for (int i = 0; i < 12; ++i) { float e = __expf(sv[i] - mx); sv[i] = e; sum += e; }
    sum += __shfl_xor(sum, 16, 64);
    sum += __shfl_xor(sum, 32, 64);
    const float inv = 1.f / sum;
    #pragma unroll
    for (int i = 0; i < 12; ++i) sv[i] *= inv;
  }

  float op[4];
  #pragma unroll
  for (int nt = 0; nt < 4; ++nt) {
    const int n = nt * 16 + col;
    f32x4 vv0 = {0.f, 0.f, 0.f, 0.f}, vv1 = vv0, vv2 = vv0;
    #pragma unroll
    for (int kst = 0; kst < 2; ++kst) {
      const s16x8 b = *(const s16x8*)&wvl[(n * 64 + kst * 32 + lg * 8) ^ ((n & 7) << 3)];
      vv0 = __builtin_amdgcn_mfma_f32_16x16x32_bf16(af[0][kst], b, vv0, 0, 0, 0);
      vv1 = __builtin_amdgcn_mfma_f32_16x16x32_bf16(af[1][kst], b, vv1, 0, 0, 0);
      vv2 = __builtin_amdgcn_mfma_f32_16x16x32_bf16(af[2][kst], b, vv2, 0, 0, 0);
    }
    const int src = lg * 16 + nt;
    float o = 0.f;
    #pragma unroll
    for (int mt = 0; mt < 3; ++mt)
      #pragma unroll
      for (int r = 0; r < 4; ++r) {
        const float a = __shfl(sv[mt * 4 + r], src, 64);
        const float v = (mt == 0) ? vv0[r] : (mt == 1) ? vv1[r] : vv2[r];
        o += a * v;
      }
    op[nt] = o;
  }
  #pragma unroll
  for (int nt = 0; nt < 4; ++nt) {
    op[nt] += __shfl_xor(op[nt], 16, 64);
    op[nt] += __shfl_xor(op[nt], 32, 64);
  }
  {
    float oo = (lg == 0) ? op[0] : (lg == 1) ? op[1] : (lg == 2) ? op[2] : op[3];
    oo += ipb[2 * CC + lg * 16 + col];
    out[(size_t)m * CC + lg * 16 + col] = oo;
  }
}

// ---------------- chain: o -> attend -> FFN -> BN -> out layer, all MFMA ----------------
__global__ __launch_bounds__(256, 2) void chain_kernel(
    float* __restrict__ inout, const unsigned short* __restrict__ wsu,
    const float* __restrict__ opb, const float* __restrict__ l1b,
    const float* __restrict__ l2b, const float* __restrict__ ob,
    const float* __restrict__ nrm, const float* __restrict__ bn2, int M)
{
  __shared__ short lds[4][5120];
  const int w = threadIdx.x >> 6;
  const int l = threadIdx.x & 63;
  const int col = l & 15, lg = l >> 4;
  const int r0 = blockIdx.x * 64 + w * 16;

  short* XH = &lds[w][0];
  short* XB = &lds[w][4096];
  const unsigned short* opw_bf = wsu + 12288;
  const unsigned short* l1_bf  = wsu + 16384;
  const unsigned short* l2_bf  = wsu + 32768;
  const unsigned short* ow_bf  = wsu + 49152;

  #pragma unroll
  for (int i = 0; i < 4; ++i) {
    int row = i * 4 + lg, cb = col * 4;
    float4 v = make_float4(0.f, 0.f, 0.f, 0.f);
    if (r0 + row < M) v = *(const float4*)(&inout[(size_t)(r0 + row) * 64 + cb]);
    s16x4 p; p[0] = (short)f2bf(v.x); p[1] = (short)f2bf(v.y);
    p[2] = (short)f2bf(v.z); p[3] = (short)f2bf(v.w);
    *(s16x4*)&XH[(row * 64 + cb) ^ ((row & 7) << 3)] = p;
  }

  s16x8 afa[2];
  #pragma unroll
  for (int kst = 0; kst < 2; ++kst)
    afa[kst] = *(const s16x8*)&XH[(col * 64 + kst * 32 + lg * 8) ^ ((col & 7) << 3)];
  f32x4 att[4];
  #pragma unroll
  for (int nt = 0; nt < 4; ++nt) {
    f32x4 acc = {0.f, 0.f, 0.f, 0.f};
    #pragma unroll
    for (int kst = 0; kst < 2; ++kst) {
      const s16x8 b = *(const s16x8*)&opw_bf[(nt * 16 + col) * 64 + kst * 32 + lg * 8];
      acc = __builtin_amdgcn_mfma_f32_16x16x32_bf16(afa[kst], b, acc, 0, 0, 0);
    }
    float bias = opb[nt * 16 + col];
    #pragma unroll
    for (int r = 0; r < 4; ++r) {
      acc[r] += bias;
      int row = lg * 4 + r;
      XB[(row * 64 + nt * 16 + col) ^ ((row & 7) << 3)] = (short)f2bf(acc[r]);
    }
    att[nt] = acc;
  }

  s16x8 afb[2];
  #pragma unroll
  for (int kst = 0; kst < 2; ++kst)
    afb[kst] = *(const s16x8*)&XB[(col * 64 + kst * 32 + lg * 8) ^ ((col & 7) << 3)];
  #pragma unroll
  for (int nt = 0; nt < 16; ++nt) {
    f32x4 acc = {0.f, 0.f, 0.f, 0.f};
    #pragma unroll
    for (int kst = 0; kst < 2; ++kst) {
      const s16x8 b = *(const s16x8*)&l1_bf[(nt * 16 + col) * 64 + kst * 32 + lg * 8];
      acc = __builtin_amdgcn_mfma_f32_16x16x32_bf16(afb[kst], b, acc, 0, 0, 0);
    }
    float bias = l1b[nt * 16 + col];
    #pragma unroll
    for (int r = 0; r < 4; ++r) {
      float h = fmaxf(acc[r] + bias, 0.f);
      int row = lg * 4 + r;
      XH[(row * 256 + nt * 16 + col) ^ ((row & 7) << 3)] = (short)f2bf(h);
    }
  }

  s16x8 afh[8];
  #pragma unroll
  for (int kst = 0; kst < 8; ++kst)
    afh[kst] = *(const s16x8*)&XH[(col * 256 + kst * 32 + lg * 8) ^ ((col & 7) << 3)];
  #pragma unroll
  for (int nt = 0; nt < 4; ++nt) {
    f32x4 acc = {0.f, 0.f, 0.f, 0.f};
    #pragma unroll
    for (int kst = 0; kst < 8; ++kst) {
      const s16x8 b = *(const s16x8*)&l2_bf[(nt * 16 + col) * 256 + kst * 32 + lg * 8];
      acc = __builtin_amdgcn_mfma_f32_16x16x32_bf16(afh[kst], b, acc, 0, 0, 0);
    }
    int nc = nt * 16 + col;
    float bias = l2b[nc], sN = nrm[nc], tN = nrm[64 + nc];
    #pragma unroll
    for (int r = 0; r < 4; ++r) {
      float x = (att[nt][r] + acc[r] + bias) * sN + tN;
      int row = lg * 4 + r;
      XB[(row * 64 + nc) ^ ((row & 7) << 3)] = (short)f2bf(x);
    }
  }

  s16x8 afx[2];
  #pragma unroll
  for (int kst = 0; kst < 2; ++kst)
    afx[kst] = *(const s16x8*)&XB[(col * 64 + kst * 32 + lg * 8) ^ ((col & 7) << 3)];
  #pragma unroll
  for (int nt = 0; nt < 4; ++nt) {
    f32x4 acc = {0.f, 0.f, 0.f, 0.f};
    #pragma unroll
    for (int kst = 0; kst < 2; ++kst) {
      const s16x8 b = *(const s16x8*)&ow_bf[(nt * 16 + col) * 64 + kst * 32 + lg * 8];
      acc = __builtin_amdgcn_mfma_f32_16x16x32_bf16(afx[kst], b, acc, 0, 0, 0);
    }
    int nc = nt * 16 + col;
    float bias = ob[nc], sB = bn2[nc], tB = bn2[64 + nc];
    #pragma unroll
    for (int r = 0; r < 4; ++r) {
      float y = fmaxf((acc[r] + bias) * sB + tB, 0.f);
      int row = lg * 4 + r;
      if (r0 + row < M) inout[(size_t)(r0 + row) * 64 + nc] = y;
    }
  }
}

extern "C" void kernel_launch(void* const* d_in, const int* in_sizes, int n_in,
                              void* d_out, int out_size, void* d_ws, size_t ws_size,
                              hipStream_t stream) {
  const float* vfeat  = (const float*)d_in[0];
  const float* vcoord = (const float*)d_in[1];
  const float* qcoord = (const float*)d_in[2];
  const int*   kidx   = (const int*)d_in[3];
  const unsigned char* km8  = (const unsigned char*)d_in[4];
  const int*           km32 = (const int*)d_in[4];
  const float* qpw = (const float*)d_in[5];
  const float* qpb = (const float*)d_in[6];
  const float* kpw = (const float*)d_in[7];
  const float* kpb = (const float*)d_in[8];
  const float* ipw = (const float*)d_in[9];
  const float* ipb = (const float*)d_in[10];
  const float* opw = (const float*)d_in[11];
  const float* opb = (const float*)d_in[12];
  const float* l1w = (const float*)d_in[13];
  const float* l1b = (const float*)d_in[14];
  const float* l2w = (const float*)d_in[15];
  const float* l2b = (const float*)d_in[16];
  const float* ng  = (const float*)d_in[17];
  const float* nb  = (const float*)d_in[18];
  const float* nm  = (const float*)d_in[19];
  const float* nv  = (const float*)d_in[20];
  const float* ow  = (const float*)d_in[21];
  const float* ob  = (const float*)d_in[22];
  const float* b2g = (const float*)d_in[23];
  const float* b2b = (const float*)d_in[24];
  const float* b2m = (const float*)d_in[25];
  const float* b2v = (const float*)d_in[26];

  const int M  = in_sizes[2] / 3;
  const int NV = in_sizes[0] / 64;
  float* ws  = (float*)d_ws;
  float* out = (float*)d_out;
  unsigned short* wsu = (unsigned short*)ws;
  const int* flag = (const int*)ws + 26880;

  const size_t need_qw  = (size_t)114688 + (size_t)M * 512;
  const size_t need_vfb = need_qw + (size_t)NV * 128;
  const size_t need_vc4 = need_vfb + (size_t)NV * 16;
  const int pre  = (ws_size >= need_qw) ? 1 : 0;
  const int pre2 = (pre && ws_size >= need_vfb) ? 1 : 0;
  const int hot  = (pre2 && ws_size >= need_vc4) ? 1 : 0;
  unsigned short* qw  = wsu + QW_OFF_U16;
  unsigned short* vfb = wsu + QW_OFF_U16 + (size_t)M * 256;
  float4* vc4 = (float4*)(wsu + QW_OFF_U16 + (size_t)M * 256 + (size_t)NV * 64);

  prep_kernel<<<210, 256, 0, stream>>>(ipw, opw, l1w, l2w, ow,
                                       ng, nb, nm, nv, b2g, b2b, b2m, b2v, km8, ws);
  if (hot)
    castv_kernel<<<2048, 256, 0, stream>>>(vfeat, vcoord, vfb, vc4, NV);
  if (pre)
    qprep_kernel<<<(M + 63) / 64, 256, 0, stream>>>(qcoord, qpw, qpb, ipb,
                                                    wsu, wsu + 4096, qw, M);
  if (hot) {
    attn_hot<<<(M + 3) / 4, 256, 0, stream>>>(vfb, vc4, qcoord, kidx,
                                              km8, km32, flag, kpw, kpb, ipb,
                                              wsu + 8192, qw, out, M);
  } else {
    attn_kernel<<<(M + 3) / 4, 256, 0, stream>>>(vfeat, vfb, vcoord, qcoord, kidx,
                                                 km8, km32, flag,
                                                 qpw, qpb, kpw, kpb, ipb,
                                                 wsu, wsu + 4096, wsu + 8192,
                                                 qw, pre, 0, out, M);
  }
  chain_kernel<<<(M + 63) / 64, 256, 0, stream>>>(out, wsu, opb, l1b, l2b, ob,
                                                  ws + 26624, ws + 26752, M);
}

// Round 11
// 93.799 us; speedup vs baseline: 4.1134x; 1.0456x over previous
//
#include <hip/hip_runtime.h>
#include <math.h>

#define CC 64
#define KK 48
#define HH 4

typedef __attribute__((ext_vector_type(8))) short s16x8;
typedef __attribute__((ext_vector_type(4))) short s16x4;
typedef __attribute__((ext_vector_type(4))) float f32x4;

// ws u16 layout: [0,4096) wq_bf | [4096,8192) wk2T_bf [4][64][16] | [8192,12288) wv_bf
//   [12288,16384) opw_bf | [16384,32768) l1_bf | [32768,49152) l2_bf | [49152,53248) ow_bf
// ws f32: [26624,26752) nrm s,t | [26752,26880) bn2 s,t | [26880] flag(int)
// qw: u16 off 57344 [M][4][64] | vfb: u16 off 57344+M*256 [NV][64] | vc4: float4[NV] after vfb
#define QW_OFF_U16 57344
#define CASTB 1024

#define WAVEFENCE() asm volatile("s_waitcnt lgkmcnt(0)" ::: "memory")

__device__ __forceinline__ unsigned short f2bf(float f) {
  return (unsigned short)((__float_as_uint(f) + 0x8000u) >> 16);  // round-half-up
}
__device__ __forceinline__ float bf2f(unsigned short h) {
  return __uint_as_float(((unsigned)h) << 16);
}

// ---------------- fused setup: prep [0,210) | castv [210,210+CASTB) | qprep rest ----------------
__global__ __launch_bounds__(256) void setup_kernel(
    const float* __restrict__ ipw, const float* __restrict__ opw,
    const float* __restrict__ l1w, const float* __restrict__ l2w,
    const float* __restrict__ ow,
    const float* __restrict__ ng, const float* __restrict__ nb,
    const float* __restrict__ nm, const float* __restrict__ nv,
    const float* __restrict__ b2g, const float* __restrict__ b2b,
    const float* __restrict__ b2m, const float* __restrict__ b2v,
    const unsigned char* __restrict__ km,
    const float* __restrict__ vf, const float* __restrict__ vcoord,
    const float* __restrict__ qcoord, const float* __restrict__ qpw,
    const float* __restrict__ qpb, const float* __restrict__ ipb,
    float* __restrict__ ws,
    unsigned short* __restrict__ vfb, float4* __restrict__ vc4,
    unsigned short* __restrict__ qw_out, int M, int NV)
{
  unsigned short* wsu = (unsigned short*)ws;
  const int b = blockIdx.x;

  if (b < 210) {                       // ---- prep part ----
    if (b == 209) {                    // mask dtype detect
      int any = 0;
      for (int i = threadIdx.x; i < 4096; i += 256)
        if ((i & 3) && km[i]) any = 1;
      __shared__ int sb;
      if (threadIdx.x == 0) sb = 0;
      __syncthreads();
      if (any) atomicOr(&sb, 1);
      __syncthreads();
      if (threadIdx.x == 0) ((int*)ws)[26880] = sb;
      return;
    }
    int e = b * 256 + threadIdx.x;
    if (e < 4096)        wsu[e] = f2bf(ipw[e]);
    else if (e < 8192)  { int i = e - 4096; int h = i >> 10, c = (i >> 4) & 63, d = i & 15;
                          wsu[e] = f2bf(ipw[(size_t)(64 + h * 16 + d) * 64 + c]); }
    else if (e < 12288)  wsu[e] = f2bf(ipw[e]);
    else if (e < 16384)  wsu[e] = f2bf(opw[e - 12288]);
    else if (e < 32768)  wsu[e] = f2bf(l1w[e - 16384]);
    else if (e < 49152)  wsu[e] = f2bf(l2w[e - 32768]);
    else if (e < 53248)  wsu[e] = f2bf(ow[e - 49152]);
    else if (e < 53312) { int c = e - 53248; float s = ng[c] / sqrtf(nv[c] + 1e-5f);
                          ws[26624 + c] = s; ws[26624 + 64 + c] = nb[c] - nm[c] * s; }
    else if (e < 53376) { int c = e - 53312; float s = b2g[c] / sqrtf(b2v[c] + 1e-5f);
                          ws[26752 + c] = s; ws[26752 + 64 + c] = b2b[c] - b2m[c] * s; }
    return;
  }

  if (b < 210 + CASTB) {               // ---- castv part (grid-stride) ----
    const int i0 = (b - 210) * 256 + threadIdx.x;
    const int stride = CASTB * 256;
    for (int i = i0; i < NV * 16; i += stride) {
      const float4 v = *(const float4*)(vf + (size_t)i * 4);
      s16x4 p; p[0] = (short)f2bf(v.x); p[1] = (short)f2bf(v.y);
      p[2] = (short)f2bf(v.z); p[3] = (short)f2bf(v.w);
      *(s16x4*)(vfb + (size_t)i * 4) = p;
    }
    for (int i = i0; i < NV; i += stride)
      vc4[i] = make_float4(vcoord[i * 3], vcoord[i * 3 + 1], vcoord[i * 3 + 2], 0.f);
    return;
  }

  // ---- qprep part: reads ipw f32 directly (inline bf16 cast == prep's rounding) ----
  {
    __shared__ __align__(16) unsigned short xa[4][1024];
    __shared__ float qc[4][48];
    const int w = threadIdx.x >> 6, l = threadIdx.x & 63;
    const int col = l & 15, lg = l >> 4;
    const int r0 = (b - 210 - CASTB) * 64 + w * 16;

    if (l < 48) {
      int gi = r0 * 3 + l;
      qc[w][l] = (gi < M * 3) ? qcoord[gi] : 0.f;
    }
    const int c0 = col * 4;
    const float4 wA = *(const float4*)(qpw + c0 * 3);
    const float4 wB = *(const float4*)(qpw + c0 * 3 + 4);
    const float4 wC = *(const float4*)(qpw + c0 * 3 + 8);
    const float4 bq4 = *(const float4*)(qpb + c0);
    __syncthreads();

    #pragma unroll
    for (int i = 0; i < 4; ++i) {
      const int row = i * 4 + lg;
      const float x = qc[w][row * 3 + 0], y = qc[w][row * 3 + 1], z = qc[w][row * 3 + 2];
      s16x4 p;
      p[0] = (short)f2bf(fmaxf(wA.x * x + wA.y * y + wA.z * z + bq4.x, 0.f));
      p[1] = (short)f2bf(fmaxf(wA.w * x + wB.x * y + wB.y * z + bq4.y, 0.f));
      p[2] = (short)f2bf(fmaxf(wB.z * x + wB.w * y + wC.x * z + bq4.z, 0.f));
      p[3] = (short)f2bf(fmaxf(wC.y * x + wC.z * y + wC.w * z + bq4.w, 0.f));
      *(s16x4*)&xa[w][(row * 64 + c0) ^ ((row & 7) << 3)] = p;
    }
    __syncthreads();

    {
      s16x8 af0 = *(const s16x8*)&xa[w][(col * 64 + 0 + lg * 8) ^ ((col & 7) << 3)];
      s16x8 af1 = *(const s16x8*)&xa[w][(col * 64 + 32 + lg * 8) ^ ((col & 7) << 3)];
      f32x4 qv[4];
      #pragma unroll
      for (int nt = 0; nt < 4; ++nt) {
        f32x4 acc = {0.f, 0.f, 0.f, 0.f};
        #pragma unroll
        for (int kst = 0; kst < 2; ++kst) {
          const float* wr = ipw + (size_t)(nt * 16 + col) * 64 + kst * 32 + lg * 8;
          const float4 w0 = *(const float4*)wr;
          const float4 w1 = *(const float4*)(wr + 4);
          s16x8 bf;
          bf[0] = (short)f2bf(w0.x); bf[1] = (short)f2bf(w0.y);
          bf[2] = (short)f2bf(w0.z); bf[3] = (short)f2bf(w0.w);
          bf[4] = (short)f2bf(w1.x); bf[5] = (short)f2bf(w1.y);
          bf[6] = (short)f2bf(w1.z); bf[7] = (short)f2bf(w1.w);
          acc = __builtin_amdgcn_mfma_f32_16x16x32_bf16(kst == 0 ? af0 : af1, bf, acc, 0, 0, 0);
        }
        qv[nt] = acc;
      }
      __syncthreads();
      #pragma unroll
      for (int nt = 0; nt < 4; ++nt) {
        const int n = nt * 16 + col;
        const float bb = ipb[n];
        #pragma unroll
        for (int r = 0; r < 4; ++r) {
          const int row = lg * 4 + r;
          xa[w][(row * 64 + n) ^ ((row & 7) << 3)] = f2bf((qv[nt][r] + bb) * 0.25f);
        }
      }
    }
    __syncthreads();

    #pragma unroll
    for (int h = 0; h < HH; ++h) {
      s16x8 a = {0, 0, 0, 0, 0, 0, 0, 0};
      if (lg < 2)
        a = *(const s16x8*)&xa[w][(col * 64 + h * 16 + lg * 8) ^ ((col & 7) << 3)];
      #pragma unroll
      for (int nt = 0; nt < 4; ++nt) {
        const int n = nt * 16 + col;
        s16x8 bf = {0, 0, 0, 0, 0, 0, 0, 0};
        if (lg < 2) {
          #pragma unroll
          for (int j = 0; j < 8; ++j)   // wk2T[h][n][lg*8+j] = ipw[(64+h*16+lg*8+j)*64+n]
            ((unsigned short*)&bf)[j] = f2bf(ipw[(size_t)(64 + h * 16 + lg * 8 + j) * 64 + n]);
        }
        f32x4 acc = {0.f, 0.f, 0.f, 0.f};
        acc = __builtin_amdgcn_mfma_f32_16x16x32_bf16(a, bf, acc, 0, 0, 0);
        #pragma unroll
        for (int r = 0; r < 4; ++r) {
          const int m = lg * 4 + r;
          if (r0 + m < M)
            qw_out[(size_t)(r0 + m) * 256 + h * 64 + n] = f2bf(acc[r]);
        }
      }
    }
  }
}

// ---------------- attn_hot: lean path (qw/vfb/vc4 all precomputed) ----------------
__global__ __launch_bounds__(256, 4) void attn_hot(
    const unsigned short* __restrict__ vfb, const float4* __restrict__ vc4,
    const float* __restrict__ qcoord, const int* __restrict__ kidx,
    const unsigned char* __restrict__ km8, const int* __restrict__ km32,
    const int* __restrict__ maskfmt,
    const float* __restrict__ kpw, const float* __restrict__ kpb,
    const float* __restrict__ ipb,
    const unsigned short* __restrict__ wv_bf,
    const unsigned short* __restrict__ qw_pre,
    float* __restrict__ out, int M)
{
  __shared__ __align__(16) unsigned short shq[4][3456];
  __shared__ __align__(16) unsigned short wvl[4096];
  const int w = threadIdx.x >> 6, l = threadIdx.x & 63;
  const int col = l & 15, lg = l >> 4;
  int m = blockIdx.x * 4 + w;
  if (m >= M) m = M - 1;
  unsigned short* sh = shq[w];
  float* relf = (float*)(sh + 3072);
  const int is_u8 = *maskfmt;

  #pragma unroll
  for (int i = 0; i < 2; ++i) {
    const int ch = threadIdx.x * 2 + i;
    const int n = ch >> 3, g = ch & 7;
    const s16x8 v = *(const s16x8*)(wv_bf + n * 64 + g * 8);
    *(s16x8*)&wvl[n * 64 + ((g ^ (n & 7)) << 3)] = v;
  }

  const float qx = qcoord[m * 3 + 0], qy = qcoord[m * 3 + 1], qz = qcoord[m * 3 + 2];
  const int c0 = col * 4;
  const float4 kwA = *(const float4*)(kpw + c0 * 3);
  const float4 kwB = *(const float4*)(kpw + c0 * 3 + 4);
  const float4 kwC = *(const float4*)(kpw + c0 * 3 + 8);
  const float4 kbv = *(const float4*)(kpb + c0);

  // qw B-frags issued early: latency hides under P1/P5
  const s16x8 qb0 = *(const s16x8*)(qw_pre + (size_t)m * 256 + (col & 3) * 64 + 0 + lg * 8);
  const s16x8 qb1 = *(const s16x8*)(qw_pre + (size_t)m * 256 + (col & 3) * 64 + 32 + lg * 8);

  unsigned char msk = 0;
  if (l < KK) {
    const int idx = kidx[m * KK + l];
    msk = is_u8 ? km8[m * KK + l] : (unsigned char)(km32[m * KK + l] != 0);
    const float4 vc = vc4[idx];
    float4 rr;
    rr.x = vc.x - qx; rr.y = vc.y - qy; rr.z = vc.z - qz;
    rr.w = __int_as_float(idx);
    *(float4*)(relf + l * 4) = rr;
  }
  const unsigned long long bm = __ballot(l < KK && msk);
  __syncthreads();                       // covers wvl (cross-wave) + relf

  #pragma unroll
  for (int half = 0; half < 2; ++half) {
    float4 ra[6]; s16x4 va[6];
    #pragma unroll
    for (int j = 0; j < 6; ++j) {
      const int k = half * 24 + j * 4 + lg;
      ra[j] = *(const float4*)(relf + k * 4);
      va[j] = *(const s16x4*)(vfb + (size_t)__float_as_int(ra[j].w) * 64 + c0);
    }
    #pragma unroll
    for (int j = 0; j < 6; ++j) {
      const int k = half * 24 + j * 4 + lg;
      const float p0 = fmaxf(kwA.x * ra[j].x + kwA.y * ra[j].y + kwA.z * ra[j].z + kbv.x, 0.f);
      const float p1 = fmaxf(kwA.w * ra[j].x + kwB.x * ra[j].y + kwB.y * ra[j].z + kbv.y, 0.f);
      const float p2 = fmaxf(kwB.z * ra[j].x + kwB.w * ra[j].y + kwC.x * ra[j].z + kbv.z, 0.f);
      const float p3 = fmaxf(kwC.y * ra[j].x + kwC.z * ra[j].y + kwC.w * ra[j].z + kbv.w, 0.f);
      s16x4 p;
      p[0] = (short)f2bf(bf2f((unsigned short)va[j][0]) + p0);
      p[1] = (short)f2bf(bf2f((unsigned short)va[j][1]) + p1);
      p[2] = (short)f2bf(bf2f((unsigned short)va[j][2]) + p2);
      p[3] = (short)f2bf(bf2f((unsigned short)va[j][3]) + p3);
      *(s16x4*)&sh[(k * 64 + c0) ^ ((k & 7) << 3)] = p;
    }
  }
  WAVEFENCE();

  // ---- scores via MFMA ----
  s16x8 af[3][2];
  #pragma unroll
  for (int mt = 0; mt < 3; ++mt)
    #pragma unroll
    for (int kst = 0; kst < 2; ++kst) {
      const int row = mt * 16 + col;
      af[mt][kst] = *(const s16x8*)&sh[(row * 64 + kst * 32 + lg * 8) ^ ((row & 7) << 3)];
    }
  f32x4 sc[3];
  sc[0] = sc[1] = sc[2] = (f32x4){0.f, 0.f, 0.f, 0.f};
  __builtin_amdgcn_s_setprio(1);
  #pragma unroll
  for (int mt = 0; mt < 3; ++mt) {
    sc[mt] = __builtin_amdgcn_mfma_f32_16x16x32_bf16(af[mt][0], qb0, sc[mt], 0, 0, 0);
    sc[mt] = __builtin_amdgcn_mfma_f32_16x16x32_bf16(af[mt][1], qb1, sc[mt], 0, 0, 0);
  }
  __builtin_amdgcn_s_setprio(0);

  // ---- softmax ----
  float sv[12];
  {
    float mx = -INFINITY;
    #pragma unroll
    for (int mt = 0; mt < 3; ++mt)
      #pragma unroll
      for (int r = 0; r < 4; ++r) {
        const int key = mt * 16 + lg * 4 + r;
        float v = sc[mt][r];
        if ((bm >> key) & 1ull) v = -1e30f;
        sv[mt * 4 + r] = v;
        mx = fmaxf(mx, v);
      }
    mx = fmaxf(mx, __shfl_xor(mx, 16, 64));
    mx = fmaxf(mx, __shfl_xor(mx, 32, 64));
    float sum = 0.f;
    #pragma unroll
    for (int i = 0; i < 12; ++i) { float e = __expf(sv[i] - mx); sv[i] = e; sum += e; }
    sum += __shfl_xor(sum, 16, 64);
    sum += __shfl_xor(sum, 32, 64);
    const float inv = 1.f / sum;
    #pragma unroll
    for (int i = 0; i < 12; ++i) sv[i] *= inv;
  }
  if (col < HH) {
    #pragma unroll
    for (int mt = 0; mt < 3; ++mt)
      #pragma unroll
      for (int r = 0; r < 4; ++r)
        relf[(mt * 16 + lg * 4 + r) * 4 + col] = sv[mt * 4 + r];
  }
  WAVEFENCE();

  // ---- vv = kin @ wv^T, then o[c] = sum_k a[k][h(c)]*vv[k][c] + bv ----
  f32x4 vva[4][3];
  __builtin_amdgcn_s_setprio(1);
  #pragma unroll
  for (int nt = 0; nt < 4; ++nt) {
    const int n = nt * 16 + col;
    vva[nt][0] = vva[nt][1] = vva[nt][2] = (f32x4){0.f, 0.f, 0.f, 0.f};
    #pragma unroll
    for (int kst = 0; kst < 2; ++kst) {
      const s16x8 b = *(const s16x8*)&wvl[(n * 64 + kst * 32 + lg * 8) ^ ((n & 7) << 3)];
      vva[nt][0] = __builtin_amdgcn_mfma_f32_16x16x32_bf16(af[0][kst], b, vva[nt][0], 0, 0, 0);
      vva[nt][1] = __builtin_amdgcn_mfma_f32_16x16x32_bf16(af[1][kst], b, vva[nt][1], 0, 0, 0);
      vva[nt][2] = __builtin_amdgcn_mfma_f32_16x16x32_bf16(af[2][kst], b, vva[nt][2], 0, 0, 0);
    }
  }
  __builtin_amdgcn_s_setprio(0);
  float op[4] = {0.f, 0.f, 0.f, 0.f};
  #pragma unroll
  for (int mt = 0; mt < 3; ++mt)
    #pragma unroll
    for (int r = 0; r < 4; ++r) {
      const float4 a4 = *(const float4*)(relf + (mt * 16 + lg * 4 + r) * 4);
      op[0] += a4.x * vva[0][mt][r];
      op[1] += a4.y * vva[1][mt][r];
      op[2] += a4.z * vva[2][mt][r];
      op[3] += a4.w * vva[3][mt][r];
    }
  #pragma unroll
  for (int nt = 0; nt < 4; ++nt) {
    op[nt] += __shfl_xor(op[nt], 16, 64);
    op[nt] += __shfl_xor(op[nt], 32, 64);
  }
  {
    float oo = (lg == 0) ? op[0] : (lg == 1) ? op[1] : (lg == 2) ? op[2] : op[3];
    oo += ipb[2 * CC + lg * 16 + col];
    out[(size_t)m * CC + lg * 16 + col] = oo;
  }
}

// ---------------- fallback kernels (ws too small): r9/r10-proven ----------------
__global__ __launch_bounds__(256) void prep_kernel(
    const float* __restrict__ ipw, const float* __restrict__ opw,
    const float* __restrict__ l1w, const float* __restrict__ l2w,
    const float* __restrict__ ow,
    const float* __restrict__ ng, const float* __restrict__ nb,
    const float* __restrict__ nm, const float* __restrict__ nv,
    const float* __restrict__ b2g, const float* __restrict__ b2b,
    const float* __restrict__ b2m, const float* __restrict__ b2v,
    const unsigned char* __restrict__ km,
    float* __restrict__ ws)
{
  unsigned short* wsu = (unsigned short*)ws;
  if (blockIdx.x == 209) {
    int any = 0;
    for (int i = threadIdx.x; i < 4096; i += 256)
      if ((i & 3) && km[i]) any = 1;
    __shared__ int sb;
    if (threadIdx.x == 0) sb = 0;
    __syncthreads();
    if (any) atomicOr(&sb, 1);
    __syncthreads();
    if (threadIdx.x == 0) ((int*)ws)[26880] = sb;
    return;
  }
  int e = blockIdx.x * 256 + threadIdx.x;
  if (e < 4096)        wsu[e] = f2bf(ipw[e]);
  else if (e < 8192)  { int i = e - 4096; int h = i >> 10, c = (i >> 4) & 63, d = i & 15;
                        wsu[e] = f2bf(ipw[(size_t)(64 + h * 16 + d) * 64 + c]); }
  else if (e < 12288)  wsu[e] = f2bf(ipw[e]);
  else if (e < 16384)  wsu[e] = f2bf(opw[e - 12288]);
  else if (e < 32768)  wsu[e] = f2bf(l1w[e - 16384]);
  else if (e < 49152)  wsu[e] = f2bf(l2w[e - 32768]);
  else if (e < 53248)  wsu[e] = f2bf(ow[e - 49152]);
  else if (e < 53312) { int c = e - 53248; float s = ng[c] / sqrtf(nv[c] + 1e-5f);
                        ws[26624 + c] = s; ws[26624 + 64 + c] = nb[c] - nm[c] * s; }
  else if (e < 53376) { int c = e - 53312; float s = b2g[c] / sqrtf(b2v[c] + 1e-5f);
                        ws[26752 + c] = s; ws[26752 + 64 + c] = b2b[c] - b2m[c] * s; }
}

__global__ __launch_bounds__(256, 4) void attn_fallback(
    const float* __restrict__ vfeat, const float* __restrict__ vcoord,
    const float* __restrict__ qcoord, const int* __restrict__ kidx,
    const unsigned char* __restrict__ km8, const int* __restrict__ km32,
    const int* __restrict__ maskfmt,
    const float* __restrict__ qpw, const float* __restrict__ qpb,
    const float* __restrict__ kpw, const float* __restrict__ kpb,
    const float* __restrict__ ipb,
    const unsigned short* __restrict__ wq_bf,
    const unsigned short* __restrict__ wk2T_bf,
    const unsigned short* __restrict__ wv_bf,
    float* __restrict__ out, int M)
{
  __shared__ __align__(16) unsigned short shq[4][3776];
  __shared__ __align__(16) unsigned short wvl[4096];
  const int w = threadIdx.x >> 6, l = threadIdx.x & 63;
  const int col = l & 15, lg = l >> 4;
  int m = blockIdx.x * 4 + w;
  if (m >= M) m = M - 1;
  unsigned short* sh = shq[w];
  const int is_u8 = *maskfmt;
  float* relf = (float*)sh + 1696;

  #pragma unroll
  for (int i = 0; i < 2; ++i) {
    const int ch = threadIdx.x * 2 + i;
    const int n = ch >> 3, g = ch & 7;
    const s16x8 v = *(const s16x8*)(wv_bf + n * 64 + g * 8);
    *(s16x8*)&wvl[n * 64 + ((g ^ (n & 7)) << 3)] = v;
  }

  const float qx = qcoord[m * 3 + 0], qy = qcoord[m * 3 + 1], qz = qcoord[m * 3 + 2];
  const int c0 = col * 4;
  const float4 kwA = *(const float4*)(kpw + c0 * 3);
  const float4 kwB = *(const float4*)(kpw + c0 * 3 + 4);
  const float4 kwC = *(const float4*)(kpw + c0 * 3 + 8);
  const float4 kbv = *(const float4*)(kpb + c0);

  {
    float v = qpw[l * 3 + 0] * qx + qpw[l * 3 + 1] * qy + qpw[l * 3 + 2] * qz + qpb[l];
    sh[3328 + l] = f2bf(fmaxf(v, 0.f));
  }
  unsigned char msk = 0;
  if (l < KK) {
    int idx = kidx[m * KK + l];
    msk = is_u8 ? km8[m * KK + l] : (unsigned char)(km32[m * KK + l] != 0);
    relf[l * 4 + 0] = vcoord[idx * 3 + 0] - qx;
    relf[l * 4 + 1] = vcoord[idx * 3 + 1] - qy;
    relf[l * 4 + 2] = vcoord[idx * 3 + 2] - qz;
    relf[l * 4 + 3] = __int_as_float(idx);
  }
  const unsigned long long bm = __ballot(l < KK && msk);
  __syncthreads();

  {
    f32x4 qacc[4];
    #pragma unroll
    for (int nt = 0; nt < 4; ++nt) qacc[nt] = (f32x4){0.f, 0.f, 0.f, 0.f};
    #pragma unroll
    for (int kst = 0; kst < 2; ++kst) {
      const s16x8 a = *(const s16x8*)&sh[3328 + kst * 32 + lg * 8];
      #pragma unroll
      for (int nt = 0; nt < 4; ++nt) {
        const s16x8 b = *(const s16x8*)(wq_bf + (nt * 16 + col) * 64 + kst * 32 + lg * 8);
        qacc[nt] = __builtin_amdgcn_mfma_f32_16x16x32_bf16(a, b, qacc[nt], 0, 0, 0);
      }
    }
    __syncthreads();
    if (lg == 0) {
      #pragma unroll
      for (int nt = 0; nt < 4; ++nt)
        sh[3328 + nt * 16 + col] = f2bf((qacc[nt][0] + ipb[nt * 16 + col]) * 0.25f);
    }
    __syncthreads();
    f32x4 wacc[4];
    #pragma unroll
    for (int nt = 0; nt < 4; ++nt) wacc[nt] = (f32x4){0.f, 0.f, 0.f, 0.f};
    #pragma unroll
    for (int kst = 0; kst < 2; ++kst) {
      const int hblk = kst * 2 + (lg >> 1);
      s16x8 a = {0, 0, 0, 0, 0, 0, 0, 0};
      if (col == hblk) a = *(const s16x8*)&sh[3328 + kst * 32 + lg * 8];
      #pragma unroll
      for (int nt = 0; nt < 4; ++nt) {
        const s16x8 b = *(const s16x8*)(wk2T_bf + hblk * 1024 + (nt * 16 + col) * 16 + (lg & 1) * 8);
        wacc[nt] = __builtin_amdgcn_mfma_f32_16x16x32_bf16(a, b, wacc[nt], 0, 0, 0);
      }
    }
    if (lg == 0) {
      #pragma unroll
      for (int nt = 0; nt < 4; ++nt)
        #pragma unroll
        for (int r = 0; r < 4; ++r)
          sh[3072 + r * 64 + nt * 16 + col] = f2bf(wacc[nt][r]);
    }
  }

  #pragma unroll
  for (int half = 0; half < 2; ++half) {
    float4 ra[6], va[6];
    #pragma unroll
    for (int j = 0; j < 6; ++j) {
      const int k = half * 24 + j * 4 + lg;
      ra[j] = *(const float4*)(relf + k * 4);
      va[j] = *(const float4*)(vfeat + (size_t)__float_as_int(ra[j].w) * 64 + c0);
    }
    #pragma unroll
    for (int j = 0; j < 6; ++j) {
      const int k = half * 24 + j * 4 + lg;
      const float p0 = fmaxf(kwA.x * ra[j].x + kwA.y * ra[j].y + kwA.z * ra[j].z + kbv.x, 0.f);
      const float p1 = fmaxf(kwA.w * ra[j].x + kwB.x * ra[j].y + kwB.y * ra[j].z + kbv.y, 0.f);
      const float p2 = fmaxf(kwB.z * ra[j].x + kwB.w * ra[j].y + kwC.x * ra[j].z + kbv.z, 0.f);
      const float p3 = fmaxf(kwC.y * ra[j].x + kwC.z * ra[j].y + kwC.w * ra[j].z + kbv.w, 0.f);
      s16x4 p;
      p[0] = (short)f2bf(va[j].x + p0); p[1] = (short)f2bf(va[j].y + p1);
      p[2] = (short)f2bf(va[j].z + p2); p[3] = (short)f2bf(va[j].w + p3);
      *(s16x4*)&sh[(k * 64 + c0) ^ ((k & 7) << 3)] = p;
    }
  }
  __syncthreads();

  s16x8 af[3][2];
  #pragma unroll
  for (int mt = 0; mt < 3; ++mt)
    #pragma unroll
    for (int kst = 0; kst < 2; ++kst) {
      const int row = mt * 16 + col;
      af[mt][kst] = *(const s16x8*)&sh[(row * 64 + kst * 32 + lg * 8) ^ ((row & 7) << 3)];
    }
  f32x4 sc[3];
  sc[0] = sc[1] = sc[2] = (f32x4){0.f, 0.f, 0.f, 0.f};
  #pragma unroll
  for (int kst = 0; kst < 2; ++kst) {
    const s16x8 b = *(const s16x8*)&sh[3072 + (col & 3) * 64 + kst * 32 + lg * 8];
    #pragma unroll
    for (int mt = 0; mt < 3; ++mt)
      sc[mt] = __builtin_amdgcn_mfma_f32_16x16x32_bf16(af[mt][kst], b, sc[mt], 0, 0, 0);
  }

  float sv[12];
  {
    float mx = -INFINITY;
    #pragma unroll
    for (int mt = 0; mt < 3; ++mt)
      #pragma unroll
      for (int r = 0; r < 4; ++r) {
        const int key = mt * 16 + lg * 4 + r;
        float v = sc[mt][r];
        if ((bm >> key) & 1ull) v = -1e30f;
        sv[mt * 4 + r] = v;
        mx = fmaxf(mx, v);
      }
    mx = fmaxf(mx, __shfl_xor(mx, 16, 64));
    mx = fmaxf(mx, __shfl_xor(mx, 32, 64));
    float sum = 0.f;
    #pragma unroll
    for (int i = 0; i < 12; ++i) { float e = __expf(sv[i] - mx); sv[i] = e; sum += e; }
    sum += __shfl_xor(sum, 16, 64);
    sum += __shfl_xor(sum, 32, 64);
    const float inv = 1.f / sum;
    #pragma unroll
    for (int i = 0; i < 12; ++i) sv[i] *= inv;
  }

  float op[4];
  #pragma unroll
  for (int nt = 0; nt < 4; ++nt) {
    const int n = nt * 16 + col;
    f32x4 vv0 = {0.f, 0.f, 0.f, 0.f}, vv1 = vv0, vv2 = vv0;
    #pragma unroll
    for (int kst = 0; kst < 2; ++kst) {
      const s16x8 b = *(const s16x8*)&wvl[(n * 64 + kst * 32 + lg * 8) ^ ((n & 7) << 3)];
      vv0 = __builtin_amdgcn_mfma_f32_16x16x32_bf16(af[0][kst], b, vv0, 0, 0, 0);
      vv1 = __builtin_amdgcn_mfma_f32_16x16x32_bf16(af[1][kst], b, vv1, 0, 0, 0);
      vv2 = __builtin_amdgcn_mfma_f32_16x16x32_bf16(af[2][kst], b, vv2, 0, 0, 0);
    }
    const int src = lg * 16 + nt;
    float o = 0.f;
    #pragma unroll
    for (int mt = 0; mt < 3; ++mt)
      #pragma unroll
      for (int r = 0; r < 4; ++r) {
        const float a = __shfl(sv[mt * 4 + r], src, 64);
        const float v = (mt == 0) ? vv0[r] : (mt == 1) ? vv1[r] : vv2[r];
        o += a * v;
      }
    op[nt] = o;
  }
  #pragma unroll
  for (int nt = 0; nt < 4; ++nt) {
    op[nt] += __shfl_xor(op[nt], 16, 64);
    op[nt] += __shfl_xor(op[nt], 32, 64);
  }
  {
    float oo = (lg == 0) ? op[0] : (lg == 1) ? op[1] : (lg == 2) ? op[2] : op[3];
    oo += ipb[2 * CC + lg * 16 + col];
    out[(size_t)m * CC + lg * 16 + col] = oo;
  }
}

// ---------------- chain: o -> attend -> FFN -> BN -> out layer, all MFMA ----------------
__global__ __launch_bounds__(256, 2) void chain_kernel(
    float* __restrict__ inout, const unsigned short* __restrict__ wsu,
    const float* __restrict__ opb, const float* __restrict__ l1b,
    const float* __restrict__ l2b, const float* __restrict__ ob,
    const float* __restrict__ nrm, const float* __restrict__ bn2, int M)
{
  __shared__ short lds[4][5120];
  const int w = threadIdx.x >> 6;
  const int l = threadIdx.x & 63;
  const int col = l & 15, lg = l >> 4;
  const int r0 = blockIdx.x * 64 + w * 16;

  short* XH = &lds[w][0];
  short* XB = &lds[w][4096];
  const unsigned short* opw_bf = wsu + 12288;
  const unsigned short* l1_bf  = wsu + 16384;
  const unsigned short* l2_bf  = wsu + 32768;
  const unsigned short* ow_bf  = wsu + 49152;

  #pragma unroll
  for (int i = 0; i < 4; ++i) {
    int row = i * 4 + lg, cb = col * 4;
    float4 v = make_float4(0.f, 0.f, 0.f, 0.f);
    if (r0 + row < M) v = *(const float4*)(&inout[(size_t)(r0 + row) * 64 + cb]);
    s16x4 p; p[0] = (short)f2bf(v.x); p[1] = (short)f2bf(v.y);
    p[2] = (short)f2bf(v.z); p[3] = (short)f2bf(v.w);
    *(s16x4*)&XH[(row * 64 + cb) ^ ((row & 7) << 3)] = p;
  }

  s16x8 afa[2];
  #pragma unroll
  for (int kst = 0; kst < 2; ++kst)
    afa[kst] = *(const s16x8*)&XH[(col * 64 + kst * 32 + lg * 8) ^ ((col & 7) << 3)];
  f32x4 att[4];
  #pragma unroll
  for (int nt = 0; nt < 4; ++nt) {
    f32x4 acc = {0.f, 0.f, 0.f, 0.f};
    #pragma unroll
    for (int kst = 0; kst < 2; ++kst) {
      const s16x8 b = *(const s16x8*)&opw_bf[(nt * 16 + col) * 64 + kst * 32 + lg * 8];
      acc = __builtin_amdgcn_mfma_f32_16x16x32_bf16(afa[kst], b, acc, 0, 0, 0);
    }
    float bias = opb[nt * 16 + col];
    #pragma unroll
    for (int r = 0; r < 4; ++r) {
      acc[r] += bias;
      int row = lg * 4 + r;
      XB[(row * 64 + nt * 16 + col) ^ ((row & 7) << 3)] = (short)f2bf(acc[r]);
    }
    att[nt] = acc;
  }

  s16x8 afb[2];
  #pragma unroll
  for (int kst = 0; kst < 2; ++kst)
    afb[kst] = *(const s16x8*)&XB[(col * 64 + kst * 32 + lg * 8) ^ ((col & 7) << 3)];
  #pragma unroll
  for (int nt = 0; nt < 16; ++nt) {
    f32x4 acc = {0.f, 0.f, 0.f, 0.f};
    #pragma unroll
    for (int kst = 0; kst < 2; ++kst) {
      const s16x8 b = *(const s16x8*)&l1_bf[(nt * 16 + col) * 64 + kst * 32 + lg * 8];
      acc = __builtin_amdgcn_mfma_f32_16x16x32_bf16(afb[kst], b, acc, 0, 0, 0);
    }
    float bias = l1b[nt * 16 + col];
    #pragma unroll
    for (int r = 0; r < 4; ++r) {
      float h = fmaxf(acc[r] + bias, 0.f);
      int row = lg * 4 + r;
      XH[(row * 256 + nt * 16 + col) ^ ((row & 7) << 3)] = (short)f2bf(h);
    }
  }

  s16x8 afh[8];
  #pragma unroll
  for (int kst = 0; kst < 8; ++kst)
    afh[kst] = *(const s16x8*)&XH[(col * 256 + kst * 32 + lg * 8) ^ ((col & 7) << 3)];
  #pragma unroll
  for (int nt = 0; nt < 4; ++nt) {
    f32x4 acc = {0.f, 0.f, 0.f, 0.f};
    #pragma unroll
    for (int kst = 0; kst < 8; ++kst) {
      const s16x8 b = *(const s16x8*)&l2_bf[(nt * 16 + col) * 256 + kst * 32 + lg * 8];
      acc = __builtin_amdgcn_mfma_f32_16x16x32_bf16(afh[kst], b, acc, 0, 0, 0);
    }
    int nc = nt * 16 + col;
    float bias = l2b[nc], sN = nrm[nc], tN = nrm[64 + nc];
    #pragma unroll
    for (int r = 0; r < 4; ++r) {
      float x = (att[nt][r] + acc[r] + bias) * sN + tN;
      int row = lg * 4 + r;
      XB[(row * 64 + nc) ^ ((row & 7) << 3)] = (short)f2bf(x);
    }
  }

  s16x8 afx[2];
  #pragma unroll
  for (int kst = 0; kst < 2; ++kst)
    afx[kst] = *(const s16x8*)&XB[(col * 64 + kst * 32 + lg * 8) ^ ((col & 7) << 3)];
  #pragma unroll
  for (int nt = 0; nt < 4; ++nt) {
    f32x4 acc = {0.f, 0.f, 0.f, 0.f};
    #pragma unroll
    for (int kst = 0; kst < 2; ++kst) {
      const s16x8 b = *(const s16x8*)&ow_bf[(nt * 16 + col) * 64 + kst * 32 + lg * 8];
      acc = __builtin_amdgcn_mfma_f32_16x16x32_bf16(afx[kst], b, acc, 0, 0, 0);
    }
    int nc = nt * 16 + col;
    float bias = ob[nc], sB = bn2[nc], tB = bn2[64 + nc];
    #pragma unroll
    for (int r = 0; r < 4; ++r) {
      float y = fmaxf((acc[r] + bias) * sB + tB, 0.f);
      int row = lg * 4 + r;
      if (r0 + row < M) inout[(size_t)(r0 + row) * 64 + nc] = y;
    }
  }
}

extern "C" void kernel_launch(void* const* d_in, const int* in_sizes, int n_in,
                              void* d_out, int out_size, void* d_ws, size_t ws_size,
                              hipStream_t stream) {
  const float* vfeat  = (const float*)d_in[0];
  const float* vcoord = (const float*)d_in[1];
  const float* qcoord = (const float*)d_in[2];
  const int*   kidx   = (const int*)d_in[3];
  const unsigned char* km8  = (const unsigned char*)d_in[4];
  const int*           km32 = (const int*)d_in[4];
  const float* qpw = (const float*)d_in[5];
  const float* qpb = (const float*)d_in[6];
  const float* kpw = (const float*)d_in[7];
  const float* kpb = (const float*)d_in[8];
  const float* ipw = (const float*)d_in[9];
  const float* ipb = (const float*)d_in[10];
  const float* opw = (const float*)d_in[11];
  const float* opb = (const float*)d_in[12];
  const float* l1w = (const float*)d_in[13];
  const float* l1b = (const float*)d_in[14];
  const float* l2w = (const float*)d_in[15];
  const float* l2b = (const float*)d_in[16];
  const float* ng  = (const float*)d_in[17];
  const float* nb  = (const float*)d_in[18];
  const float* nm  = (const float*)d_in[19];
  const float* nv  = (const float*)d_in[20];
  const float* ow  = (const float*)d_in[21];
  const float* ob  = (const float*)d_in[22];
  const float* b2g = (const float*)d_in[23];
  const float* b2b = (const float*)d_in[24];
  const float* b2m = (const float*)d_in[25];
  const float* b2v = (const float*)d_in[26];

  const int M  = in_sizes[2] / 3;
  const int NV = in_sizes[0] / 64;
  float* ws  = (float*)d_ws;
  float* out = (float*)d_out;
  unsigned short* wsu = (unsigned short*)ws;
  const int* flag = (const int*)ws + 26880;

  const size_t need = (size_t)114688 + (size_t)M * 512 + (size_t)NV * 128 + (size_t)NV * 16;
  const int hot = (ws_size >= need) ? 1 : 0;
  unsigned short* qw  = wsu + QW_OFF_U16;
  unsigned short* vfb = wsu + QW_OFF_U16 + (size_t)M * 256;
  float4* vc4 = (float4*)(wsu + QW_OFF_U16 + (size_t)M * 256 + (size_t)NV * 64);

  if (hot) {
    const int qblocks = (M + 63) / 64;
    setup_kernel<<<210 + CASTB + qblocks, 256, 0, stream>>>(
        ipw, opw, l1w, l2w, ow, ng, nb, nm, nv, b2g, b2b, b2m, b2v, km8,
        vfeat, vcoord, qcoord, qpw, qpb, ipb, ws, vfb, vc4, qw, M, NV);
    attn_hot<<<(M + 3) / 4, 256, 0, stream>>>(vfb, vc4, qcoord, kidx,
                                              km8, km32, flag, kpw, kpb, ipb,
                                              wsu + 8192, qw, out, M);
  } else {
    prep_kernel<<<210, 256, 0, stream>>>(ipw, opw, l1w, l2w, ow,
                                         ng, nb, nm, nv, b2g, b2b, b2m, b2v, km8, ws);
    attn_fallback<<<(M + 3) / 4, 256, 0, stream>>>(vfeat, vcoord, qcoord, kidx,
                                                   km8, km32, flag,
                                                   qpw, qpb, kpw, kpb, ipb,
                                                   wsu, wsu + 4096, wsu + 8192, out, M);
  }
  chain_kernel<<<(M + 63) / 64, 256, 0, stream>>>(out, wsu, opb, l1b, l2b, ob,
                                                  ws + 26624, ws + 26752, M);
}